// Round 8
// baseline (820.582 us; speedup 1.0000x reference)
//
#include <hip/hip_runtime.h>
#include <hip/hip_bf16.h>

#define NN 50000
#define EE 800000
#define GG 64
#define PCH 16   // pooling chunks per graph
#define SCB ((NN + 255) / 256)   // 196 scan blocks
// D=128, H=8, C=16, L=3

typedef __attribute__((ext_vector_type(8)))  short          s16x8;
typedef __attribute__((ext_vector_type(8)))  unsigned short u16x8;
typedef __attribute__((ext_vector_type(16))) float          f32x16;

// bf16 helpers (bit-pattern based)
union BFU { __hip_bfloat16 h; unsigned short u; };
__device__ __forceinline__ unsigned short f2bf(float f) {
    BFU b; b.h = __float2bfloat16(f); return b.u;
}
#define B2F_LO(u) __uint_as_float((u) << 16)
#define B2F_HI(u) __uint_as_float((u) & 0xffff0000u)
#define BF2F(us)  __uint_as_float(((unsigned)(us)) << 16)

// ---------------------------------------------------------------- CSR build
__global__ __launch_bounds__(256) void hist_kernel(const int* __restrict__ dst,
                                                   int* __restrict__ counts) {
    int e = blockIdx.x * 256 + threadIdx.x;
    if (e < EE) atomicAdd(&counts[dst[e]], 1);
}

__global__ __launch_bounds__(256)
void block_scan(const int* __restrict__ counts, int* __restrict__ offsets,
                int* __restrict__ bsums) {
    __shared__ int sm[256];
    const int t = threadIdx.x;
    const int i = blockIdx.x * 256 + t;
    const int v = (i < NN) ? counts[i] : 0;
    sm[t] = v;
    __syncthreads();
    for (int off = 1; off < 256; off <<= 1) {
        int val = (t >= off) ? sm[t - off] : 0;
        __syncthreads();
        sm[t] += val;
        __syncthreads();
    }
    if (i < NN) offsets[i] = sm[t] - v;      // exclusive
    if (t == 255) bsums[blockIdx.x] = sm[255];
}

__global__ __launch_bounds__(256)
void scan_sums(int* __restrict__ bsums) {   // in-place -> exclusive block bases
    __shared__ int sm[256];
    const int t = threadIdx.x;
    const int v = (t < SCB) ? bsums[t] : 0;
    sm[t] = v;
    __syncthreads();
    for (int off = 1; off < 256; off <<= 1) {
        int val = (t >= off) ? sm[t - off] : 0;
        __syncthreads();
        sm[t] += val;
        __syncthreads();
    }
    if (t < SCB) bsums[t] = sm[t] - v;       // exclusive base
}

__global__ __launch_bounds__(256)
void add_base(int* __restrict__ offsets, const int* __restrict__ bsums) {
    const int i = blockIdx.x * 256 + threadIdx.x;
    if (i < NN) offsets[i] += bsums[blockIdx.x];
    if (i == 0) offsets[NN] = EE;            // total edges is a constant
}

__global__ __launch_bounds__(256) void scatter_kernel(const int* __restrict__ src,
                                                      const int* __restrict__ dst,
                                                      const int* __restrict__ offs,
                                                      int* __restrict__ cursor,
                                                      int* __restrict__ csrc) {
    int e = blockIdx.x * 256 + threadIdx.x;
    if (e < EE) {
        int dn = dst[e];
        int p = atomicAdd(&cursor[dn], 1);
        csrc[offs[dn] + p] = src[e];
    }
}

__global__ __launch_bounds__(256) void starts_kernel(const int* __restrict__ batch,
                                                     int* __restrict__ starts) {
    int i = blockIdx.x * 256 + threadIdx.x;
    if (i > NN) return;
    int b  = (i < NN) ? batch[i] : GG;
    int bp = (i == 0) ? -1 : batch[i - 1];
    for (int g = bp + 1; g <= b && g <= GG; ++g) starts[g] = i;
}

// ---- degree-sorted node permutation (kills degree divergence in attn) ----
// Per-node results are independent of processing order, so within-bin
// nondeterminism of the counting sort cannot change the output bits.
__global__ __launch_bounds__(256)
void deg_hist(const int* __restrict__ counts, int* __restrict__ dhist) {
    int i = blockIdx.x * 256 + threadIdx.x;
    if (i < NN) atomicAdd(&dhist[min(counts[i], 255)], 1);
}

__global__ __launch_bounds__(256)
void deg_scan(int* __restrict__ dhist) {     // in-place -> exclusive bases
    __shared__ int sm[256];
    const int t = threadIdx.x;
    const int v = dhist[t];
    sm[t] = v;
    __syncthreads();
    for (int off = 1; off < 256; off <<= 1) {
        int val = (t >= off) ? sm[t - off] : 0;
        __syncthreads();
        sm[t] += val;
        __syncthreads();
    }
    dhist[t] = sm[t] - v;                    // exclusive base
}

__global__ __launch_bounds__(256)
void deg_scatter(const int* __restrict__ counts, const int* __restrict__ dbase,
                 int* __restrict__ dcur, int* __restrict__ perm) {
    int i = blockIdx.x * 256 + threadIdx.x;
    if (i < NN) {
        int d = min(counts[i], 255);
        int p = atomicAdd(&dcur[d], 1);
        perm[dbase[d] + p] = i;
    }
}

// ---------------------------------------------------------------- weight prep
__global__ __launch_bounds__(256)
void prep_weights(const float* __restrict__ Wq, const float* __restrict__ Wk,
                  const float* __restrict__ Wv, const float* __restrict__ Ws,
                  unsigned short* __restrict__ wtbh, unsigned short* __restrict__ wtbl) {
    const int mat = blockIdx.x;           // 0..11
    const int l = mat >> 2, m = mat & 3;
    const float* W;
    switch (m) {
        case 0:  W = Wq; break;
        case 1:  W = Wk; break;
        case 2:  W = Wv; break;
        default: W = Ws; break;
    }
    W += (size_t)l * 16384;
    const int t = threadIdx.x;
    const int col = blockIdx.y * 16 + (t >> 4);
    const int kb  = (t & 15) * 8;
    u16x8 hi, lo;
    #pragma unroll
    for (int j = 0; j < 8; ++j) {
        float w = W[(kb + j) * 128 + col];
        unsigned short uh = f2bf(w);
        hi[j] = uh;
        lo[j] = f2bf(w - BF2F(uh));
    }
    const size_t o = (size_t)mat * 16384 + col * 128 + kb;
    *(u16x8*)(wtbh + o) = hi;
    *(u16x8*)(wtbl + o) = lo;
}

// ---------------------------------------------------------------- MFMA GEMM (split-bf16)
__global__ __launch_bounds__(256, 2)
void gemm_mfma(const float* __restrict__ xin,
               const unsigned short* __restrict__ wHg,   // + l*4*16384
               const unsigned short* __restrict__ wLg,
               const float* __restrict__ bq, const float* __restrict__ bk,
               const float* __restrict__ bv, const float* __restrict__ bs,
               float* __restrict__ q, unsigned short* __restrict__ kvb,
               float* __restrict__ xs) {
    __shared__ unsigned short xl[16384];   // [0..8191]=hi, [8192..]=lo
    __shared__ unsigned short wsm[16384];
    const int t = threadIdx.x;
    const int n0 = blockIdx.x * 64;

    // ---- stage x (fp32 -> split bf16, swizzled) ----
    const float4* X4 = (const float4*)xin;
    for (int i = t; i < 1024; i += 256) {            // 64 rows x 16 chunks
        const int row = i >> 4, ch = i & 15;
        const int node = n0 + row;
        float4 fa = make_float4(0.f, 0.f, 0.f, 0.f);
        float4 fb = make_float4(0.f, 0.f, 0.f, 0.f);
        if (node < NN) { fa = X4[node * 32 + ch * 2]; fb = X4[node * 32 + ch * 2 + 1]; }
        const float fv[8] = {fa.x, fa.y, fa.z, fa.w, fb.x, fb.y, fb.z, fb.w};
        u16x8 hi, lo;
        #pragma unroll
        for (int j = 0; j < 8; ++j) {
            unsigned short uh = f2bf(fv[j]);
            hi[j] = uh;
            lo[j] = f2bf(fv[j] - BF2F(uh));
        }
        const int base = row * 128 + (ch ^ (row & 7)) * 8;
        *(u16x8*)&xl[base] = hi;
        *(u16x8*)&xl[8192 + base] = lo;
    }
    __syncthreads();

    // ---- per-wave tile & A-fragments (held in regs for all 4 matrices) ----
    const int lane = t & 63, wid = t >> 6;
    const int r = lane & 31, g = lane >> 5;
    const int nt = (wid & 1) * 32;        // node offset in tile
    const int cb = (wid >> 1) * 64;       // col base
    s16x8 ah[8], al[8];
    {
        const int row = nt + r;
        const int s = row & 7;
        const int rb = row * 128;
        #pragma unroll
        for (int kc = 0; kc < 8; ++kc) {
            const int idx = rb + (((kc << 1) | g) ^ s) * 8;
            ah[kc] = *(const s16x8*)&xl[idx];
            al[kc] = *(const s16x8*)&xl[8192 + idx];
        }
    }
    const int col0 = cb + r, col1 = cb + 32 + r;
    const int wb0 = col0 * 128, ws0 = col0 & 7;
    const int wb1 = col1 * 128, ws1 = col1 & 7;

    for (int m = 0; m < 4; ++m) {
        f32x16 acc0, acc1;
        #pragma unroll
        for (int j = 0; j < 16; ++j) { acc0[j] = 0.f; acc1[j] = 0.f; }

        #pragma unroll
        for (int part = 0; part < 2; ++part) {
            __syncthreads();
            const u16x8* Wg = (const u16x8*)((part == 0 ? wHg : wLg) + m * 16384);
            for (int i = t; i < 2048; i += 256) {    // 128 rows x 16 chunks
                const int row = i >> 4, ch = i & 15;
                *(u16x8*)&wsm[row * 128 + (ch ^ (row & 7)) * 8] = Wg[i];
            }
            __syncthreads();
            #pragma unroll
            for (int kc = 0; kc < 8; ++kc) {
                const s16x8 b0 = *(const s16x8*)&wsm[wb0 + (((kc << 1) | g) ^ ws0) * 8];
                const s16x8 b1 = *(const s16x8*)&wsm[wb1 + (((kc << 1) | g) ^ ws1) * 8];
                acc0 = __builtin_amdgcn_mfma_f32_32x32x16_bf16(ah[kc], b0, acc0, 0, 0, 0);
                acc1 = __builtin_amdgcn_mfma_f32_32x32x16_bf16(ah[kc], b1, acc1, 0, 0, 0);
                if (part == 0) {
                    acc0 = __builtin_amdgcn_mfma_f32_32x32x16_bf16(al[kc], b0, acc0, 0, 0, 0);
                    acc1 = __builtin_amdgcn_mfma_f32_32x32x16_bf16(al[kc], b1, acc1, 0, 0, 0);
                }
            }
        }

        // ---- epilogue ----
        const float* bp;
        switch (m) {
            case 0:  bp = bq; break;
            case 1:  bp = bk; break;
            case 2:  bp = bv; break;
            default: bp = bs; break;
        }
        const float b0 = bp[col0], b1 = bp[col1];
        if (m == 0 || m == 3) {
            float* outp = (m == 0) ? q : xs;
            #pragma unroll
            for (int reg = 0; reg < 16; ++reg) {
                const int node = n0 + nt + (reg & 3) + 8 * (reg >> 2) + 4 * g;
                if (node < NN) {
                    outp[node * 128 + col0] = acc0[reg] + b0;
                    outp[node * 128 + col1] = acc1[reg] + b1;
                }
            }
        } else {
            const int koff = (m == 1) ? 0 : 16;      // k at +0, v at +16 (ushorts)
            const int o0 = (col0 >> 4) * 32 + koff + (col0 & 15);
            const int o1 = (col1 >> 4) * 32 + koff + (col1 & 15);
            #pragma unroll
            for (int reg = 0; reg < 16; ++reg) {
                const int node = n0 + nt + (reg & 3) + 8 * (reg >> 2) + 4 * g;
                if (node < NN) {
                    kvb[(size_t)node * 256 + o0] = f2bf(acc0[reg] + b0);
                    kvb[(size_t)node * 256 + o1] = f2bf(acc1[reg] + b1);
                }
            }
        }
    }
}

// ---------------------------------------------------------------- attention (CSR, online softmax)
// thread = (perm'd node, head); degree-sorted perm makes the 8 groups of a
// wave have near-equal trip counts (removes ~36% exec-mask waste).
__global__ __launch_bounds__(256)
void attn_kernel(const float* __restrict__ q, const uint4* __restrict__ kv4,
                 float* __restrict__ xio,
                 const int* __restrict__ offs, const int* __restrict__ csrc,
                 const int* __restrict__ perm) {
    const int t = threadIdx.x;
    const int h = t & 7;
    const int idx = blockIdx.x * 32 + (t >> 3);
    if (idx >= NN) return;
    const int n = perm[idx];
    const float4* qp = (const float4*)(q + n * 128 + h * 16);
    const float4 q0 = qp[0], q1 = qp[1], q2 = qp[2], q3 = qp[3];
    float m = -__builtin_inff();
    float d = 0.f;
    float4 a0 = {}, a1 = {}, a2 = {}, a3 = {};
    const int e0 = offs[n], e1 = offs[n + 1];
    for (int e = e0; e < e1; ++e) {
        const int s = csrc[e];
        const uint4* kvp = kv4 + (size_t)s * 32 + h * 4;   // 512B row, 64B per head
        const uint4 ka = kvp[0], kb = kvp[1];              // k: 16 bf16
        float dot =
            q0.x * B2F_LO(ka.x) + q0.y * B2F_HI(ka.x) + q0.z * B2F_LO(ka.y) + q0.w * B2F_HI(ka.y)
          + q1.x * B2F_LO(ka.z) + q1.y * B2F_HI(ka.z) + q1.z * B2F_LO(ka.w) + q1.w * B2F_HI(ka.w)
          + q2.x * B2F_LO(kb.x) + q2.y * B2F_HI(kb.x) + q2.z * B2F_LO(kb.y) + q2.w * B2F_HI(kb.y)
          + q3.x * B2F_LO(kb.z) + q3.y * B2F_HI(kb.z) + q3.z * B2F_LO(kb.w) + q3.w * B2F_HI(kb.w);
        const float alpha = dot * 0.25f;                   // / sqrt(C=16)
        const float nm = fmaxf(m, alpha);
        const float scale = __expf(m - nm);                // 0 on first edge
        const float p = __expf(alpha - nm);
        d = d * scale + p;
        const uint4 va = kvp[2], vb = kvp[3];              // v: 16 bf16
        a0.x = a0.x * scale + p * B2F_LO(va.x); a0.y = a0.y * scale + p * B2F_HI(va.x);
        a0.z = a0.z * scale + p * B2F_LO(va.y); a0.w = a0.w * scale + p * B2F_HI(va.y);
        a1.x = a1.x * scale + p * B2F_LO(va.z); a1.y = a1.y * scale + p * B2F_HI(va.z);
        a1.z = a1.z * scale + p * B2F_LO(va.w); a1.w = a1.w * scale + p * B2F_HI(va.w);
        a2.x = a2.x * scale + p * B2F_LO(vb.x); a2.y = a2.y * scale + p * B2F_HI(vb.x);
        a2.z = a2.z * scale + p * B2F_LO(vb.y); a2.w = a2.w * scale + p * B2F_HI(vb.y);
        a3.x = a3.x * scale + p * B2F_LO(vb.z); a3.y = a3.y * scale + p * B2F_HI(vb.z);
        a3.z = a3.z * scale + p * B2F_LO(vb.w); a3.w = a3.w * scale + p * B2F_HI(vb.w);
        m = nm;
    }
    const float inv = 1.f / (d + 1e-16f);
    float4* op = (float4*)(xio + n * 128 + h * 16);
    float4 o0 = op[0], o1 = op[1], o2 = op[2], o3 = op[3];
    o0.x += a0.x * inv; o0.y += a0.y * inv; o0.z += a0.z * inv; o0.w += a0.w * inv;
    o1.x += a1.x * inv; o1.y += a1.y * inv; o1.z += a1.z * inv; o1.w += a1.w * inv;
    o2.x += a2.x * inv; o2.y += a2.y * inv; o2.z += a2.z * inv; o2.w += a2.w * inv;
    o3.x += a3.x * inv; o3.y += a3.y * inv; o3.z += a3.z * inv; o3.w += a3.w * inv;
    op[0] = o0; op[1] = o1; op[2] = o2; op[3] = o3;
}

// ---------------------------------------------------------------- readout (2-phase, fused gate)
__global__ __launch_bounds__(128)
void pool_partial(const float* __restrict__ x, const float* __restrict__ wg,
                  const float* __restrict__ bg, const int* __restrict__ starts,
                  float* __restrict__ psum, float* __restrict__ pmax) {
    const int g  = blockIdx.x / PCH;
    const int ch = blockIdx.x % PCH;
    const int c  = threadIdx.x;
    const int s0 = starts[g], s1 = starts[g + 1];
    const int total = s1 - s0;
    const int len = (total + PCH - 1) / PCH;
    const int n0 = s0 + ch * len;
    const int n1 = min(n0 + len, s1);
    const float w = wg[c];
    const float b = bg[0];
    __shared__ float red[2];
    float sum = 0.f, mx = -__builtin_inff();
    for (int n = n0; n < n1; ++n) {
        const float xv = x[n * 128 + c];
        float p = xv * w;
        #pragma unroll
        for (int o = 32; o; o >>= 1) p += __shfl_xor(p, o);
        if ((c & 63) == 0) red[c >> 6] = p;
        __syncthreads();
        const float dot = red[0] + red[1];
        __syncthreads();
        const float score = 1.f / (1.f + __expf(-(dot + b)));
        sum += score * xv;
        mx = fmaxf(mx, xv);
    }
    psum[blockIdx.x * 128 + c] = sum;
    pmax[blockIdx.x * 128 + c] = mx;
}

__global__ __launch_bounds__(128)
void pool_final(const float* __restrict__ psum, const float* __restrict__ pmax,
                float* __restrict__ out) {
    const int g = blockIdx.x, c = threadIdx.x;
    float s = 0.f, m = -__builtin_inff();
    #pragma unroll
    for (int ch = 0; ch < PCH; ++ch) {
        s += psum[(g * PCH + ch) * 128 + c];
        m = fmaxf(m, pmax[(g * PCH + ch) * 128 + c]);
    }
    out[g * 256 + c] = s;
    out[g * 256 + 128 + c] = m;
}

// ---------------------------------------------------------------- launch
extern "C" void kernel_launch(void* const* d_in, const int* in_sizes, int n_in,
                              void* d_out, int out_size, void* d_ws, size_t ws_size,
                              hipStream_t stream) {
    const float* x     = (const float*)d_in[0];
    const int*   ei    = (const int*)d_in[1];
    const int*   batch = (const int*)d_in[2];
    const float* Wq = (const float*)d_in[3];
    const float* bq = (const float*)d_in[4];
    const float* Wk = (const float*)d_in[5];
    const float* bk = (const float*)d_in[6];
    const float* Wv = (const float*)d_in[7];
    const float* bv = (const float*)d_in[8];
    const float* Ws = (const float*)d_in[9];
    const float* bs = (const float*)d_in[10];
    const float* wg = (const float*)d_in[11];
    const float* bg = (const float*)d_in[12];
    float* out = (float*)d_out;

    char* w = (char*)d_ws;
    float* qb            = (float*)w;          w += (size_t)NN * 128 * 4;
    unsigned short* kvb  = (unsigned short*)w; w += (size_t)NN * 256 * 2;
    float* bufA          = (float*)w;          w += (size_t)NN * 128 * 4;
    float* bufB          = (float*)w;          w += (size_t)NN * 128 * 4;
    float* psum          = (float*)w;          w += (size_t)GG * PCH * 128 * 4;
    float* pmax          = (float*)w;          w += (size_t)GG * PCH * 128 * 4;
    unsigned short* wtbh = (unsigned short*)w; w += (size_t)12 * 16384 * 2;
    unsigned short* wtbl = (unsigned short*)w; w += (size_t)12 * 16384 * 2;
    int* counts          = (int*)w;            w += (size_t)NN * 4;
    int* offsets         = (int*)w;            w += (size_t)(NN + 1) * 4;
    int* bsums           = (int*)w;            w += (size_t)256 * 4;
    int* dhist           = (int*)w;            w += (size_t)256 * 4;
    int* dcur            = (int*)w;            w += (size_t)256 * 4;
    int* perm            = (int*)w;            w += (size_t)NN * 4;
    int* csrc            = (int*)w;            w += (size_t)EE * 4;
    int* starts          = (int*)w;            w += (size_t)(GG + 1) * 4;

    const int* srcI = ei;
    const int* dstI = ei + EE;

    // CSR over dst (reused by all 3 layers) + degree-sorted perm + weight prep
    hipMemsetAsync(counts, 0, (size_t)NN * 4, stream);
    hipMemsetAsync(dhist, 0, 256 * 4, stream);
    hipMemsetAsync(dcur, 0, 256 * 4, stream);
    hist_kernel<<<(EE + 255) / 256, 256, 0, stream>>>(dstI, counts);
    block_scan<<<SCB, 256, 0, stream>>>(counts, offsets, bsums);
    scan_sums<<<1, 256, 0, stream>>>(bsums);
    add_base<<<SCB, 256, 0, stream>>>(offsets, bsums);
    deg_hist<<<SCB, 256, 0, stream>>>(counts, dhist);
    deg_scan<<<1, 256, 0, stream>>>(dhist);
    deg_scatter<<<SCB, 256, 0, stream>>>(counts, dhist, dcur, perm);
    hipMemsetAsync(counts, 0, (size_t)NN * 4, stream);  // reuse as cursor
    scatter_kernel<<<(EE + 255) / 256, 256, 0, stream>>>(srcI, dstI, offsets, counts, csrc);
    starts_kernel<<<(NN + 256) / 256, 256, 0, stream>>>(batch, starts);
    prep_weights<<<dim3(12, 8), 256, 0, stream>>>(Wq, Wk, Wv, Ws, wtbh, wtbl);

    const float* xin = x;
    float* bufs[2] = {bufA, bufB};
    const int gemmBlocks = (NN + 63) / 64;   // 782
    const int attnBlocks = (NN + 31) / 32;   // 1563
    for (int l = 0; l < 3; ++l) {
        float* xs = bufs[l & 1];
        gemm_mfma<<<gemmBlocks, 256, 0, stream>>>(
            xin, wtbh + (size_t)l * 4 * 16384, wtbl + (size_t)l * 4 * 16384,
            bq + (size_t)l * 128, bk + (size_t)l * 128,
            bv + (size_t)l * 128, bs + (size_t)l * 128,
            qb, kvb, xs);
        attn_kernel<<<attnBlocks, 256, 0, stream>>>(qb, (const uint4*)kvb, xs, offsets, csrc, perm);
        xin = xs;
    }

    pool_partial<<<GG * PCH, 128, 0, stream>>>(xin, wg, bg, starts, psum, pmax);
    pool_final<<<GG, 128, 0, stream>>>(psum, pmax, out);
}

// Round 9
// 550.668 us; speedup vs baseline: 1.4902x; 1.4902x over previous
//
#include <hip/hip_runtime.h>
#include <hip/hip_bf16.h>

#define NN 50000
#define EE 800000
#define GG 64
#define PCH 16   // pooling chunks per graph
#define SCB ((NN + 255) / 256)   // 196 scan blocks
// D=128, H=8, C=16, L=3

typedef __attribute__((ext_vector_type(8)))  short          s16x8;
typedef __attribute__((ext_vector_type(8)))  unsigned short u16x8;
typedef __attribute__((ext_vector_type(16))) float          f32x16;

// bf16 helpers (bit-pattern based)
union BFU { __hip_bfloat16 h; unsigned short u; };
__device__ __forceinline__ unsigned short f2bf(float f) {
    BFU b; b.h = __float2bfloat16(f); return b.u;
}
#define B2F_LO(u) __uint_as_float((u) << 16)
#define B2F_HI(u) __uint_as_float((u) & 0xffff0000u)
#define BF2F(us)  __uint_as_float(((unsigned)(us)) << 16)

// ---------------------------------------------------------------- CSR build
__global__ __launch_bounds__(256) void hist_kernel(const int* __restrict__ dst,
                                                   int* __restrict__ counts) {
    int e = blockIdx.x * 256 + threadIdx.x;
    if (e < EE) atomicAdd(&counts[dst[e]], 1);
}

__global__ __launch_bounds__(256)
void block_scan(const int* __restrict__ counts, int* __restrict__ offsets,
                int* __restrict__ bsums) {
    __shared__ int sm[256];
    const int t = threadIdx.x;
    const int i = blockIdx.x * 256 + t;
    const int v = (i < NN) ? counts[i] : 0;
    sm[t] = v;
    __syncthreads();
    for (int off = 1; off < 256; off <<= 1) {
        int val = (t >= off) ? sm[t - off] : 0;
        __syncthreads();
        sm[t] += val;
        __syncthreads();
    }
    if (i < NN) offsets[i] = sm[t] - v;      // exclusive
    if (t == 255) bsums[blockIdx.x] = sm[255];
}

__global__ __launch_bounds__(256)
void scan_sums(int* __restrict__ bsums) {   // in-place -> exclusive block bases
    __shared__ int sm[256];
    const int t = threadIdx.x;
    const int v = (t < SCB) ? bsums[t] : 0;
    sm[t] = v;
    __syncthreads();
    for (int off = 1; off < 256; off <<= 1) {
        int val = (t >= off) ? sm[t - off] : 0;
        __syncthreads();
        sm[t] += val;
        __syncthreads();
    }
    if (t < SCB) bsums[t] = sm[t] - v;       // exclusive base
}

__global__ __launch_bounds__(256)
void add_base(int* __restrict__ offsets, const int* __restrict__ bsums) {
    const int i = blockIdx.x * 256 + threadIdx.x;
    if (i < NN) offsets[i] += bsums[blockIdx.x];
    if (i == 0) offsets[NN] = EE;            // total edges is a constant
}

__global__ __launch_bounds__(256) void scatter_kernel(const int* __restrict__ src,
                                                      const int* __restrict__ dst,
                                                      const int* __restrict__ offs,
                                                      int* __restrict__ cursor,
                                                      int* __restrict__ csrc) {
    int e = blockIdx.x * 256 + threadIdx.x;
    if (e < EE) {
        int dn = dst[e];
        int p = atomicAdd(&cursor[dn], 1);
        csrc[offs[dn] + p] = src[e];
    }
}

__global__ __launch_bounds__(256) void starts_kernel(const int* __restrict__ batch,
                                                     int* __restrict__ starts) {
    int i = blockIdx.x * 256 + threadIdx.x;
    if (i > NN) return;
    int b  = (i < NN) ? batch[i] : GG;
    int bp = (i == 0) ? -1 : batch[i - 1];
    for (int g = bp + 1; g <= b && g <= GG; ++g) starts[g] = i;
}

// ---- degree-sorted node permutation (kills degree divergence in attn) ----
// LDS-aggregated counting sort: global atomics reduced from 1/node to
// 1/(block,bin) — the round-8 versions serialized 50k atomics on ~40 hot
// bin addresses (139us each at 0.01% VALUBusy).
__global__ __launch_bounds__(256)
void deg_hist(const int* __restrict__ counts, int* __restrict__ dhist) {
    __shared__ int lh[256];
    const int t = threadIdx.x;
    lh[t] = 0;
    __syncthreads();
    const int i = blockIdx.x * 256 + t;
    if (i < NN) atomicAdd(&lh[min(counts[i], 255)], 1);
    __syncthreads();
    if (lh[t]) atomicAdd(&dhist[t], lh[t]);
}

__global__ __launch_bounds__(256)
void deg_scan(int* __restrict__ dhist) {     // in-place -> exclusive bases
    __shared__ int sm[256];
    const int t = threadIdx.x;
    const int v = dhist[t];
    sm[t] = v;
    __syncthreads();
    for (int off = 1; off < 256; off <<= 1) {
        int val = (t >= off) ? sm[t - off] : 0;
        __syncthreads();
        sm[t] += val;
        __syncthreads();
    }
    dhist[t] = sm[t] - v;                    // exclusive base
}

__global__ __launch_bounds__(256)
void deg_scatter(const int* __restrict__ counts, const int* __restrict__ dbase,
                 int* __restrict__ dcur, int* __restrict__ perm) {
    __shared__ int lh[256];   // per-bin count in this block (then reused as rank src)
    __shared__ int lb[256];   // this block's reserved chunk base within bin
    const int t = threadIdx.x;
    lh[t] = 0;
    __syncthreads();
    const int i = blockIdx.x * 256 + t;
    int d = 0, r = 0;
    if (i < NN) {
        d = min(counts[i], 255);
        r = atomicAdd(&lh[d], 1);            // rank within block (LDS speed)
    }
    __syncthreads();
    if (lh[t]) lb[t] = atomicAdd(&dcur[t], lh[t]);   // one global atomic per bin
    __syncthreads();
    if (i < NN) perm[dbase[d] + lb[d] + r] = i;
}

// ---------------------------------------------------------------- weight prep
__global__ __launch_bounds__(256)
void prep_weights(const float* __restrict__ Wq, const float* __restrict__ Wk,
                  const float* __restrict__ Wv, const float* __restrict__ Ws,
                  unsigned short* __restrict__ wtbh, unsigned short* __restrict__ wtbl) {
    const int mat = blockIdx.x;           // 0..11
    const int l = mat >> 2, m = mat & 3;
    const float* W;
    switch (m) {
        case 0:  W = Wq; break;
        case 1:  W = Wk; break;
        case 2:  W = Wv; break;
        default: W = Ws; break;
    }
    W += (size_t)l * 16384;
    const int t = threadIdx.x;
    const int col = blockIdx.y * 16 + (t >> 4);
    const int kb  = (t & 15) * 8;
    u16x8 hi, lo;
    #pragma unroll
    for (int j = 0; j < 8; ++j) {
        float w = W[(kb + j) * 128 + col];
        unsigned short uh = f2bf(w);
        hi[j] = uh;
        lo[j] = f2bf(w - BF2F(uh));
    }
    const size_t o = (size_t)mat * 16384 + col * 128 + kb;
    *(u16x8*)(wtbh + o) = hi;
    *(u16x8*)(wtbl + o) = lo;
}

// ---------------------------------------------------------------- MFMA GEMM (split-bf16)
__global__ __launch_bounds__(256, 2)
void gemm_mfma(const float* __restrict__ xin,
               const unsigned short* __restrict__ wHg,   // + l*4*16384
               const unsigned short* __restrict__ wLg,
               const float* __restrict__ bq, const float* __restrict__ bk,
               const float* __restrict__ bv, const float* __restrict__ bs,
               float* __restrict__ q, unsigned short* __restrict__ kvb,
               float* __restrict__ xs) {
    __shared__ unsigned short xl[16384];   // [0..8191]=hi, [8192..]=lo
    __shared__ unsigned short wsm[16384];
    const int t = threadIdx.x;
    const int n0 = blockIdx.x * 64;

    // ---- stage x (fp32 -> split bf16, swizzled) ----
    const float4* X4 = (const float4*)xin;
    for (int i = t; i < 1024; i += 256) {            // 64 rows x 16 chunks
        const int row = i >> 4, ch = i & 15;
        const int node = n0 + row;
        float4 fa = make_float4(0.f, 0.f, 0.f, 0.f);
        float4 fb = make_float4(0.f, 0.f, 0.f, 0.f);
        if (node < NN) { fa = X4[node * 32 + ch * 2]; fb = X4[node * 32 + ch * 2 + 1]; }
        const float fv[8] = {fa.x, fa.y, fa.z, fa.w, fb.x, fb.y, fb.z, fb.w};
        u16x8 hi, lo;
        #pragma unroll
        for (int j = 0; j < 8; ++j) {
            unsigned short uh = f2bf(fv[j]);
            hi[j] = uh;
            lo[j] = f2bf(fv[j] - BF2F(uh));
        }
        const int base = row * 128 + (ch ^ (row & 7)) * 8;
        *(u16x8*)&xl[base] = hi;
        *(u16x8*)&xl[8192 + base] = lo;
    }
    __syncthreads();

    // ---- per-wave tile & A-fragments (held in regs for all 4 matrices) ----
    const int lane = t & 63, wid = t >> 6;
    const int r = lane & 31, g = lane >> 5;
    const int nt = (wid & 1) * 32;        // node offset in tile
    const int cb = (wid >> 1) * 64;       // col base
    s16x8 ah[8], al[8];
    {
        const int row = nt + r;
        const int s = row & 7;
        const int rb = row * 128;
        #pragma unroll
        for (int kc = 0; kc < 8; ++kc) {
            const int idx = rb + (((kc << 1) | g) ^ s) * 8;
            ah[kc] = *(const s16x8*)&xl[idx];
            al[kc] = *(const s16x8*)&xl[8192 + idx];
        }
    }
    const int col0 = cb + r, col1 = cb + 32 + r;
    const int wb0 = col0 * 128, ws0 = col0 & 7;
    const int wb1 = col1 * 128, ws1 = col1 & 7;

    for (int m = 0; m < 4; ++m) {
        f32x16 acc0, acc1;
        #pragma unroll
        for (int j = 0; j < 16; ++j) { acc0[j] = 0.f; acc1[j] = 0.f; }

        #pragma unroll
        for (int part = 0; part < 2; ++part) {
            __syncthreads();
            const u16x8* Wg = (const u16x8*)((part == 0 ? wHg : wLg) + m * 16384);
            for (int i = t; i < 2048; i += 256) {    // 128 rows x 16 chunks
                const int row = i >> 4, ch = i & 15;
                *(u16x8*)&wsm[row * 128 + (ch ^ (row & 7)) * 8] = Wg[i];
            }
            __syncthreads();
            #pragma unroll
            for (int kc = 0; kc < 8; ++kc) {
                const s16x8 b0 = *(const s16x8*)&wsm[wb0 + (((kc << 1) | g) ^ ws0) * 8];
                const s16x8 b1 = *(const s16x8*)&wsm[wb1 + (((kc << 1) | g) ^ ws1) * 8];
                acc0 = __builtin_amdgcn_mfma_f32_32x32x16_bf16(ah[kc], b0, acc0, 0, 0, 0);
                acc1 = __builtin_amdgcn_mfma_f32_32x32x16_bf16(ah[kc], b1, acc1, 0, 0, 0);
                if (part == 0) {
                    acc0 = __builtin_amdgcn_mfma_f32_32x32x16_bf16(al[kc], b0, acc0, 0, 0, 0);
                    acc1 = __builtin_amdgcn_mfma_f32_32x32x16_bf16(al[kc], b1, acc1, 0, 0, 0);
                }
            }
        }

        // ---- epilogue ----
        const float* bp;
        switch (m) {
            case 0:  bp = bq; break;
            case 1:  bp = bk; break;
            case 2:  bp = bv; break;
            default: bp = bs; break;
        }
        const float b0 = bp[col0], b1 = bp[col1];
        if (m == 0 || m == 3) {
            float* outp = (m == 0) ? q : xs;
            #pragma unroll
            for (int reg = 0; reg < 16; ++reg) {
                const int node = n0 + nt + (reg & 3) + 8 * (reg >> 2) + 4 * g;
                if (node < NN) {
                    outp[node * 128 + col0] = acc0[reg] + b0;
                    outp[node * 128 + col1] = acc1[reg] + b1;
                }
            }
        } else {
            const int koff = (m == 1) ? 0 : 16;      // k at +0, v at +16 (ushorts)
            const int o0 = (col0 >> 4) * 32 + koff + (col0 & 15);
            const int o1 = (col1 >> 4) * 32 + koff + (col1 & 15);
            #pragma unroll
            for (int reg = 0; reg < 16; ++reg) {
                const int node = n0 + nt + (reg & 3) + 8 * (reg >> 2) + 4 * g;
                if (node < NN) {
                    kvb[(size_t)node * 256 + o0] = f2bf(acc0[reg] + b0);
                    kvb[(size_t)node * 256 + o1] = f2bf(acc1[reg] + b1);
                }
            }
        }
    }
}

// ---------------------------------------------------------------- attention (CSR, online softmax)
// thread = (perm'd node, head); degree-sorted perm makes the 8 groups of a
// wave have near-equal trip counts (removes ~36% exec-mask waste).
__global__ __launch_bounds__(256)
void attn_kernel(const float* __restrict__ q, const uint4* __restrict__ kv4,
                 float* __restrict__ xio,
                 const int* __restrict__ offs, const int* __restrict__ csrc,
                 const int* __restrict__ perm) {
    const int t = threadIdx.x;
    const int h = t & 7;
    const int idx = blockIdx.x * 32 + (t >> 3);
    if (idx >= NN) return;
    const int n = perm[idx];
    const float4* qp = (const float4*)(q + n * 128 + h * 16);
    const float4 q0 = qp[0], q1 = qp[1], q2 = qp[2], q3 = qp[3];
    float m = -__builtin_inff();
    float d = 0.f;
    float4 a0 = {}, a1 = {}, a2 = {}, a3 = {};
    const int e0 = offs[n], e1 = offs[n + 1];
    for (int e = e0; e < e1; ++e) {
        const int s = csrc[e];
        const uint4* kvp = kv4 + (size_t)s * 32 + h * 4;   // 512B row, 64B per head
        const uint4 ka = kvp[0], kb = kvp[1];              // k: 16 bf16
        float dot =
            q0.x * B2F_LO(ka.x) + q0.y * B2F_HI(ka.x) + q0.z * B2F_LO(ka.y) + q0.w * B2F_HI(ka.y)
          + q1.x * B2F_LO(ka.z) + q1.y * B2F_HI(ka.z) + q1.z * B2F_LO(ka.w) + q1.w * B2F_HI(ka.w)
          + q2.x * B2F_LO(kb.x) + q2.y * B2F_HI(kb.x) + q2.z * B2F_LO(kb.y) + q2.w * B2F_HI(kb.y)
          + q3.x * B2F_LO(kb.z) + q3.y * B2F_HI(kb.z) + q3.z * B2F_LO(kb.w) + q3.w * B2F_HI(kb.w);
        const float alpha = dot * 0.25f;                   // / sqrt(C=16)
        const float nm = fmaxf(m, alpha);
        const float scale = __expf(m - nm);                // 0 on first edge
        const float p = __expf(alpha - nm);
        d = d * scale + p;
        const uint4 va = kvp[2], vb = kvp[3];              // v: 16 bf16
        a0.x = a0.x * scale + p * B2F_LO(va.x); a0.y = a0.y * scale + p * B2F_HI(va.x);
        a0.z = a0.z * scale + p * B2F_LO(va.y); a0.w = a0.w * scale + p * B2F_HI(va.y);
        a1.x = a1.x * scale + p * B2F_LO(va.z); a1.y = a1.y * scale + p * B2F_HI(va.z);
        a1.z = a1.z * scale + p * B2F_LO(va.w); a1.w = a1.w * scale + p * B2F_HI(va.w);
        a2.x = a2.x * scale + p * B2F_LO(vb.x); a2.y = a2.y * scale + p * B2F_HI(vb.x);
        a2.z = a2.z * scale + p * B2F_LO(vb.y); a2.w = a2.w * scale + p * B2F_HI(vb.y);
        a3.x = a3.x * scale + p * B2F_LO(vb.z); a3.y = a3.y * scale + p * B2F_HI(vb.z);
        a3.z = a3.z * scale + p * B2F_LO(vb.w); a3.w = a3.w * scale + p * B2F_HI(vb.w);
        m = nm;
    }
    const float inv = 1.f / (d + 1e-16f);
    float4* op = (float4*)(xio + n * 128 + h * 16);
    float4 o0 = op[0], o1 = op[1], o2 = op[2], o3 = op[3];
    o0.x += a0.x * inv; o0.y += a0.y * inv; o0.z += a0.z * inv; o0.w += a0.w * inv;
    o1.x += a1.x * inv; o1.y += a1.y * inv; o1.z += a1.z * inv; o1.w += a1.w * inv;
    o2.x += a2.x * inv; o2.y += a2.y * inv; o2.z += a2.z * inv; o2.w += a2.w * inv;
    o3.x += a3.x * inv; o3.y += a3.y * inv; o3.z += a3.z * inv; o3.w += a3.w * inv;
    op[0] = o0; op[1] = o1; op[2] = o2; op[3] = o3;
}

// ---------------------------------------------------------------- readout (2-phase, fused gate)
__global__ __launch_bounds__(128)
void pool_partial(const float* __restrict__ x, const float* __restrict__ wg,
                  const float* __restrict__ bg, const int* __restrict__ starts,
                  float* __restrict__ psum, float* __restrict__ pmax) {
    const int g  = blockIdx.x / PCH;
    const int ch = blockIdx.x % PCH;
    const int c  = threadIdx.x;
    const int s0 = starts[g], s1 = starts[g + 1];
    const int total = s1 - s0;
    const int len = (total + PCH - 1) / PCH;
    const int n0 = s0 + ch * len;
    const int n1 = min(n0 + len, s1);
    const float w = wg[c];
    const float b = bg[0];
    __shared__ float red[2];
    float sum = 0.f, mx = -__builtin_inff();
    for (int n = n0; n < n1; ++n) {
        const float xv = x[n * 128 + c];
        float p = xv * w;
        #pragma unroll
        for (int o = 32; o; o >>= 1) p += __shfl_xor(p, o);
        if ((c & 63) == 0) red[c >> 6] = p;
        __syncthreads();
        const float dot = red[0] + red[1];
        __syncthreads();
        const float score = 1.f / (1.f + __expf(-(dot + b)));
        sum += score * xv;
        mx = fmaxf(mx, xv);
    }
    psum[blockIdx.x * 128 + c] = sum;
    pmax[blockIdx.x * 128 + c] = mx;
}

__global__ __launch_bounds__(128)
void pool_final(const float* __restrict__ psum, const float* __restrict__ pmax,
                float* __restrict__ out) {
    const int g = blockIdx.x, c = threadIdx.x;
    float s = 0.f, m = -__builtin_inff();
    #pragma unroll
    for (int ch = 0; ch < PCH; ++ch) {
        s += psum[(g * PCH + ch) * 128 + c];
        m = fmaxf(m, pmax[(g * PCH + ch) * 128 + c]);
    }
    out[g * 256 + c] = s;
    out[g * 256 + 128 + c] = m;
}

// ---------------------------------------------------------------- launch
extern "C" void kernel_launch(void* const* d_in, const int* in_sizes, int n_in,
                              void* d_out, int out_size, void* d_ws, size_t ws_size,
                              hipStream_t stream) {
    const float* x     = (const float*)d_in[0];
    const int*   ei    = (const int*)d_in[1];
    const int*   batch = (const int*)d_in[2];
    const float* Wq = (const float*)d_in[3];
    const float* bq = (const float*)d_in[4];
    const float* Wk = (const float*)d_in[5];
    const float* bk = (const float*)d_in[6];
    const float* Wv = (const float*)d_in[7];
    const float* bv = (const float*)d_in[8];
    const float* Ws = (const float*)d_in[9];
    const float* bs = (const float*)d_in[10];
    const float* wg = (const float*)d_in[11];
    const float* bg = (const float*)d_in[12];
    float* out = (float*)d_out;

    char* w = (char*)d_ws;
    float* qb            = (float*)w;          w += (size_t)NN * 128 * 4;
    unsigned short* kvb  = (unsigned short*)w; w += (size_t)NN * 256 * 2;
    float* bufA          = (float*)w;          w += (size_t)NN * 128 * 4;
    float* bufB          = (float*)w;          w += (size_t)NN * 128 * 4;
    float* psum          = (float*)w;          w += (size_t)GG * PCH * 128 * 4;
    float* pmax          = (float*)w;          w += (size_t)GG * PCH * 128 * 4;
    unsigned short* wtbh = (unsigned short*)w; w += (size_t)12 * 16384 * 2;
    unsigned short* wtbl = (unsigned short*)w; w += (size_t)12 * 16384 * 2;
    int* counts          = (int*)w;            w += (size_t)NN * 4;
    int* offsets         = (int*)w;            w += (size_t)(NN + 1) * 4;
    int* bsums           = (int*)w;            w += (size_t)256 * 4;
    int* dhist           = (int*)w;            w += (size_t)256 * 4;
    int* dcur            = (int*)w;            w += (size_t)256 * 4;
    int* perm            = (int*)w;            w += (size_t)NN * 4;
    int* csrc            = (int*)w;            w += (size_t)EE * 4;
    int* starts          = (int*)w;            w += (size_t)(GG + 1) * 4;

    const int* srcI = ei;
    const int* dstI = ei + EE;

    // CSR over dst (reused by all 3 layers) + degree-sorted perm + weight prep
    hipMemsetAsync(counts, 0, (size_t)NN * 4, stream);
    hipMemsetAsync(dhist, 0, 256 * 4, stream);
    hipMemsetAsync(dcur, 0, 256 * 4, stream);
    hist_kernel<<<(EE + 255) / 256, 256, 0, stream>>>(dstI, counts);
    block_scan<<<SCB, 256, 0, stream>>>(counts, offsets, bsums);
    scan_sums<<<1, 256, 0, stream>>>(bsums);
    add_base<<<SCB, 256, 0, stream>>>(offsets, bsums);
    deg_hist<<<SCB, 256, 0, stream>>>(counts, dhist);
    deg_scan<<<1, 256, 0, stream>>>(dhist);
    deg_scatter<<<SCB, 256, 0, stream>>>(counts, dhist, dcur, perm);
    hipMemsetAsync(counts, 0, (size_t)NN * 4, stream);  // reuse as cursor
    scatter_kernel<<<(EE + 255) / 256, 256, 0, stream>>>(srcI, dstI, offsets, counts, csrc);
    starts_kernel<<<(NN + 256) / 256, 256, 0, stream>>>(batch, starts);
    prep_weights<<<dim3(12, 8), 256, 0, stream>>>(Wq, Wk, Wv, Ws, wtbh, wtbl);

    const float* xin = x;
    float* bufs[2] = {bufA, bufB};
    const int gemmBlocks = (NN + 63) / 64;   // 782
    const int attnBlocks = (NN + 31) / 32;   // 1563
    for (int l = 0; l < 3; ++l) {
        float* xs = bufs[l & 1];
        gemm_mfma<<<gemmBlocks, 256, 0, stream>>>(
            xin, wtbh + (size_t)l * 4 * 16384, wtbl + (size_t)l * 4 * 16384,
            bq + (size_t)l * 128, bk + (size_t)l * 128,
            bv + (size_t)l * 128, bs + (size_t)l * 128,
            qb, kvb, xs);
        attn_kernel<<<attnBlocks, 256, 0, stream>>>(qb, (const uint4*)kvb, xs, offsets, csrc, perm);
        xin = xs;
    }

    pool_partial<<<GG * PCH, 128, 0, stream>>>(xin, wg, bg, starts, psum, pmax);
    pool_final<<<GG, 128, 0, stream>>>(psum, pmax, out);
}

// Round 10
// 525.178 us; speedup vs baseline: 1.5625x; 1.0485x over previous
//
#include <hip/hip_runtime.h>
#include <hip/hip_bf16.h>

#define NN 50000
#define EE 800000
#define GG 64
#define PCH 16   // pooling chunks per graph
#define SCB ((NN + 255) / 256)   // 196 scan blocks
// D=128, H=8, C=16, L=3

typedef __attribute__((ext_vector_type(8)))  short          s16x8;
typedef __attribute__((ext_vector_type(8)))  unsigned short u16x8;
typedef __attribute__((ext_vector_type(16))) float          f32x16;

// bf16 helpers (bit-pattern based)
union BFU { __hip_bfloat16 h; unsigned short u; };
__device__ __forceinline__ unsigned short f2bf(float f) {
    BFU b; b.h = __float2bfloat16(f); return b.u;
}
#define B2F_LO(u) __uint_as_float((u) << 16)
#define B2F_HI(u) __uint_as_float((u) & 0xffff0000u)
#define BF2F(us)  __uint_as_float(((unsigned)(us)) << 16)

// ---------------------------------------------------------------- CSR build
__global__ __launch_bounds__(256) void hist_kernel(const int* __restrict__ dst,
                                                   int* __restrict__ counts) {
    int e = blockIdx.x * 256 + threadIdx.x;
    if (e < EE) atomicAdd(&counts[dst[e]], 1);
}

__global__ __launch_bounds__(256)
void block_scan(const int* __restrict__ counts, int* __restrict__ offsets,
                int* __restrict__ bsums) {
    __shared__ int sm[256];
    const int t = threadIdx.x;
    const int i = blockIdx.x * 256 + t;
    const int v = (i < NN) ? counts[i] : 0;
    sm[t] = v;
    __syncthreads();
    for (int off = 1; off < 256; off <<= 1) {
        int val = (t >= off) ? sm[t - off] : 0;
        __syncthreads();
        sm[t] += val;
        __syncthreads();
    }
    if (i < NN) offsets[i] = sm[t] - v;      // exclusive
    if (t == 255) bsums[blockIdx.x] = sm[255];
}

__global__ __launch_bounds__(256)
void scan_sums(int* __restrict__ bsums) {   // in-place -> exclusive block bases
    __shared__ int sm[256];
    const int t = threadIdx.x;
    const int v = (t < SCB) ? bsums[t] : 0;
    sm[t] = v;
    __syncthreads();
    for (int off = 1; off < 256; off <<= 1) {
        int val = (t >= off) ? sm[t - off] : 0;
        __syncthreads();
        sm[t] += val;
        __syncthreads();
    }
    if (t < SCB) bsums[t] = sm[t] - v;       // exclusive base
}

__global__ __launch_bounds__(256)
void add_base(int* __restrict__ offsets, const int* __restrict__ bsums) {
    const int i = blockIdx.x * 256 + threadIdx.x;
    if (i < NN) offsets[i] += bsums[blockIdx.x];
    if (i == 0) offsets[NN] = EE;            // total edges is a constant
}

__global__ __launch_bounds__(256) void scatter_kernel(const int* __restrict__ src,
                                                      const int* __restrict__ dst,
                                                      const int* __restrict__ offs,
                                                      int* __restrict__ cursor,
                                                      int* __restrict__ csrc) {
    int e = blockIdx.x * 256 + threadIdx.x;
    if (e < EE) {
        int dn = dst[e];
        int p = atomicAdd(&cursor[dn], 1);
        csrc[offs[dn] + p] = src[e];
    }
}

__global__ __launch_bounds__(256) void starts_kernel(const int* __restrict__ batch,
                                                     int* __restrict__ starts) {
    int i = blockIdx.x * 256 + threadIdx.x;
    if (i > NN) return;
    int b  = (i < NN) ? batch[i] : GG;
    int bp = (i == 0) ? -1 : batch[i - 1];
    for (int g = bp + 1; g <= b && g <= GG; ++g) starts[g] = i;
}

// ---- degree-sorted node permutation (equalizes trip counts per wave) ----
__global__ __launch_bounds__(256)
void deg_hist(const int* __restrict__ counts, int* __restrict__ dhist) {
    __shared__ int lh[256];
    const int t = threadIdx.x;
    lh[t] = 0;
    __syncthreads();
    const int i = blockIdx.x * 256 + t;
    if (i < NN) atomicAdd(&lh[min(counts[i], 255)], 1);
    __syncthreads();
    if (lh[t]) atomicAdd(&dhist[t], lh[t]);
}

__global__ __launch_bounds__(256)
void deg_scan(int* __restrict__ dhist) {     // in-place -> exclusive bases
    __shared__ int sm[256];
    const int t = threadIdx.x;
    const int v = dhist[t];
    sm[t] = v;
    __syncthreads();
    for (int off = 1; off < 256; off <<= 1) {
        int val = (t >= off) ? sm[t - off] : 0;
        __syncthreads();
        sm[t] += val;
        __syncthreads();
    }
    dhist[t] = sm[t] - v;                    // exclusive base
}

__global__ __launch_bounds__(256)
void deg_scatter(const int* __restrict__ counts, const int* __restrict__ dbase,
                 int* __restrict__ dcur, int* __restrict__ perm) {
    __shared__ int lh[256];   // per-bin count in this block
    __shared__ int lb[256];   // block's reserved chunk base within bin
    const int t = threadIdx.x;
    lh[t] = 0;
    __syncthreads();
    const int i = blockIdx.x * 256 + t;
    int d = 0, r = 0;
    if (i < NN) {
        d = min(counts[i], 255);
        r = atomicAdd(&lh[d], 1);            // rank within block (LDS speed)
    }
    __syncthreads();
    if (lh[t]) lb[t] = atomicAdd(&dcur[t], lh[t]);   // one global atomic per bin
    __syncthreads();
    if (i < NN) perm[dbase[d] + lb[d] + r] = i;
}

// ---------------------------------------------------------------- weight prep
__global__ __launch_bounds__(256)
void prep_weights(const float* __restrict__ Wq, const float* __restrict__ Wk,
                  const float* __restrict__ Wv, const float* __restrict__ Ws,
                  unsigned short* __restrict__ wtbh, unsigned short* __restrict__ wtbl) {
    const int mat = blockIdx.x;           // 0..11
    const int l = mat >> 2, m = mat & 3;
    const float* W;
    switch (m) {
        case 0:  W = Wq; break;
        case 1:  W = Wk; break;
        case 2:  W = Wv; break;
        default: W = Ws; break;
    }
    W += (size_t)l * 16384;
    const int t = threadIdx.x;
    const int col = blockIdx.y * 16 + (t >> 4);
    const int kb  = (t & 15) * 8;
    u16x8 hi, lo;
    #pragma unroll
    for (int j = 0; j < 8; ++j) {
        float w = W[(kb + j) * 128 + col];
        unsigned short uh = f2bf(w);
        hi[j] = uh;
        lo[j] = f2bf(w - BF2F(uh));
    }
    const size_t o = (size_t)mat * 16384 + col * 128 + kb;
    *(u16x8*)(wtbh + o) = hi;
    *(u16x8*)(wtbl + o) = lo;
}

// ---------------------------------------------------------------- MFMA GEMM (split-bf16)
__global__ __launch_bounds__(256, 2)
void gemm_mfma(const float* __restrict__ xin,
               const unsigned short* __restrict__ wHg,   // + l*4*16384
               const unsigned short* __restrict__ wLg,
               const float* __restrict__ bq, const float* __restrict__ bk,
               const float* __restrict__ bv, const float* __restrict__ bs,
               float* __restrict__ q, unsigned short* __restrict__ kvb,
               float* __restrict__ xs) {
    __shared__ unsigned short xl[16384];   // [0..8191]=hi, [8192..]=lo
    __shared__ unsigned short wsm[16384];
    const int t = threadIdx.x;
    const int n0 = blockIdx.x * 64;

    // ---- stage x (fp32 -> split bf16, swizzled) ----
    const float4* X4 = (const float4*)xin;
    for (int i = t; i < 1024; i += 256) {            // 64 rows x 16 chunks
        const int row = i >> 4, ch = i & 15;
        const int node = n0 + row;
        float4 fa = make_float4(0.f, 0.f, 0.f, 0.f);
        float4 fb = make_float4(0.f, 0.f, 0.f, 0.f);
        if (node < NN) { fa = X4[node * 32 + ch * 2]; fb = X4[node * 32 + ch * 2 + 1]; }
        const float fv[8] = {fa.x, fa.y, fa.z, fa.w, fb.x, fb.y, fb.z, fb.w};
        u16x8 hi, lo;
        #pragma unroll
        for (int j = 0; j < 8; ++j) {
            unsigned short uh = f2bf(fv[j]);
            hi[j] = uh;
            lo[j] = f2bf(fv[j] - BF2F(uh));
        }
        const int base = row * 128 + (ch ^ (row & 7)) * 8;
        *(u16x8*)&xl[base] = hi;
        *(u16x8*)&xl[8192 + base] = lo;
    }
    __syncthreads();

    // ---- per-wave tile & A-fragments (held in regs for all 4 matrices) ----
    const int lane = t & 63, wid = t >> 6;
    const int r = lane & 31, g = lane >> 5;
    const int nt = (wid & 1) * 32;        // node offset in tile
    const int cb = (wid >> 1) * 64;       // col base
    s16x8 ah[8], al[8];
    {
        const int row = nt + r;
        const int s = row & 7;
        const int rb = row * 128;
        #pragma unroll
        for (int kc = 0; kc < 8; ++kc) {
            const int idx = rb + (((kc << 1) | g) ^ s) * 8;
            ah[kc] = *(const s16x8*)&xl[idx];
            al[kc] = *(const s16x8*)&xl[8192 + idx];
        }
    }
    const int col0 = cb + r, col1 = cb + 32 + r;
    const int wb0 = col0 * 128, ws0 = col0 & 7;
    const int wb1 = col1 * 128, ws1 = col1 & 7;

    for (int m = 0; m < 4; ++m) {
        f32x16 acc0, acc1;
        #pragma unroll
        for (int j = 0; j < 16; ++j) { acc0[j] = 0.f; acc1[j] = 0.f; }

        #pragma unroll
        for (int part = 0; part < 2; ++part) {
            __syncthreads();
            const u16x8* Wg = (const u16x8*)((part == 0 ? wHg : wLg) + m * 16384);
            for (int i = t; i < 2048; i += 256) {    // 128 rows x 16 chunks
                const int row = i >> 4, ch = i & 15;
                *(u16x8*)&wsm[row * 128 + (ch ^ (row & 7)) * 8] = Wg[i];
            }
            __syncthreads();
            #pragma unroll
            for (int kc = 0; kc < 8; ++kc) {
                const s16x8 b0 = *(const s16x8*)&wsm[wb0 + (((kc << 1) | g) ^ ws0) * 8];
                const s16x8 b1 = *(const s16x8*)&wsm[wb1 + (((kc << 1) | g) ^ ws1) * 8];
                acc0 = __builtin_amdgcn_mfma_f32_32x32x16_bf16(ah[kc], b0, acc0, 0, 0, 0);
                acc1 = __builtin_amdgcn_mfma_f32_32x32x16_bf16(ah[kc], b1, acc1, 0, 0, 0);
                if (part == 0) {
                    acc0 = __builtin_amdgcn_mfma_f32_32x32x16_bf16(al[kc], b0, acc0, 0, 0, 0);
                    acc1 = __builtin_amdgcn_mfma_f32_32x32x16_bf16(al[kc], b1, acc1, 0, 0, 0);
                }
            }
        }

        // ---- epilogue ----
        const float* bp;
        switch (m) {
            case 0:  bp = bq; break;
            case 1:  bp = bk; break;
            case 2:  bp = bv; break;
            default: bp = bs; break;
        }
        const float b0 = bp[col0], b1 = bp[col1];
        if (m == 0 || m == 3) {
            float* outp = (m == 0) ? q : xs;
            #pragma unroll
            for (int reg = 0; reg < 16; ++reg) {
                const int node = n0 + nt + (reg & 3) + 8 * (reg >> 2) + 4 * g;
                if (node < NN) {
                    outp[node * 128 + col0] = acc0[reg] + b0;
                    outp[node * 128 + col1] = acc1[reg] + b1;
                }
            }
        } else {
            const int koff = (m == 1) ? 0 : 16;      // k at +0, v at +16 (ushorts)
            const int o0 = (col0 >> 4) * 32 + koff + (col0 & 15);
            const int o1 = (col1 >> 4) * 32 + koff + (col1 & 15);
            #pragma unroll
            for (int reg = 0; reg < 16; ++reg) {
                const int node = n0 + nt + (reg & 3) + 8 * (reg >> 2) + 4 * g;
                if (node < NN) {
                    kvb[(size_t)node * 256 + o0] = f2bf(acc0[reg] + b0);
                    kvb[(size_t)node * 256 + o1] = f2bf(acc1[reg] + b1);
                }
            }
        }
    }
}

// ---------------------------------------------------------------- attention (CSR, online softmax)
// thread = (node, head, edge-half): 16 threads/node. Doubles wave count and
// halves each thread's serial chain vs round 9 (latency-bound diagnosis).
// 1-edge-ahead software pipeline keeps ~8 loads in flight per thread.
// Half-streams merged exactly in the epilogue via __shfl_xor(.,8) (same wave;
// grid 3125*16 == 50000 exactly, so no inactive lanes).
__global__ __launch_bounds__(256)
void attn_kernel(const float* __restrict__ q, const uint4* __restrict__ kv4,
                 float* __restrict__ xio,
                 const int* __restrict__ offs, const int* __restrict__ csrc,
                 const int* __restrict__ perm) {
    const int t = threadIdx.x;
    const int h = t & 7;
    const int half = (t >> 3) & 1;
    const int idx = blockIdx.x * 16 + (t >> 4);
    const int n = perm[idx];
    const float4* qp = (const float4*)(q + n * 128 + h * 16);
    const float4 q0 = qp[0], q1 = qp[1], q2 = qp[2], q3 = qp[3];
    float m = -__builtin_inff();
    float d = 0.f;
    float4 a0 = {}, a1 = {}, a2 = {}, a3 = {};
    const int e0 = offs[n], e1 = offs[n + 1];
    const int e = e0 + half;
    if (e < e1) {
        const uint4* kvp = kv4 + (size_t)csrc[e] * 32 + h * 4;
        uint4 ka = kvp[0], kb = kvp[1], va = kvp[2], vb = kvp[3];
        for (int en = e + 2;; en += 2) {
            uint4 nka, nkb, nva, nvb;
            const bool more = (en < e1);
            if (more) {                                     // prefetch next edge
                const uint4* kvn = kv4 + (size_t)csrc[en] * 32 + h * 4;
                nka = kvn[0]; nkb = kvn[1]; nva = kvn[2]; nvb = kvn[3];
            }
            float dot =
                q0.x * B2F_LO(ka.x) + q0.y * B2F_HI(ka.x) + q0.z * B2F_LO(ka.y) + q0.w * B2F_HI(ka.y)
              + q1.x * B2F_LO(ka.z) + q1.y * B2F_HI(ka.z) + q1.z * B2F_LO(ka.w) + q1.w * B2F_HI(ka.w)
              + q2.x * B2F_LO(kb.x) + q2.y * B2F_HI(kb.x) + q2.z * B2F_LO(kb.y) + q2.w * B2F_HI(kb.y)
              + q3.x * B2F_LO(kb.z) + q3.y * B2F_HI(kb.z) + q3.z * B2F_LO(kb.w) + q3.w * B2F_HI(kb.w);
            const float alpha = dot * 0.25f;                // / sqrt(C=16)
            const float nm = fmaxf(m, alpha);
            const float scale = __expf(m - nm);             // 0 on first edge
            const float p = __expf(alpha - nm);
            d = d * scale + p;
            a0.x = a0.x * scale + p * B2F_LO(va.x); a0.y = a0.y * scale + p * B2F_HI(va.x);
            a0.z = a0.z * scale + p * B2F_LO(va.y); a0.w = a0.w * scale + p * B2F_HI(va.y);
            a1.x = a1.x * scale + p * B2F_LO(va.z); a1.y = a1.y * scale + p * B2F_HI(va.z);
            a1.z = a1.z * scale + p * B2F_LO(va.w); a1.w = a1.w * scale + p * B2F_HI(va.w);
            a2.x = a2.x * scale + p * B2F_LO(vb.x); a2.y = a2.y * scale + p * B2F_HI(vb.x);
            a2.z = a2.z * scale + p * B2F_LO(vb.y); a2.w = a2.w * scale + p * B2F_HI(vb.y);
            a3.x = a3.x * scale + p * B2F_LO(vb.z); a3.y = a3.y * scale + p * B2F_HI(vb.z);
            a3.z = a3.z * scale + p * B2F_LO(vb.w); a3.w = a3.w * scale + p * B2F_HI(vb.w);
            m = nm;
            if (!more) break;
            ka = nka; kb = nkb; va = nva; vb = nvb;
        }
    }
    // ---- merge the two half-streams (exact in fp32) ----
    const float mp = __shfl_xor(m, 8);
    const float dp = __shfl_xor(d, 8);
    const float mc = fmaxf(fmaxf(m, mp), -1e30f);  // -1e30 guard: deg-0 NaN
    const float s0 = __expf(m - mc);
    const float s1 = __expf(mp - mc);
    const float dc = d * s0 + dp * s1;
    float pa;
    pa = __shfl_xor(a0.x, 8); a0.x = a0.x * s0 + pa * s1;
    pa = __shfl_xor(a0.y, 8); a0.y = a0.y * s0 + pa * s1;
    pa = __shfl_xor(a0.z, 8); a0.z = a0.z * s0 + pa * s1;
    pa = __shfl_xor(a0.w, 8); a0.w = a0.w * s0 + pa * s1;
    pa = __shfl_xor(a1.x, 8); a1.x = a1.x * s0 + pa * s1;
    pa = __shfl_xor(a1.y, 8); a1.y = a1.y * s0 + pa * s1;
    pa = __shfl_xor(a1.z, 8); a1.z = a1.z * s0 + pa * s1;
    pa = __shfl_xor(a1.w, 8); a1.w = a1.w * s0 + pa * s1;
    pa = __shfl_xor(a2.x, 8); a2.x = a2.x * s0 + pa * s1;
    pa = __shfl_xor(a2.y, 8); a2.y = a2.y * s0 + pa * s1;
    pa = __shfl_xor(a2.z, 8); a2.z = a2.z * s0 + pa * s1;
    pa = __shfl_xor(a2.w, 8); a2.w = a2.w * s0 + pa * s1;
    pa = __shfl_xor(a3.x, 8); a3.x = a3.x * s0 + pa * s1;
    pa = __shfl_xor(a3.y, 8); a3.y = a3.y * s0 + pa * s1;
    pa = __shfl_xor(a3.z, 8); a3.z = a3.z * s0 + pa * s1;
    pa = __shfl_xor(a3.w, 8); a3.w = a3.w * s0 + pa * s1;
    if (half == 0) {
        const float inv = 1.f / (dc + 1e-16f);
        float4* op = (float4*)(xio + n * 128 + h * 16);
        float4 o0 = op[0], o1 = op[1], o2 = op[2], o3 = op[3];
        o0.x += a0.x * inv; o0.y += a0.y * inv; o0.z += a0.z * inv; o0.w += a0.w * inv;
        o1.x += a1.x * inv; o1.y += a1.y * inv; o1.z += a1.z * inv; o1.w += a1.w * inv;
        o2.x += a2.x * inv; o2.y += a2.y * inv; o2.z += a2.z * inv; o2.w += a2.w * inv;
        o3.x += a3.x * inv; o3.y += a3.y * inv; o3.z += a3.z * inv; o3.w += a3.w * inv;
        op[0] = o0; op[1] = o1; op[2] = o2; op[3] = o3;
    }
}

// ---------------------------------------------------------------- readout (2-phase, fused gate)
__global__ __launch_bounds__(128)
void pool_partial(const float* __restrict__ x, const float* __restrict__ wg,
                  const float* __restrict__ bg, const int* __restrict__ starts,
                  float* __restrict__ psum, float* __restrict__ pmax) {
    const int g  = blockIdx.x / PCH;
    const int ch = blockIdx.x % PCH;
    const int c  = threadIdx.x;
    const int s0 = starts[g], s1 = starts[g + 1];
    const int total = s1 - s0;
    const int len = (total + PCH - 1) / PCH;
    const int n0 = s0 + ch * len;
    const int n1 = min(n0 + len, s1);
    const float w = wg[c];
    const float b = bg[0];
    __shared__ float red[2];
    float sum = 0.f, mx = -__builtin_inff();
    for (int n = n0; n < n1; ++n) {
        const float xv = x[n * 128 + c];
        float p = xv * w;
        #pragma unroll
        for (int o = 32; o; o >>= 1) p += __shfl_xor(p, o);
        if ((c & 63) == 0) red[c >> 6] = p;
        __syncthreads();
        const float dot = red[0] + red[1];
        __syncthreads();
        const float score = 1.f / (1.f + __expf(-(dot + b)));
        sum += score * xv;
        mx = fmaxf(mx, xv);
    }
    psum[blockIdx.x * 128 + c] = sum;
    pmax[blockIdx.x * 128 + c] = mx;
}

__global__ __launch_bounds__(128)
void pool_final(const float* __restrict__ psum, const float* __restrict__ pmax,
                float* __restrict__ out) {
    const int g = blockIdx.x, c = threadIdx.x;
    float s = 0.f, m = -__builtin_inff();
    #pragma unroll
    for (int ch = 0; ch < PCH; ++ch) {
        s += psum[(g * PCH + ch) * 128 + c];
        m = fmaxf(m, pmax[(g * PCH + ch) * 128 + c]);
    }
    out[g * 256 + c] = s;
    out[g * 256 + 128 + c] = m;
}

// ---------------------------------------------------------------- launch
extern "C" void kernel_launch(void* const* d_in, const int* in_sizes, int n_in,
                              void* d_out, int out_size, void* d_ws, size_t ws_size,
                              hipStream_t stream) {
    const float* x     = (const float*)d_in[0];
    const int*   ei    = (const int*)d_in[1];
    const int*   batch = (const int*)d_in[2];
    const float* Wq = (const float*)d_in[3];
    const float* bq = (const float*)d_in[4];
    const float* Wk = (const float*)d_in[5];
    const float* bk = (const float*)d_in[6];
    const float* Wv = (const float*)d_in[7];
    const float* bv = (const float*)d_in[8];
    const float* Ws = (const float*)d_in[9];
    const float* bs = (const float*)d_in[10];
    const float* wg = (const float*)d_in[11];
    const float* bg = (const float*)d_in[12];
    float* out = (float*)d_out;

    char* w = (char*)d_ws;
    float* qb            = (float*)w;          w += (size_t)NN * 128 * 4;
    unsigned short* kvb  = (unsigned short*)w; w += (size_t)NN * 256 * 2;
    float* bufA          = (float*)w;          w += (size_t)NN * 128 * 4;
    float* bufB          = (float*)w;          w += (size_t)NN * 128 * 4;
    float* psum          = (float*)w;          w += (size_t)GG * PCH * 128 * 4;
    float* pmax          = (float*)w;          w += (size_t)GG * PCH * 128 * 4;
    unsigned short* wtbh = (unsigned short*)w; w += (size_t)12 * 16384 * 2;
    unsigned short* wtbl = (unsigned short*)w; w += (size_t)12 * 16384 * 2;
    int* counts          = (int*)w;            w += (size_t)NN * 4;
    int* offsets         = (int*)w;            w += (size_t)(NN + 1) * 4;
    int* bsums           = (int*)w;            w += (size_t)256 * 4;
    int* dhist           = (int*)w;            w += (size_t)256 * 4;
    int* dcur            = (int*)w;            w += (size_t)256 * 4;
    int* perm            = (int*)w;            w += (size_t)NN * 4;
    int* csrc            = (int*)w;            w += (size_t)EE * 4;
    int* starts          = (int*)w;            w += (size_t)(GG + 1) * 4;

    const int* srcI = ei;
    const int* dstI = ei + EE;

    // CSR over dst (reused by all 3 layers) + degree-sorted perm + weight prep
    hipMemsetAsync(counts, 0, (size_t)NN * 4, stream);
    hipMemsetAsync(dhist, 0, 256 * 4, stream);
    hipMemsetAsync(dcur, 0, 256 * 4, stream);
    hist_kernel<<<(EE + 255) / 256, 256, 0, stream>>>(dstI, counts);
    block_scan<<<SCB, 256, 0, stream>>>(counts, offsets, bsums);
    scan_sums<<<1, 256, 0, stream>>>(bsums);
    add_base<<<SCB, 256, 0, stream>>>(offsets, bsums);
    deg_hist<<<SCB, 256, 0, stream>>>(counts, dhist);
    deg_scan<<<1, 256, 0, stream>>>(dhist);
    deg_scatter<<<SCB, 256, 0, stream>>>(counts, dhist, dcur, perm);
    hipMemsetAsync(counts, 0, (size_t)NN * 4, stream);  // reuse as cursor
    scatter_kernel<<<(EE + 255) / 256, 256, 0, stream>>>(srcI, dstI, offsets, counts, csrc);
    starts_kernel<<<(NN + 256) / 256, 256, 0, stream>>>(batch, starts);
    prep_weights<<<dim3(12, 8), 256, 0, stream>>>(Wq, Wk, Wv, Ws, wtbh, wtbl);

    const float* xin = x;
    float* bufs[2] = {bufA, bufB};
    const int gemmBlocks = (NN + 63) / 64;   // 782
    const int attnBlocks = NN / 16;          // 3125, exact
    for (int l = 0; l < 3; ++l) {
        float* xs = bufs[l & 1];
        gemm_mfma<<<gemmBlocks, 256, 0, stream>>>(
            xin, wtbh + (size_t)l * 4 * 16384, wtbl + (size_t)l * 4 * 16384,
            bq + (size_t)l * 128, bk + (size_t)l * 128,
            bv + (size_t)l * 128, bs + (size_t)l * 128,
            qb, kvb, xs);
        attn_kernel<<<attnBlocks, 256, 0, stream>>>(qb, (const uint4*)kvb, xs, offsets, csrc, perm);
        xin = xs;
    }

    pool_partial<<<GG * PCH, 128, 0, stream>>>(xin, wg, bg, starts, psum, pmax);
    pool_final<<<GG, 128, 0, stream>>>(psum, pmax, out);
}

// Round 11
// 519.878 us; speedup vs baseline: 1.5784x; 1.0102x over previous
//
#include <hip/hip_runtime.h>
#include <hip/hip_bf16.h>

#define NN 50000
#define EE 800000
#define GG 64
#define PCH 16   // pooling chunks per graph
#define SCB ((NN + 255) / 256)   // 196 scan blocks
// D=128, H=8, C=16, L=3

typedef __attribute__((ext_vector_type(8)))  short          s16x8;
typedef __attribute__((ext_vector_type(8)))  unsigned short u16x8;
typedef __attribute__((ext_vector_type(16))) float          f32x16;

// bf16 helpers (bit-pattern based)
union BFU { __hip_bfloat16 h; unsigned short u; };
__device__ __forceinline__ unsigned short f2bf(float f) {
    BFU b; b.h = __float2bfloat16(f); return b.u;
}
#define B2F_LO(u) __uint_as_float((u) << 16)
#define B2F_HI(u) __uint_as_float((u) & 0xffff0000u)
#define BF2F(us)  __uint_as_float(((unsigned)(us)) << 16)

// ---------------------------------------------------------------- CSR build
__global__ __launch_bounds__(256) void hist_kernel(const int* __restrict__ dst,
                                                   int* __restrict__ counts) {
    int e = blockIdx.x * 256 + threadIdx.x;
    if (e < EE) atomicAdd(&counts[dst[e]], 1);
}

__global__ __launch_bounds__(256)
void block_scan(const int* __restrict__ counts, int* __restrict__ offsets,
                int* __restrict__ bsums) {
    __shared__ int sm[256];
    const int t = threadIdx.x;
    const int i = blockIdx.x * 256 + t;
    const int v = (i < NN) ? counts[i] : 0;
    sm[t] = v;
    __syncthreads();
    for (int off = 1; off < 256; off <<= 1) {
        int val = (t >= off) ? sm[t - off] : 0;
        __syncthreads();
        sm[t] += val;
        __syncthreads();
    }
    if (i < NN) offsets[i] = sm[t] - v;      // exclusive
    if (t == 255) bsums[blockIdx.x] = sm[255];
}

__global__ __launch_bounds__(256)
void scan_sums(int* __restrict__ bsums) {   // in-place -> exclusive block bases
    __shared__ int sm[256];
    const int t = threadIdx.x;
    const int v = (t < SCB) ? bsums[t] : 0;
    sm[t] = v;
    __syncthreads();
    for (int off = 1; off < 256; off <<= 1) {
        int val = (t >= off) ? sm[t - off] : 0;
        __syncthreads();
        sm[t] += val;
        __syncthreads();
    }
    if (t < SCB) bsums[t] = sm[t] - v;       // exclusive base
}

__global__ __launch_bounds__(256)
void add_base(int* __restrict__ offsets, const int* __restrict__ bsums) {
    const int i = blockIdx.x * 256 + threadIdx.x;
    if (i < NN) offsets[i] += bsums[blockIdx.x];
    if (i == 0) offsets[NN] = EE;            // total edges is a constant
}

__global__ __launch_bounds__(256) void scatter_kernel(const int* __restrict__ src,
                                                      const int* __restrict__ dst,
                                                      const int* __restrict__ offs,
                                                      int* __restrict__ cursor,
                                                      int* __restrict__ csrc) {
    int e = blockIdx.x * 256 + threadIdx.x;
    if (e < EE) {
        int dn = dst[e];
        int p = atomicAdd(&cursor[dn], 1);
        csrc[offs[dn] + p] = src[e];
    }
}

__global__ __launch_bounds__(256) void starts_kernel(const int* __restrict__ batch,
                                                     int* __restrict__ starts) {
    int i = blockIdx.x * 256 + threadIdx.x;
    if (i > NN) return;
    int b  = (i < NN) ? batch[i] : GG;
    int bp = (i == 0) ? -1 : batch[i - 1];
    for (int g = bp + 1; g <= b && g <= GG; ++g) starts[g] = i;
}

// ---- degree-sorted node permutation (equalizes trip counts per wave) ----
__global__ __launch_bounds__(256)
void deg_hist(const int* __restrict__ counts, int* __restrict__ dhist) {
    __shared__ int lh[256];
    const int t = threadIdx.x;
    lh[t] = 0;
    __syncthreads();
    const int i = blockIdx.x * 256 + t;
    if (i < NN) atomicAdd(&lh[min(counts[i], 255)], 1);
    __syncthreads();
    if (lh[t]) atomicAdd(&dhist[t], lh[t]);
}

__global__ __launch_bounds__(256)
void deg_scan(int* __restrict__ dhist) {     // in-place -> exclusive bases
    __shared__ int sm[256];
    const int t = threadIdx.x;
    const int v = dhist[t];
    sm[t] = v;
    __syncthreads();
    for (int off = 1; off < 256; off <<= 1) {
        int val = (t >= off) ? sm[t - off] : 0;
        __syncthreads();
        sm[t] += val;
        __syncthreads();
    }
    dhist[t] = sm[t] - v;                    // exclusive base
}

__global__ __launch_bounds__(256)
void deg_scatter(const int* __restrict__ counts, const int* __restrict__ dbase,
                 int* __restrict__ dcur, int* __restrict__ perm) {
    __shared__ int lh[256];   // per-bin count in this block
    __shared__ int lb[256];   // block's reserved chunk base within bin
    const int t = threadIdx.x;
    lh[t] = 0;
    __syncthreads();
    const int i = blockIdx.x * 256 + t;
    int d = 0, r = 0;
    if (i < NN) {
        d = min(counts[i], 255);
        r = atomicAdd(&lh[d], 1);            // rank within block (LDS speed)
    }
    __syncthreads();
    if (lh[t]) lb[t] = atomicAdd(&dcur[t], lh[t]);   // one global atomic per bin
    __syncthreads();
    if (i < NN) perm[dbase[d] + lb[d] + r] = i;
}

// ---------------------------------------------------------------- weight prep
__global__ __launch_bounds__(256)
void prep_weights(const float* __restrict__ Wq, const float* __restrict__ Wk,
                  const float* __restrict__ Wv, const float* __restrict__ Ws,
                  unsigned short* __restrict__ wtbh, unsigned short* __restrict__ wtbl) {
    const int mat = blockIdx.x;           // 0..11
    const int l = mat >> 2, m = mat & 3;
    const float* W;
    switch (m) {
        case 0:  W = Wq; break;
        case 1:  W = Wk; break;
        case 2:  W = Wv; break;
        default: W = Ws; break;
    }
    W += (size_t)l * 16384;
    const int t = threadIdx.x;
    const int col = blockIdx.y * 16 + (t >> 4);
    const int kb  = (t & 15) * 8;
    u16x8 hi, lo;
    #pragma unroll
    for (int j = 0; j < 8; ++j) {
        float w = W[(kb + j) * 128 + col];
        unsigned short uh = f2bf(w);
        hi[j] = uh;
        lo[j] = f2bf(w - BF2F(uh));
    }
    const size_t o = (size_t)mat * 16384 + col * 128 + kb;
    *(u16x8*)(wtbh + o) = hi;
    *(u16x8*)(wtbl + o) = lo;
}

// ---------------------------------------------------------------- MFMA GEMM
// Split-bf16 3-term (xh*Wh + xl*Wh + xh*Wl, ~fp32 quality) ONLY for q (m=0,
// feeds logits as fp32) and skip xs (m=3, compounds across layers). k,v
// (m=1,2) use a single hi-term: their results are packed to bf16 anyway, so
// the extra terms only changed final-rounding ulps. 8 MFMA passes (was 12),
// 6 W-stage phases (was 8).
__global__ __launch_bounds__(256, 2)
void gemm_mfma(const float* __restrict__ xin,
               const unsigned short* __restrict__ wHg,   // + l*4*16384
               const unsigned short* __restrict__ wLg,
               const float* __restrict__ bq, const float* __restrict__ bk,
               const float* __restrict__ bv, const float* __restrict__ bs,
               float* __restrict__ q, unsigned short* __restrict__ kvb,
               float* __restrict__ xs) {
    __shared__ unsigned short xl[16384];   // [0..8191]=hi, [8192..]=lo
    __shared__ unsigned short wsm[16384];
    const int t = threadIdx.x;
    const int n0 = blockIdx.x * 64;

    // ---- stage x (fp32 -> split bf16, swizzled) ----
    const float4* X4 = (const float4*)xin;
    for (int i = t; i < 1024; i += 256) {            // 64 rows x 16 chunks
        const int row = i >> 4, ch = i & 15;
        const int node = n0 + row;
        float4 fa = make_float4(0.f, 0.f, 0.f, 0.f);
        float4 fb = make_float4(0.f, 0.f, 0.f, 0.f);
        if (node < NN) { fa = X4[node * 32 + ch * 2]; fb = X4[node * 32 + ch * 2 + 1]; }
        const float fv[8] = {fa.x, fa.y, fa.z, fa.w, fb.x, fb.y, fb.z, fb.w};
        u16x8 hi, lo;
        #pragma unroll
        for (int j = 0; j < 8; ++j) {
            unsigned short uh = f2bf(fv[j]);
            hi[j] = uh;
            lo[j] = f2bf(fv[j] - BF2F(uh));
        }
        const int base = row * 128 + (ch ^ (row & 7)) * 8;
        *(u16x8*)&xl[base] = hi;
        *(u16x8*)&xl[8192 + base] = lo;
    }
    __syncthreads();

    // ---- per-wave tile & A-fragments (held in regs for all 4 matrices) ----
    const int lane = t & 63, wid = t >> 6;
    const int r = lane & 31, g = lane >> 5;
    const int nt = (wid & 1) * 32;        // node offset in tile
    const int cb = (wid >> 1) * 64;       // col base
    s16x8 ah[8], al[8];
    {
        const int row = nt + r;
        const int s = row & 7;
        const int rb = row * 128;
        #pragma unroll
        for (int kc = 0; kc < 8; ++kc) {
            const int idx = rb + (((kc << 1) | g) ^ s) * 8;
            ah[kc] = *(const s16x8*)&xl[idx];
            al[kc] = *(const s16x8*)&xl[8192 + idx];
        }
    }
    const int col0 = cb + r, col1 = cb + 32 + r;
    const int wb0 = col0 * 128, ws0 = col0 & 7;
    const int wb1 = col1 * 128, ws1 = col1 & 7;

    for (int m = 0; m < 4; ++m) {
        const bool split = (m == 0 || m == 3);
        f32x16 acc0, acc1;
        #pragma unroll
        for (int j = 0; j < 16; ++j) { acc0[j] = 0.f; acc1[j] = 0.f; }

        const int nparts = split ? 2 : 1;
        for (int part = 0; part < nparts; ++part) {
            __syncthreads();
            const u16x8* Wg = (const u16x8*)((part == 0 ? wHg : wLg) + m * 16384);
            for (int i = t; i < 2048; i += 256) {    // 128 rows x 16 chunks
                const int row = i >> 4, ch = i & 15;
                *(u16x8*)&wsm[row * 128 + (ch ^ (row & 7)) * 8] = Wg[i];
            }
            __syncthreads();
            #pragma unroll
            for (int kc = 0; kc < 8; ++kc) {
                const s16x8 b0 = *(const s16x8*)&wsm[wb0 + (((kc << 1) | g) ^ ws0) * 8];
                const s16x8 b1 = *(const s16x8*)&wsm[wb1 + (((kc << 1) | g) ^ ws1) * 8];
                acc0 = __builtin_amdgcn_mfma_f32_32x32x16_bf16(ah[kc], b0, acc0, 0, 0, 0);
                acc1 = __builtin_amdgcn_mfma_f32_32x32x16_bf16(ah[kc], b1, acc1, 0, 0, 0);
                if (split && part == 0) {
                    acc0 = __builtin_amdgcn_mfma_f32_32x32x16_bf16(al[kc], b0, acc0, 0, 0, 0);
                    acc1 = __builtin_amdgcn_mfma_f32_32x32x16_bf16(al[kc], b1, acc1, 0, 0, 0);
                }
            }
        }

        // ---- epilogue ----
        const float* bp;
        switch (m) {
            case 0:  bp = bq; break;
            case 1:  bp = bk; break;
            case 2:  bp = bv; break;
            default: bp = bs; break;
        }
        const float b0 = bp[col0], b1 = bp[col1];
        if (m == 0 || m == 3) {
            float* outp = (m == 0) ? q : xs;
            #pragma unroll
            for (int reg = 0; reg < 16; ++reg) {
                const int node = n0 + nt + (reg & 3) + 8 * (reg >> 2) + 4 * g;
                if (node < NN) {
                    outp[node * 128 + col0] = acc0[reg] + b0;
                    outp[node * 128 + col1] = acc1[reg] + b1;
                }
            }
        } else {
            const int koff = (m == 1) ? 0 : 16;      // k at +0, v at +16 (ushorts)
            const int o0 = (col0 >> 4) * 32 + koff + (col0 & 15);
            const int o1 = (col1 >> 4) * 32 + koff + (col1 & 15);
            #pragma unroll
            for (int reg = 0; reg < 16; ++reg) {
                const int node = n0 + nt + (reg & 3) + 8 * (reg >> 2) + 4 * g;
                if (node < NN) {
                    kvb[(size_t)node * 256 + o0] = f2bf(acc0[reg] + b0);
                    kvb[(size_t)node * 256 + o1] = f2bf(acc1[reg] + b1);
                }
            }
        }
    }
}

// ---------------------------------------------------------------- attention (CSR, online softmax)
// thread = (node, head, edge-quarter): 32 threads/node. 4-way edge split
// (latency-bound diagnosis: more waves + shorter serial chains). 1-edge-ahead
// prefetch. Quarter-streams merged exactly via two __shfl_xor rounds (8,16);
// node spans lanes [32k,32k+31] of one wave. Grid 6250*8 == 50000 exact.
__global__ __launch_bounds__(256)
void attn_kernel(const float* __restrict__ q, const uint4* __restrict__ kv4,
                 float* __restrict__ xio,
                 const int* __restrict__ offs, const int* __restrict__ csrc,
                 const int* __restrict__ perm) {
    const int t = threadIdx.x;
    const int h = t & 7;
    const int quarter = (t >> 3) & 3;
    const int idx = blockIdx.x * 8 + (t >> 5);
    const int n = perm[idx];
    const float4* qp = (const float4*)(q + n * 128 + h * 16);
    const float4 q0 = qp[0], q1 = qp[1], q2 = qp[2], q3 = qp[3];
    float m = -__builtin_inff();
    float d = 0.f;
    float4 a0 = {}, a1 = {}, a2 = {}, a3 = {};
    const int e0 = offs[n], e1 = offs[n + 1];
    const int e = e0 + quarter;
    if (e < e1) {
        const uint4* kvp = kv4 + (size_t)csrc[e] * 32 + h * 4;
        uint4 ka = kvp[0], kb = kvp[1], va = kvp[2], vb = kvp[3];
        for (int en = e + 4;; en += 4) {
            uint4 nka, nkb, nva, nvb;
            const bool more = (en < e1);
            if (more) {                                     // prefetch next edge
                const uint4* kvn = kv4 + (size_t)csrc[en] * 32 + h * 4;
                nka = kvn[0]; nkb = kvn[1]; nva = kvn[2]; nvb = kvn[3];
            }
            float dot =
                q0.x * B2F_LO(ka.x) + q0.y * B2F_HI(ka.x) + q0.z * B2F_LO(ka.y) + q0.w * B2F_HI(ka.y)
              + q1.x * B2F_LO(ka.z) + q1.y * B2F_HI(ka.z) + q1.z * B2F_LO(ka.w) + q1.w * B2F_HI(ka.w)
              + q2.x * B2F_LO(kb.x) + q2.y * B2F_HI(kb.x) + q2.z * B2F_LO(kb.y) + q2.w * B2F_HI(kb.y)
              + q3.x * B2F_LO(kb.z) + q3.y * B2F_HI(kb.z) + q3.z * B2F_LO(kb.w) + q3.w * B2F_HI(kb.w);
            const float alpha = dot * 0.25f;                // / sqrt(C=16)
            const float nm = fmaxf(m, alpha);
            const float scale = __expf(m - nm);             // 0 on first edge
            const float p = __expf(alpha - nm);
            d = d * scale + p;
            a0.x = a0.x * scale + p * B2F_LO(va.x); a0.y = a0.y * scale + p * B2F_HI(va.x);
            a0.z = a0.z * scale + p * B2F_LO(va.y); a0.w = a0.w * scale + p * B2F_HI(va.y);
            a1.x = a1.x * scale + p * B2F_LO(va.z); a1.y = a1.y * scale + p * B2F_HI(va.z);
            a1.z = a1.z * scale + p * B2F_LO(va.w); a1.w = a1.w * scale + p * B2F_HI(va.w);
            a2.x = a2.x * scale + p * B2F_LO(vb.x); a2.y = a2.y * scale + p * B2F_HI(vb.x);
            a2.z = a2.z * scale + p * B2F_LO(vb.y); a2.w = a2.w * scale + p * B2F_HI(vb.y);
            a3.x = a3.x * scale + p * B2F_LO(vb.z); a3.y = a3.y * scale + p * B2F_HI(vb.z);
            a3.z = a3.z * scale + p * B2F_LO(vb.w); a3.w = a3.w * scale + p * B2F_HI(vb.w);
            m = nm;
            if (!more) break;
            ka = nka; kb = nkb; va = nva; vb = nvb;
        }
    }
    // ---- merge the four quarter-streams (exact in fp32): xor 8, then 16 ----
    #pragma unroll
    for (int o = 8; o <= 16; o <<= 1) {
        const float mp = __shfl_xor(m, o);
        const float dp = __shfl_xor(d, o);
        const float mc = fmaxf(fmaxf(m, mp), -1e30f);  // -1e30 guard: empty-stream NaN
        const float s0 = __expf(m - mc);
        const float s1 = __expf(mp - mc);
        d = d * s0 + dp * s1;
        float pa;
        pa = __shfl_xor(a0.x, o); a0.x = a0.x * s0 + pa * s1;
        pa = __shfl_xor(a0.y, o); a0.y = a0.y * s0 + pa * s1;
        pa = __shfl_xor(a0.z, o); a0.z = a0.z * s0 + pa * s1;
        pa = __shfl_xor(a0.w, o); a0.w = a0.w * s0 + pa * s1;
        pa = __shfl_xor(a1.x, o); a1.x = a1.x * s0 + pa * s1;
        pa = __shfl_xor(a1.y, o); a1.y = a1.y * s0 + pa * s1;
        pa = __shfl_xor(a1.z, o); a1.z = a1.z * s0 + pa * s1;
        pa = __shfl_xor(a1.w, o); a1.w = a1.w * s0 + pa * s1;
        pa = __shfl_xor(a2.x, o); a2.x = a2.x * s0 + pa * s1;
        pa = __shfl_xor(a2.y, o); a2.y = a2.y * s0 + pa * s1;
        pa = __shfl_xor(a2.z, o); a2.z = a2.z * s0 + pa * s1;
        pa = __shfl_xor(a2.w, o); a2.w = a2.w * s0 + pa * s1;
        pa = __shfl_xor(a3.x, o); a3.x = a3.x * s0 + pa * s1;
        pa = __shfl_xor(a3.y, o); a3.y = a3.y * s0 + pa * s1;
        pa = __shfl_xor(a3.z, o); a3.z = a3.z * s0 + pa * s1;
        pa = __shfl_xor(a3.w, o); a3.w = a3.w * s0 + pa * s1;
        m = mc;
    }
    if (quarter == 0) {
        const float inv = 1.f / (d + 1e-16f);
        float4* op = (float4*)(xio + n * 128 + h * 16);
        float4 o0 = op[0], o1 = op[1], o2 = op[2], o3 = op[3];
        o0.x += a0.x * inv; o0.y += a0.y * inv; o0.z += a0.z * inv; o0.w += a0.w * inv;
        o1.x += a1.x * inv; o1.y += a1.y * inv; o1.z += a1.z * inv; o1.w += a1.w * inv;
        o2.x += a2.x * inv; o2.y += a2.y * inv; o2.z += a2.z * inv; o2.w += a2.w * inv;
        o3.x += a3.x * inv; o3.y += a3.y * inv; o3.z += a3.z * inv; o3.w += a3.w * inv;
        op[0] = o0; op[1] = o1; op[2] = o2; op[3] = o3;
    }
}

// ---------------------------------------------------------------- readout (2-phase, fused gate)
__global__ __launch_bounds__(128)
void pool_partial(const float* __restrict__ x, const float* __restrict__ wg,
                  const float* __restrict__ bg, const int* __restrict__ starts,
                  float* __restrict__ psum, float* __restrict__ pmax) {
    const int g  = blockIdx.x / PCH;
    const int ch = blockIdx.x % PCH;
    const int c  = threadIdx.x;
    const int s0 = starts[g], s1 = starts[g + 1];
    const int total = s1 - s0;
    const int len = (total + PCH - 1) / PCH;
    const int n0 = s0 + ch * len;
    const int n1 = min(n0 + len, s1);
    const float w = wg[c];
    const float b = bg[0];
    __shared__ float red[2];
    float sum = 0.f, mx = -__builtin_inff();
    for (int n = n0; n < n1; ++n) {
        const float xv = x[n * 128 + c];
        float p = xv * w;
        #pragma unroll
        for (int o = 32; o; o >>= 1) p += __shfl_xor(p, o);
        if ((c & 63) == 0) red[c >> 6] = p;
        __syncthreads();
        const float dot = red[0] + red[1];
        __syncthreads();
        const float score = 1.f / (1.f + __expf(-(dot + b)));
        sum += score * xv;
        mx = fmaxf(mx, xv);
    }
    psum[blockIdx.x * 128 + c] = sum;
    pmax[blockIdx.x * 128 + c] = mx;
}

__global__ __launch_bounds__(128)
void pool_final(const float* __restrict__ psum, const float* __restrict__ pmax,
                float* __restrict__ out) {
    const int g = blockIdx.x, c = threadIdx.x;
    float s = 0.f, m = -__builtin_inff();
    #pragma unroll
    for (int ch = 0; ch < PCH; ++ch) {
        s += psum[(g * PCH + ch) * 128 + c];
        m = fmaxf(m, pmax[(g * PCH + ch) * 128 + c]);
    }
    out[g * 256 + c] = s;
    out[g * 256 + 128 + c] = m;
}

// ---------------------------------------------------------------- launch
extern "C" void kernel_launch(void* const* d_in, const int* in_sizes, int n_in,
                              void* d_out, int out_size, void* d_ws, size_t ws_size,
                              hipStream_t stream) {
    const float* x     = (const float*)d_in[0];
    const int*   ei    = (const int*)d_in[1];
    const int*   batch = (const int*)d_in[2];
    const float* Wq = (const float*)d_in[3];
    const float* bq = (const float*)d_in[4];
    const float* Wk = (const float*)d_in[5];
    const float* bk = (const float*)d_in[6];
    const float* Wv = (const float*)d_in[7];
    const float* bv = (const float*)d_in[8];
    const float* Ws = (const float*)d_in[9];
    const float* bs = (const float*)d_in[10];
    const float* wg = (const float*)d_in[11];
    const float* bg = (const float*)d_in[12];
    float* out = (float*)d_out;

    char* w = (char*)d_ws;
    float* qb            = (float*)w;          w += (size_t)NN * 128 * 4;
    unsigned short* kvb  = (unsigned short*)w; w += (size_t)NN * 256 * 2;
    float* bufA          = (float*)w;          w += (size_t)NN * 128 * 4;
    float* bufB          = (float*)w;          w += (size_t)NN * 128 * 4;
    float* psum          = (float*)w;          w += (size_t)GG * PCH * 128 * 4;
    float* pmax          = (float*)w;          w += (size_t)GG * PCH * 128 * 4;
    unsigned short* wtbh = (unsigned short*)w; w += (size_t)12 * 16384 * 2;
    unsigned short* wtbl = (unsigned short*)w; w += (size_t)12 * 16384 * 2;
    int* counts          = (int*)w;            w += (size_t)NN * 4;
    int* offsets         = (int*)w;            w += (size_t)(NN + 1) * 4;
    int* bsums           = (int*)w;            w += (size_t)256 * 4;
    int* dhist           = (int*)w;            w += (size_t)256 * 4;
    int* dcur            = (int*)w;            w += (size_t)256 * 4;
    int* perm            = (int*)w;            w += (size_t)NN * 4;
    int* csrc            = (int*)w;            w += (size_t)EE * 4;
    int* starts          = (int*)w;            w += (size_t)(GG + 1) * 4;

    const int* srcI = ei;
    const int* dstI = ei + EE;

    // CSR over dst (reused by all 3 layers) + degree-sorted perm + weight prep
    hipMemsetAsync(counts, 0, (size_t)NN * 4, stream);
    hipMemsetAsync(dhist, 0, 256 * 4, stream);
    hipMemsetAsync(dcur, 0, 256 * 4, stream);
    hist_kernel<<<(EE + 255) / 256, 256, 0, stream>>>(dstI, counts);
    block_scan<<<SCB, 256, 0, stream>>>(counts, offsets, bsums);
    scan_sums<<<1, 256, 0, stream>>>(bsums);
    add_base<<<SCB, 256, 0, stream>>>(offsets, bsums);
    deg_hist<<<SCB, 256, 0, stream>>>(counts, dhist);
    deg_scan<<<1, 256, 0, stream>>>(dhist);
    deg_scatter<<<SCB, 256, 0, stream>>>(counts, dhist, dcur, perm);
    hipMemsetAsync(counts, 0, (size_t)NN * 4, stream);  // reuse as cursor
    scatter_kernel<<<(EE + 255) / 256, 256, 0, stream>>>(srcI, dstI, offsets, counts, csrc);
    starts_kernel<<<(NN + 256) / 256, 256, 0, stream>>>(batch, starts);
    prep_weights<<<dim3(12, 8), 256, 0, stream>>>(Wq, Wk, Wv, Ws, wtbh, wtbl);

    const float* xin = x;
    float* bufs[2] = {bufA, bufB};
    const int gemmBlocks = (NN + 63) / 64;   // 782
    const int attnBlocks = NN / 8;           // 6250, exact
    for (int l = 0; l < 3; ++l) {
        float* xs = bufs[l & 1];
        gemm_mfma<<<gemmBlocks, 256, 0, stream>>>(
            xin, wtbh + (size_t)l * 4 * 16384, wtbl + (size_t)l * 4 * 16384,
            bq + (size_t)l * 128, bk + (size_t)l * 128,
            bv + (size_t)l * 128, bs + (size_t)l * 128,
            qb, kvb, xs);
        attn_kernel<<<attnBlocks, 256, 0, stream>>>(qb, (const uint4*)kvb, xs, offsets, csrc, perm);
        xin = xs;
    }

    pool_partial<<<GG * PCH, 128, 0, stream>>>(xin, wg, bg, starts, psum, pmax);
    pool_final<<<GG, 128, 0, stream>>>(psum, pmax, out);
}

// Round 12
// 479.194 us; speedup vs baseline: 1.7124x; 1.0849x over previous
//
#include <hip/hip_runtime.h>
#include <hip/hip_bf16.h>

#define NN 50000
#define EE 800000
#define GG 64
#define PCH 16   // pooling chunks per graph
#define SCB ((NN + 255) / 256)   // 196 scan blocks
// D=128, H=8, C=16, L=3

typedef __attribute__((ext_vector_type(8)))  short          s16x8;
typedef __attribute__((ext_vector_type(8)))  unsigned short u16x8;
typedef __attribute__((ext_vector_type(16))) float          f32x16;

// bf16 helpers (bit-pattern based)
union BFU { __hip_bfloat16 h; unsigned short u; };
__device__ __forceinline__ unsigned short f2bf(float f) {
    BFU b; b.h = __float2bfloat16(f); return b.u;
}
#define B2F_LO(u) __uint_as_float((u) << 16)
#define B2F_HI(u) __uint_as_float((u) & 0xffff0000u)
#define BF2F(us)  __uint_as_float(((unsigned)(us)) << 16)

// ---------------------------------------------------------------- CSR build
__global__ __launch_bounds__(256) void hist_kernel(const int* __restrict__ dst,
                                                   int* __restrict__ counts) {
    int e = blockIdx.x * 256 + threadIdx.x;
    if (e < EE) atomicAdd(&counts[dst[e]], 1);
}

__global__ __launch_bounds__(256)
void block_scan(const int* __restrict__ counts, int* __restrict__ offsets,
                int* __restrict__ bsums) {
    __shared__ int sm[256];
    const int t = threadIdx.x;
    const int i = blockIdx.x * 256 + t;
    const int v = (i < NN) ? counts[i] : 0;
    sm[t] = v;
    __syncthreads();
    for (int off = 1; off < 256; off <<= 1) {
        int val = (t >= off) ? sm[t - off] : 0;
        __syncthreads();
        sm[t] += val;
        __syncthreads();
    }
    if (i < NN) offsets[i] = sm[t] - v;      // exclusive
    if (t == 255) bsums[blockIdx.x] = sm[255];
}

__global__ __launch_bounds__(256)
void scan_sums(int* __restrict__ bsums) {   // in-place -> exclusive block bases
    __shared__ int sm[256];
    const int t = threadIdx.x;
    const int v = (t < SCB) ? bsums[t] : 0;
    sm[t] = v;
    __syncthreads();
    for (int off = 1; off < 256; off <<= 1) {
        int val = (t >= off) ? sm[t - off] : 0;
        __syncthreads();
        sm[t] += val;
        __syncthreads();
    }
    if (t < SCB) bsums[t] = sm[t] - v;       // exclusive base
}

__global__ __launch_bounds__(256)
void add_base(int* __restrict__ offsets, const int* __restrict__ bsums) {
    const int i = blockIdx.x * 256 + threadIdx.x;
    if (i < NN) offsets[i] += bsums[blockIdx.x];
    if (i == 0) offsets[NN] = EE;            // total edges is a constant
}

__global__ __launch_bounds__(256) void scatter_kernel(const int* __restrict__ src,
                                                      const int* __restrict__ dst,
                                                      const int* __restrict__ offs,
                                                      int* __restrict__ cursor,
                                                      int* __restrict__ csrc) {
    int e = blockIdx.x * 256 + threadIdx.x;
    if (e < EE) {
        int dn = dst[e];
        int p = atomicAdd(&cursor[dn], 1);
        csrc[offs[dn] + p] = src[e];
    }
}

__global__ __launch_bounds__(256) void starts_kernel(const int* __restrict__ batch,
                                                     int* __restrict__ starts) {
    int i = blockIdx.x * 256 + threadIdx.x;
    if (i > NN) return;
    int b  = (i < NN) ? batch[i] : GG;
    int bp = (i == 0) ? -1 : batch[i - 1];
    for (int g = bp + 1; g <= b && g <= GG; ++g) starts[g] = i;
}

// ---- degree-sorted node permutation (equalizes trip counts per wave) ----
__global__ __launch_bounds__(256)
void deg_hist(const int* __restrict__ counts, int* __restrict__ dhist) {
    __shared__ int lh[256];
    const int t = threadIdx.x;
    lh[t] = 0;
    __syncthreads();
    const int i = blockIdx.x * 256 + t;
    if (i < NN) atomicAdd(&lh[min(counts[i], 255)], 1);
    __syncthreads();
    if (lh[t]) atomicAdd(&dhist[t], lh[t]);
}

__global__ __launch_bounds__(256)
void deg_scan(int* __restrict__ dhist) {     // in-place -> exclusive bases
    __shared__ int sm[256];
    const int t = threadIdx.x;
    const int v = dhist[t];
    sm[t] = v;
    __syncthreads();
    for (int off = 1; off < 256; off <<= 1) {
        int val = (t >= off) ? sm[t - off] : 0;
        __syncthreads();
        sm[t] += val;
        __syncthreads();
    }
    dhist[t] = sm[t] - v;                    // exclusive base
}

__global__ __launch_bounds__(256)
void deg_scatter(const int* __restrict__ counts, const int* __restrict__ dbase,
                 int* __restrict__ dcur, int* __restrict__ perm) {
    __shared__ int lh[256];   // per-bin count in this block
    __shared__ int lb[256];   // block's reserved chunk base within bin
    const int t = threadIdx.x;
    lh[t] = 0;
    __syncthreads();
    const int i = blockIdx.x * 256 + t;
    int d = 0, r = 0;
    if (i < NN) {
        d = min(counts[i], 255);
        r = atomicAdd(&lh[d], 1);            // rank within block (LDS speed)
    }
    __syncthreads();
    if (lh[t]) lb[t] = atomicAdd(&dcur[t], lh[t]);   // one global atomic per bin
    __syncthreads();
    if (i < NN) perm[dbase[d] + lb[d] + r] = i;
}

// ---------------------------------------------------------------- weight prep
// W[l][k][c] fp32 -> B-FRAGMENT-ORDER split-bf16:
//   wf[mat][(kk*128 + col)*8 + j] = W[kk*8 + j][col],  kk = K-chunk 0..15.
// A wave reading fragment (kk, col0=cb+r) across lanes r=0..31 hits one
// contiguous 512B segment -> coalesced, L2-broadcast across all blocks.
// This kills the GEMM's LDS W-staging + its barriers entirely.
__global__ __launch_bounds__(256)
void prep_weights(const float* __restrict__ Wq, const float* __restrict__ Wk,
                  const float* __restrict__ Wv, const float* __restrict__ Ws,
                  unsigned short* __restrict__ wfh, unsigned short* __restrict__ wfl) {
    const int mat = blockIdx.x;           // 0..11
    const int l = mat >> 2, m = mat & 3;
    const float* W;
    switch (m) {
        case 0:  W = Wq; break;
        case 1:  W = Wk; break;
        case 2:  W = Wv; break;
        default: W = Ws; break;
    }
    W += (size_t)l * 16384;
    const int t = threadIdx.x;
    const int col = blockIdx.y * 16 + (t >> 4);
    const int kk  = t & 15;               // chunk of 8 K values
    u16x8 hi, lo;
    #pragma unroll
    for (int j = 0; j < 8; ++j) {
        float w = W[(kk * 8 + j) * 128 + col];
        unsigned short uh = f2bf(w);
        hi[j] = uh;
        lo[j] = f2bf(w - BF2F(uh));
    }
    const size_t o = (size_t)mat * 16384 + ((size_t)kk * 128 + col) * 8;
    *(u16x8*)(wfh + o) = hi;
    *(u16x8*)(wfl + o) = lo;
}

// ---------------------------------------------------------------- MFMA GEMM
// One barrier total (x stage). B-frags stream from global (L2-hot, 192KB/layer)
// in fragment order. Split-bf16 3-term for q (m=0) and skip xs (m=3);
// single hi-term for k,v (packed to bf16 anyway). LDS 16KB -> higher occupancy.
__global__ __launch_bounds__(256)
void gemm_mfma(const float* __restrict__ xin,
               const unsigned short* __restrict__ wHg,   // + l*4*16384, frag order
               const unsigned short* __restrict__ wLg,
               const float* __restrict__ bq, const float* __restrict__ bk,
               const float* __restrict__ bv, const float* __restrict__ bs,
               float* __restrict__ q, unsigned short* __restrict__ kvb,
               float* __restrict__ xs) {
    __shared__ unsigned short xl[16384];   // [0..8191]=hi, [8192..]=lo
    const int t = threadIdx.x;
    const int n0 = blockIdx.x * 64;

    // ---- stage x (fp32 -> split bf16, swizzled) ----
    const float4* X4 = (const float4*)xin;
    for (int i = t; i < 1024; i += 256) {            // 64 rows x 16 chunks
        const int row = i >> 4, ch = i & 15;
        const int node = n0 + row;
        float4 fa = make_float4(0.f, 0.f, 0.f, 0.f);
        float4 fb = make_float4(0.f, 0.f, 0.f, 0.f);
        if (node < NN) { fa = X4[node * 32 + ch * 2]; fb = X4[node * 32 + ch * 2 + 1]; }
        const float fv[8] = {fa.x, fa.y, fa.z, fa.w, fb.x, fb.y, fb.z, fb.w};
        u16x8 hi, lo;
        #pragma unroll
        for (int j = 0; j < 8; ++j) {
            unsigned short uh = f2bf(fv[j]);
            hi[j] = uh;
            lo[j] = f2bf(fv[j] - BF2F(uh));
        }
        const int base = row * 128 + (ch ^ (row & 7)) * 8;
        *(u16x8*)&xl[base] = hi;
        *(u16x8*)&xl[8192 + base] = lo;
    }
    __syncthreads();

    // ---- per-wave tile & A-fragments (held in regs for all 4 matrices) ----
    const int lane = t & 63, wid = t >> 6;
    const int r = lane & 31, g = lane >> 5;
    const int nt = (wid & 1) * 32;        // node offset in tile
    const int cb = (wid >> 1) * 64;       // col base
    s16x8 ah[8], al[8];
    {
        const int row = nt + r;
        const int s = row & 7;
        const int rb = row * 128;
        #pragma unroll
        for (int kc = 0; kc < 8; ++kc) {
            const int idx = rb + (((kc << 1) | g) ^ s) * 8;
            ah[kc] = *(const s16x8*)&xl[idx];
            al[kc] = *(const s16x8*)&xl[8192 + idx];
        }
    }
    const int col0 = cb + r, col1 = cb + 32 + r;

    #pragma unroll
    for (int m = 0; m < 4; ++m) {
        const bool split = (m == 0 || m == 3);
        const unsigned short* WH = wHg + m * 16384;
        const unsigned short* WL = wLg + m * 16384;
        f32x16 acc0, acc1;
        #pragma unroll
        for (int j = 0; j < 16; ++j) { acc0[j] = 0.f; acc1[j] = 0.f; }

        #pragma unroll
        for (int kc = 0; kc < 8; ++kc) {
            const int kk = (kc << 1) | g;
            const s16x8 b0 = *(const s16x8*)&WH[(kk * 128 + col0) * 8];
            const s16x8 b1 = *(const s16x8*)&WH[(kk * 128 + col1) * 8];
            acc0 = __builtin_amdgcn_mfma_f32_32x32x16_bf16(ah[kc], b0, acc0, 0, 0, 0);
            acc1 = __builtin_amdgcn_mfma_f32_32x32x16_bf16(ah[kc], b1, acc1, 0, 0, 0);
            if (split) {
                acc0 = __builtin_amdgcn_mfma_f32_32x32x16_bf16(al[kc], b0, acc0, 0, 0, 0);
                acc1 = __builtin_amdgcn_mfma_f32_32x32x16_bf16(al[kc], b1, acc1, 0, 0, 0);
                const s16x8 c0 = *(const s16x8*)&WL[(kk * 128 + col0) * 8];
                const s16x8 c1 = *(const s16x8*)&WL[(kk * 128 + col1) * 8];
                acc0 = __builtin_amdgcn_mfma_f32_32x32x16_bf16(ah[kc], c0, acc0, 0, 0, 0);
                acc1 = __builtin_amdgcn_mfma_f32_32x32x16_bf16(ah[kc], c1, acc1, 0, 0, 0);
            }
        }

        // ---- epilogue ----
        const float* bp;
        switch (m) {
            case 0:  bp = bq; break;
            case 1:  bp = bk; break;
            case 2:  bp = bv; break;
            default: bp = bs; break;
        }
        const float b0 = bp[col0], b1 = bp[col1];
        if (m == 0 || m == 3) {
            float* outp = (m == 0) ? q : xs;
            #pragma unroll
            for (int reg = 0; reg < 16; ++reg) {
                const int node = n0 + nt + (reg & 3) + 8 * (reg >> 2) + 4 * g;
                if (node < NN) {
                    outp[node * 128 + col0] = acc0[reg] + b0;
                    outp[node * 128 + col1] = acc1[reg] + b1;
                }
            }
        } else {
            const int koff = (m == 1) ? 0 : 16;      // k at +0, v at +16 (ushorts)
            const int o0 = (col0 >> 4) * 32 + koff + (col0 & 15);
            const int o1 = (col1 >> 4) * 32 + koff + (col1 & 15);
            #pragma unroll
            for (int reg = 0; reg < 16; ++reg) {
                const int node = n0 + nt + (reg & 3) + 8 * (reg >> 2) + 4 * g;
                if (node < NN) {
                    kvb[(size_t)node * 256 + o0] = f2bf(acc0[reg] + b0);
                    kvb[(size_t)node * 256 + o1] = f2bf(acc1[reg] + b1);
                }
            }
        }
    }
}

// ---------------------------------------------------------------- attention (CSR, online softmax)
// thread = (node, head, edge-quarter): 32 threads/node, 1-edge-ahead prefetch,
// two-round shfl merge. (Round-11 proven: 65.5us, occ 52%.)
__global__ __launch_bounds__(256)
void attn_kernel(const float* __restrict__ q, const uint4* __restrict__ kv4,
                 float* __restrict__ xio,
                 const int* __restrict__ offs, const int* __restrict__ csrc,
                 const int* __restrict__ perm) {
    const int t = threadIdx.x;
    const int h = t & 7;
    const int quarter = (t >> 3) & 3;
    const int idx = blockIdx.x * 8 + (t >> 5);
    const int n = perm[idx];
    const float4* qp = (const float4*)(q + n * 128 + h * 16);
    const float4 q0 = qp[0], q1 = qp[1], q2 = qp[2], q3 = qp[3];
    float m = -__builtin_inff();
    float d = 0.f;
    float4 a0 = {}, a1 = {}, a2 = {}, a3 = {};
    const int e0 = offs[n], e1 = offs[n + 1];
    const int e = e0 + quarter;
    if (e < e1) {
        const uint4* kvp = kv4 + (size_t)csrc[e] * 32 + h * 4;
        uint4 ka = kvp[0], kb = kvp[1], va = kvp[2], vb = kvp[3];
        for (int en = e + 4;; en += 4) {
            uint4 nka, nkb, nva, nvb;
            const bool more = (en < e1);
            if (more) {                                     // prefetch next edge
                const uint4* kvn = kv4 + (size_t)csrc[en] * 32 + h * 4;
                nka = kvn[0]; nkb = kvn[1]; nva = kvn[2]; nvb = kvn[3];
            }
            float dot =
                q0.x * B2F_LO(ka.x) + q0.y * B2F_HI(ka.x) + q0.z * B2F_LO(ka.y) + q0.w * B2F_HI(ka.y)
              + q1.x * B2F_LO(ka.z) + q1.y * B2F_HI(ka.z) + q1.z * B2F_LO(ka.w) + q1.w * B2F_HI(ka.w)
              + q2.x * B2F_LO(kb.x) + q2.y * B2F_HI(kb.x) + q2.z * B2F_LO(kb.y) + q2.w * B2F_HI(kb.y)
              + q3.x * B2F_LO(kb.z) + q3.y * B2F_HI(kb.z) + q3.z * B2F_LO(kb.w) + q3.w * B2F_HI(kb.w);
            const float alpha = dot * 0.25f;                // / sqrt(C=16)
            const float nm = fmaxf(m, alpha);
            const float scale = __expf(m - nm);             // 0 on first edge
            const float p = __expf(alpha - nm);
            d = d * scale + p;
            a0.x = a0.x * scale + p * B2F_LO(va.x); a0.y = a0.y * scale + p * B2F_HI(va.x);
            a0.z = a0.z * scale + p * B2F_LO(va.y); a0.w = a0.w * scale + p * B2F_HI(va.y);
            a1.x = a1.x * scale + p * B2F_LO(va.z); a1.y = a1.y * scale + p * B2F_HI(va.z);
            a1.z = a1.z * scale + p * B2F_LO(va.w); a1.w = a1.w * scale + p * B2F_HI(va.w);
            a2.x = a2.x * scale + p * B2F_LO(vb.x); a2.y = a2.y * scale + p * B2F_HI(vb.x);
            a2.z = a2.z * scale + p * B2F_LO(vb.y); a2.w = a2.w * scale + p * B2F_HI(vb.y);
            a3.x = a3.x * scale + p * B2F_LO(vb.z); a3.y = a3.y * scale + p * B2F_HI(vb.z);
            a3.z = a3.z * scale + p * B2F_LO(vb.w); a3.w = a3.w * scale + p * B2F_HI(vb.w);
            m = nm;
            if (!more) break;
            ka = nka; kb = nkb; va = nva; vb = nvb;
        }
    }
    // ---- merge the four quarter-streams (exact in fp32): xor 8, then 16 ----
    #pragma unroll
    for (int o = 8; o <= 16; o <<= 1) {
        const float mp = __shfl_xor(m, o);
        const float dp = __shfl_xor(d, o);
        const float mc = fmaxf(fmaxf(m, mp), -1e30f);  // -1e30 guard: empty-stream NaN
        const float s0 = __expf(m - mc);
        const float s1 = __expf(mp - mc);
        d = d * s0 + dp * s1;
        float pa;
        pa = __shfl_xor(a0.x, o); a0.x = a0.x * s0 + pa * s1;
        pa = __shfl_xor(a0.y, o); a0.y = a0.y * s0 + pa * s1;
        pa = __shfl_xor(a0.z, o); a0.z = a0.z * s0 + pa * s1;
        pa = __shfl_xor(a0.w, o); a0.w = a0.w * s0 + pa * s1;
        pa = __shfl_xor(a1.x, o); a1.x = a1.x * s0 + pa * s1;
        pa = __shfl_xor(a1.y, o); a1.y = a1.y * s0 + pa * s1;
        pa = __shfl_xor(a1.z, o); a1.z = a1.z * s0 + pa * s1;
        pa = __shfl_xor(a1.w, o); a1.w = a1.w * s0 + pa * s1;
        pa = __shfl_xor(a2.x, o); a2.x = a2.x * s0 + pa * s1;
        pa = __shfl_xor(a2.y, o); a2.y = a2.y * s0 + pa * s1;
        pa = __shfl_xor(a2.z, o); a2.z = a2.z * s0 + pa * s1;
        pa = __shfl_xor(a2.w, o); a2.w = a2.w * s0 + pa * s1;
        pa = __shfl_xor(a3.x, o); a3.x = a3.x * s0 + pa * s1;
        pa = __shfl_xor(a3.y, o); a3.y = a3.y * s0 + pa * s1;
        pa = __shfl_xor(a3.z, o); a3.z = a3.z * s0 + pa * s1;
        pa = __shfl_xor(a3.w, o); a3.w = a3.w * s0 + pa * s1;
        m = mc;
    }
    if (quarter == 0) {
        const float inv = 1.f / (d + 1e-16f);
        float4* op = (float4*)(xio + n * 128 + h * 16);
        float4 o0 = op[0], o1 = op[1], o2 = op[2], o3 = op[3];
        o0.x += a0.x * inv; o0.y += a0.y * inv; o0.z += a0.z * inv; o0.w += a0.w * inv;
        o1.x += a1.x * inv; o1.y += a1.y * inv; o1.z += a1.z * inv; o1.w += a1.w * inv;
        o2.x += a2.x * inv; o2.y += a2.y * inv; o2.z += a2.z * inv; o2.w += a2.w * inv;
        o3.x += a3.x * inv; o3.y += a3.y * inv; o3.z += a3.z * inv; o3.w += a3.w * inv;
        op[0] = o0; op[1] = o1; op[2] = o2; op[3] = o3;
    }
}

// ---------------------------------------------------------------- readout (2-phase, fused gate)
__global__ __launch_bounds__(128)
void pool_partial(const float* __restrict__ x, const float* __restrict__ wg,
                  const float* __restrict__ bg, const int* __restrict__ starts,
                  float* __restrict__ psum, float* __restrict__ pmax) {
    const int g  = blockIdx.x / PCH;
    const int ch = blockIdx.x % PCH;
    const int c  = threadIdx.x;
    const int s0 = starts[g], s1 = starts[g + 1];
    const int total = s1 - s0;
    const int len = (total + PCH - 1) / PCH;
    const int n0 = s0 + ch * len;
    const int n1 = min(n0 + len, s1);
    const float w = wg[c];
    const float b = bg[0];
    __shared__ float red[2];
    float sum = 0.f, mx = -__builtin_inff();
    for (int n = n0; n < n1; ++n) {
        const float xv = x[n * 128 + c];
        float p = xv * w;
        #pragma unroll
        for (int o = 32; o; o >>= 1) p += __shfl_xor(p, o);
        if ((c & 63) == 0) red[c >> 6] = p;
        __syncthreads();
        const float dot = red[0] + red[1];
        __syncthreads();
        const float score = 1.f / (1.f + __expf(-(dot + b)));
        sum += score * xv;
        mx = fmaxf(mx, xv);
    }
    psum[blockIdx.x * 128 + c] = sum;
    pmax[blockIdx.x * 128 + c] = mx;
}

__global__ __launch_bounds__(128)
void pool_final(const float* __restrict__ psum, const float* __restrict__ pmax,
                float* __restrict__ out) {
    const int g = blockIdx.x, c = threadIdx.x;
    float s = 0.f, m = -__builtin_inff();
    #pragma unroll
    for (int ch = 0; ch < PCH; ++ch) {
        s += psum[(g * PCH + ch) * 128 + c];
        m = fmaxf(m, pmax[(g * PCH + ch) * 128 + c]);
    }
    out[g * 256 + c] = s;
    out[g * 256 + 128 + c] = m;
}

// ---------------------------------------------------------------- launch
extern "C" void kernel_launch(void* const* d_in, const int* in_sizes, int n_in,
                              void* d_out, int out_size, void* d_ws, size_t ws_size,
                              hipStream_t stream) {
    const float* x     = (const float*)d_in[0];
    const int*   ei    = (const int*)d_in[1];
    const int*   batch = (const int*)d_in[2];
    const float* Wq = (const float*)d_in[3];
    const float* bq = (const float*)d_in[4];
    const float* Wk = (const float*)d_in[5];
    const float* bk = (const float*)d_in[6];
    const float* Wv = (const float*)d_in[7];
    const float* bv = (const float*)d_in[8];
    const float* Ws = (const float*)d_in[9];
    const float* bs = (const float*)d_in[10];
    const float* wg = (const float*)d_in[11];
    const float* bg = (const float*)d_in[12];
    float* out = (float*)d_out;

    char* w = (char*)d_ws;
    float* qb            = (float*)w;          w += (size_t)NN * 128 * 4;
    unsigned short* kvb  = (unsigned short*)w; w += (size_t)NN * 256 * 2;
    float* bufA          = (float*)w;          w += (size_t)NN * 128 * 4;
    float* bufB          = (float*)w;          w += (size_t)NN * 128 * 4;
    float* psum          = (float*)w;          w += (size_t)GG * PCH * 128 * 4;
    float* pmax          = (float*)w;          w += (size_t)GG * PCH * 128 * 4;
    unsigned short* wfh  = (unsigned short*)w; w += (size_t)12 * 16384 * 2;
    unsigned short* wfl  = (unsigned short*)w; w += (size_t)12 * 16384 * 2;
    int* counts          = (int*)w;            w += (size_t)NN * 4;
    int* offsets         = (int*)w;            w += (size_t)(NN + 1) * 4;
    int* bsums           = (int*)w;            w += (size_t)256 * 4;
    int* dhist           = (int*)w;            w += (size_t)256 * 4;
    int* dcur            = (int*)w;            w += (size_t)256 * 4;
    int* perm            = (int*)w;            w += (size_t)NN * 4;
    int* csrc            = (int*)w;            w += (size_t)EE * 4;
    int* starts          = (int*)w;            w += (size_t)(GG + 1) * 4;

    const int* srcI = ei;
    const int* dstI = ei + EE;

    // CSR over dst (reused by all 3 layers) + degree-sorted perm + weight prep
    hipMemsetAsync(counts, 0, (size_t)NN * 4, stream);
    hipMemsetAsync(dhist, 0, 256 * 4, stream);
    hipMemsetAsync(dcur, 0, 256 * 4, stream);
    hist_kernel<<<(EE + 255) / 256, 256, 0, stream>>>(dstI, counts);
    block_scan<<<SCB, 256, 0, stream>>>(counts, offsets, bsums);
    scan_sums<<<1, 256, 0, stream>>>(bsums);
    add_base<<<SCB, 256, 0, stream>>>(offsets, bsums);
    deg_hist<<<SCB, 256, 0, stream>>>(counts, dhist);
    deg_scan<<<1, 256, 0, stream>>>(dhist);
    deg_scatter<<<SCB, 256, 0, stream>>>(counts, dhist, dcur, perm);
    hipMemsetAsync(counts, 0, (size_t)NN * 4, stream);  // reuse as cursor
    scatter_kernel<<<(EE + 255) / 256, 256, 0, stream>>>(srcI, dstI, offsets, counts, csrc);
    starts_kernel<<<(NN + 256) / 256, 256, 0, stream>>>(batch, starts);
    prep_weights<<<dim3(12, 8), 256, 0, stream>>>(Wq, Wk, Wv, Ws, wfh, wfl);

    const float* xin = x;
    float* bufs[2] = {bufA, bufB};
    const int gemmBlocks = (NN + 63) / 64;   // 782
    const int attnBlocks = NN / 8;           // 6250, exact
    for (int l = 0; l < 3; ++l) {
        float* xs = bufs[l & 1];
        gemm_mfma<<<gemmBlocks, 256, 0, stream>>>(
            xin, wfh + (size_t)l * 4 * 16384, wfl + (size_t)l * 4 * 16384,
            bq + (size_t)l * 128, bk + (size_t)l * 128,
            bv + (size_t)l * 128, bs + (size_t)l * 128,
            qb, kvb, xs);
        attn_kernel<<<attnBlocks, 256, 0, stream>>>(qb, (const uint4*)kvb, xs, offsets, csrc, perm);
        xin = xs;
    }

    pool_partial<<<GG * PCH, 128, 0, stream>>>(xin, wg, bg, starts, psum, pmax);
    pool_final<<<GG, 128, 0, stream>>>(psum, pmax, out);
}

// Round 13
// 477.348 us; speedup vs baseline: 1.7190x; 1.0039x over previous
//
#include <hip/hip_runtime.h>
#include <hip/hip_bf16.h>

#define NN 50000
#define EE 800000
#define GG 64
#define PCH 16   // pooling chunks per graph
#define SCB ((NN + 255) / 256)   // 196 scan blocks
// D=128, H=8, C=16, L=3

typedef __attribute__((ext_vector_type(8)))  short          s16x8;
typedef __attribute__((ext_vector_type(8)))  unsigned short u16x8;
typedef __attribute__((ext_vector_type(16))) float          f32x16;

// bf16 helpers (bit-pattern based)
union BFU { __hip_bfloat16 h; unsigned short u; };
__device__ __forceinline__ unsigned short f2bf(float f) {
    BFU b; b.h = __float2bfloat16(f); return b.u;
}
#define B2F_LO(u) __uint_as_float((u) << 16)
#define B2F_HI(u) __uint_as_float((u) & 0xffff0000u)
#define BF2F(us)  __uint_as_float(((unsigned)(us)) << 16)

// ---------------------------------------------------------------- CSR build
__global__ __launch_bounds__(256) void hist_kernel(const int* __restrict__ dst,
                                                   int* __restrict__ counts) {
    int e = blockIdx.x * 256 + threadIdx.x;
    if (e < EE) atomicAdd(&counts[dst[e]], 1);
}

__global__ __launch_bounds__(256)
void block_scan(const int* __restrict__ counts, int* __restrict__ offsets,
                int* __restrict__ bsums) {
    __shared__ int sm[256];
    const int t = threadIdx.x;
    const int i = blockIdx.x * 256 + t;
    const int v = (i < NN) ? counts[i] : 0;
    sm[t] = v;
    __syncthreads();
    for (int off = 1; off < 256; off <<= 1) {
        int val = (t >= off) ? sm[t - off] : 0;
        __syncthreads();
        sm[t] += val;
        __syncthreads();
    }
    if (i < NN) offsets[i] = sm[t] - v;      // exclusive
    if (t == 255) bsums[blockIdx.x] = sm[255];
}

__global__ __launch_bounds__(256)
void scan_sums(int* __restrict__ bsums) {   // in-place -> exclusive block bases
    __shared__ int sm[256];
    const int t = threadIdx.x;
    const int v = (t < SCB) ? bsums[t] : 0;
    sm[t] = v;
    __syncthreads();
    for (int off = 1; off < 256; off <<= 1) {
        int val = (t >= off) ? sm[t - off] : 0;
        __syncthreads();
        sm[t] += val;
        __syncthreads();
    }
    if (t < SCB) bsums[t] = sm[t] - v;       // exclusive base
}

__global__ __launch_bounds__(256)
void add_base(int* __restrict__ offsets, const int* __restrict__ bsums) {
    const int i = blockIdx.x * 256 + threadIdx.x;
    if (i < NN) offsets[i] += bsums[blockIdx.x];
    if (i == 0) offsets[NN] = EE;            // total edges is a constant
}

__global__ __launch_bounds__(256) void scatter_kernel(const int* __restrict__ src,
                                                      const int* __restrict__ dst,
                                                      const int* __restrict__ offs,
                                                      int* __restrict__ cursor,
                                                      int* __restrict__ csrc) {
    int e = blockIdx.x * 256 + threadIdx.x;
    if (e < EE) {
        int dn = dst[e];
        int p = atomicAdd(&cursor[dn], 1);
        csrc[offs[dn] + p] = src[e];
    }
}

__global__ __launch_bounds__(256) void starts_kernel(const int* __restrict__ batch,
                                                     int* __restrict__ starts) {
    int i = blockIdx.x * 256 + threadIdx.x;
    if (i > NN) return;
    int b  = (i < NN) ? batch[i] : GG;
    int bp = (i == 0) ? -1 : batch[i - 1];
    for (int g = bp + 1; g <= b && g <= GG; ++g) starts[g] = i;
}

// ---- degree-sorted node permutation (equalizes trip counts per wave) ----
__global__ __launch_bounds__(256)
void deg_hist(const int* __restrict__ counts, int* __restrict__ dhist) {
    __shared__ int lh[256];
    const int t = threadIdx.x;
    lh[t] = 0;
    __syncthreads();
    const int i = blockIdx.x * 256 + t;
    if (i < NN) atomicAdd(&lh[min(counts[i], 255)], 1);
    __syncthreads();
    if (lh[t]) atomicAdd(&dhist[t], lh[t]);
}

__global__ __launch_bounds__(256)
void deg_scan(int* __restrict__ dhist) {     // in-place -> exclusive bases
    __shared__ int sm[256];
    const int t = threadIdx.x;
    const int v = dhist[t];
    sm[t] = v;
    __syncthreads();
    for (int off = 1; off < 256; off <<= 1) {
        int val = (t >= off) ? sm[t - off] : 0;
        __syncthreads();
        sm[t] += val;
        __syncthreads();
    }
    dhist[t] = sm[t] - v;                    // exclusive base
}

__global__ __launch_bounds__(256)
void deg_scatter(const int* __restrict__ counts, const int* __restrict__ dbase,
                 int* __restrict__ dcur, int* __restrict__ perm) {
    __shared__ int lh[256];   // per-bin count in this block
    __shared__ int lb[256];   // block's reserved chunk base within bin
    const int t = threadIdx.x;
    lh[t] = 0;
    __syncthreads();
    const int i = blockIdx.x * 256 + t;
    int d = 0, r = 0;
    if (i < NN) {
        d = min(counts[i], 255);
        r = atomicAdd(&lh[d], 1);            // rank within block (LDS speed)
    }
    __syncthreads();
    if (lh[t]) lb[t] = atomicAdd(&dcur[t], lh[t]);   // one global atomic per bin
    __syncthreads();
    if (i < NN) perm[dbase[d] + lb[d] + r] = i;
}

// ---------------------------------------------------------------- weight prep
// W[l][k][c] fp32 -> B-FRAGMENT-ORDER split-bf16:
//   wf[mat][(kk*128 + col)*8 + j] = W[kk*8 + j][col],  kk = K-chunk 0..15.
__global__ __launch_bounds__(256)
void prep_weights(const float* __restrict__ Wq, const float* __restrict__ Wk,
                  const float* __restrict__ Wv, const float* __restrict__ Ws,
                  unsigned short* __restrict__ wfh, unsigned short* __restrict__ wfl) {
    const int mat = blockIdx.x;           // 0..11
    const int l = mat >> 2, m = mat & 3;
    const float* W;
    switch (m) {
        case 0:  W = Wq; break;
        case 1:  W = Wk; break;
        case 2:  W = Wv; break;
        default: W = Ws; break;
    }
    W += (size_t)l * 16384;
    const int t = threadIdx.x;
    const int col = blockIdx.y * 16 + (t >> 4);
    const int kk  = t & 15;               // chunk of 8 K values
    u16x8 hi, lo;
    #pragma unroll
    for (int j = 0; j < 8; ++j) {
        float w = W[(kk * 8 + j) * 128 + col];
        unsigned short uh = f2bf(w);
        hi[j] = uh;
        lo[j] = f2bf(w - BF2F(uh));
    }
    const size_t o = (size_t)mat * 16384 + ((size_t)kk * 128 + col) * 8;
    *(u16x8*)(wfh + o) = hi;
    *(u16x8*)(wfl + o) = lo;
}

// ---------------------------------------------------------------- MFMA GEMM
// One barrier total (x stage). B-frags stream from global (L2-hot, 192KB/layer)
// in fragment order. Split-bf16 3-term for q (m=0) and skip xs (m=3);
// single hi-term for k,v (packed to bf16 anyway).
__global__ __launch_bounds__(256)
void gemm_mfma(const float* __restrict__ xin,
               const unsigned short* __restrict__ wHg,   // + l*4*16384, frag order
               const unsigned short* __restrict__ wLg,
               const float* __restrict__ bq, const float* __restrict__ bk,
               const float* __restrict__ bv, const float* __restrict__ bs,
               float* __restrict__ q, unsigned short* __restrict__ kvb,
               float* __restrict__ xs) {
    __shared__ unsigned short xl[16384];   // [0..8191]=hi, [8192..]=lo
    const int t = threadIdx.x;
    const int n0 = blockIdx.x * 64;

    // ---- stage x (fp32 -> split bf16, swizzled) ----
    const float4* X4 = (const float4*)xin;
    for (int i = t; i < 1024; i += 256) {            // 64 rows x 16 chunks
        const int row = i >> 4, ch = i & 15;
        const int node = n0 + row;
        float4 fa = make_float4(0.f, 0.f, 0.f, 0.f);
        float4 fb = make_float4(0.f, 0.f, 0.f, 0.f);
        if (node < NN) { fa = X4[node * 32 + ch * 2]; fb = X4[node * 32 + ch * 2 + 1]; }
        const float fv[8] = {fa.x, fa.y, fa.z, fa.w, fb.x, fb.y, fb.z, fb.w};
        u16x8 hi, lo;
        #pragma unroll
        for (int j = 0; j < 8; ++j) {
            unsigned short uh = f2bf(fv[j]);
            hi[j] = uh;
            lo[j] = f2bf(fv[j] - BF2F(uh));
        }
        const int base = row * 128 + (ch ^ (row & 7)) * 8;
        *(u16x8*)&xl[base] = hi;
        *(u16x8*)&xl[8192 + base] = lo;
    }
    __syncthreads();

    // ---- per-wave tile & A-fragments (held in regs for all 4 matrices) ----
    const int lane = t & 63, wid = t >> 6;
    const int r = lane & 31, g = lane >> 5;
    const int nt = (wid & 1) * 32;        // node offset in tile
    const int cb = (wid >> 1) * 64;       // col base
    s16x8 ah[8], al[8];
    {
        const int row = nt + r;
        const int s = row & 7;
        const int rb = row * 128;
        #pragma unroll
        for (int kc = 0; kc < 8; ++kc) {
            const int idx = rb + (((kc << 1) | g) ^ s) * 8;
            ah[kc] = *(const s16x8*)&xl[idx];
            al[kc] = *(const s16x8*)&xl[8192 + idx];
        }
    }
    const int col0 = cb + r, col1 = cb + 32 + r;

    #pragma unroll
    for (int m = 0; m < 4; ++m) {
        const bool split = (m == 0 || m == 3);
        const unsigned short* WH = wHg + m * 16384;
        const unsigned short* WL = wLg + m * 16384;
        f32x16 acc0, acc1;
        #pragma unroll
        for (int j = 0; j < 16; ++j) { acc0[j] = 0.f; acc1[j] = 0.f; }

        #pragma unroll
        for (int kc = 0; kc < 8; ++kc) {
            const int kk = (kc << 1) | g;
            const s16x8 b0 = *(const s16x8*)&WH[(kk * 128 + col0) * 8];
            const s16x8 b1 = *(const s16x8*)&WH[(kk * 128 + col1) * 8];
            acc0 = __builtin_amdgcn_mfma_f32_32x32x16_bf16(ah[kc], b0, acc0, 0, 0, 0);
            acc1 = __builtin_amdgcn_mfma_f32_32x32x16_bf16(ah[kc], b1, acc1, 0, 0, 0);
            if (split) {
                acc0 = __builtin_amdgcn_mfma_f32_32x32x16_bf16(al[kc], b0, acc0, 0, 0, 0);
                acc1 = __builtin_amdgcn_mfma_f32_32x32x16_bf16(al[kc], b1, acc1, 0, 0, 0);
                const s16x8 c0 = *(const s16x8*)&WL[(kk * 128 + col0) * 8];
                const s16x8 c1 = *(const s16x8*)&WL[(kk * 128 + col1) * 8];
                acc0 = __builtin_amdgcn_mfma_f32_32x32x16_bf16(ah[kc], c0, acc0, 0, 0, 0);
                acc1 = __builtin_amdgcn_mfma_f32_32x32x16_bf16(ah[kc], c1, acc1, 0, 0, 0);
            }
        }

        // ---- epilogue ----
        const float* bp;
        switch (m) {
            case 0:  bp = bq; break;
            case 1:  bp = bk; break;
            case 2:  bp = bv; break;
            default: bp = bs; break;
        }
        const float b0 = bp[col0], b1 = bp[col1];
        if (m == 0 || m == 3) {
            float* outp = (m == 0) ? q : xs;
            #pragma unroll
            for (int reg = 0; reg < 16; ++reg) {
                const int node = n0 + nt + (reg & 3) + 8 * (reg >> 2) + 4 * g;
                if (node < NN) {
                    outp[node * 128 + col0] = acc0[reg] + b0;
                    outp[node * 128 + col1] = acc1[reg] + b1;
                }
            }
        } else {
            const int koff = (m == 1) ? 0 : 16;      // k at +0, v at +16 (ushorts)
            const int o0 = (col0 >> 4) * 32 + koff + (col0 & 15);
            const int o1 = (col1 >> 4) * 32 + koff + (col1 & 15);
            #pragma unroll
            for (int reg = 0; reg < 16; ++reg) {
                const int node = n0 + nt + (reg & 3) + 8 * (reg >> 2) + 4 * g;
                if (node < NN) {
                    kvb[(size_t)node * 256 + o0] = f2bf(acc0[reg] + b0);
                    kvb[(size_t)node * 256 + o1] = f2bf(acc1[reg] + b1);
                }
            }
        }
    }
}

// ---------------------------------------------------------------- attention (CSR, online softmax)
// thread = (node, head, edge-quarter): 32 threads/node, two-round shfl merge.
// LPT: traverse perm in DESCENDING degree order so heavy blocks dispatch
// first (round-12 Occupancy 52% was the ascending-order dispatch tail).
// Prefetch depth 2: three kv rows in flight per thread.
__global__ __launch_bounds__(256)
void attn_kernel(const float* __restrict__ q, const uint4* __restrict__ kv4,
                 float* __restrict__ xio,
                 const int* __restrict__ offs, const int* __restrict__ csrc,
                 const int* __restrict__ perm) {
    const int t = threadIdx.x;
    const int h = t & 7;
    const int quarter = (t >> 3) & 3;
    const int idx = blockIdx.x * 8 + (t >> 5);
    const int n = perm[NN - 1 - idx];              // LPT order
    const float4* qp = (const float4*)(q + n * 128 + h * 16);
    const float4 q0 = qp[0], q1 = qp[1], q2 = qp[2], q3 = qp[3];
    float m = -__builtin_inff();
    float d = 0.f;
    float4 a0 = {}, a1 = {}, a2 = {}, a3 = {};
    const int e0 = offs[n], e1 = offs[n + 1];
    const int estart = e0 + quarter;
    if (estart < e1) {
        uint4 ka, kb, va, vb;                       // current
        { const uint4* p = kv4 + (size_t)csrc[estart] * 32 + h * 4;
          ka = p[0]; kb = p[1]; va = p[2]; vb = p[3]; }
        uint4 na, nb, nc, nd;                       // next
        if (estart + 4 < e1) {
            const uint4* p = kv4 + (size_t)csrc[estart + 4] * 32 + h * 4;
            na = p[0]; nb = p[1]; nc = p[2]; nd = p[3];
        }
        for (int ec = estart; ec < e1; ec += 4) {
            uint4 fa, fb, fc, fd;                   // next-next
            if (ec + 8 < e1) {
                const uint4* p = kv4 + (size_t)csrc[ec + 8] * 32 + h * 4;
                fa = p[0]; fb = p[1]; fc = p[2]; fd = p[3];
            }
            float dot =
                q0.x * B2F_LO(ka.x) + q0.y * B2F_HI(ka.x) + q0.z * B2F_LO(ka.y) + q0.w * B2F_HI(ka.y)
              + q1.x * B2F_LO(ka.z) + q1.y * B2F_HI(ka.z) + q1.z * B2F_LO(ka.w) + q1.w * B2F_HI(ka.w)
              + q2.x * B2F_LO(kb.x) + q2.y * B2F_HI(kb.x) + q2.z * B2F_LO(kb.y) + q2.w * B2F_HI(kb.y)
              + q3.x * B2F_LO(kb.z) + q3.y * B2F_HI(kb.z) + q3.z * B2F_LO(kb.w) + q3.w * B2F_HI(kb.w);
            const float alpha = dot * 0.25f;        // / sqrt(C=16)
            const float nm = fmaxf(m, alpha);
            const float scale = __expf(m - nm);     // 0 on first edge
            const float p = __expf(alpha - nm);
            d = d * scale + p;
            a0.x = a0.x * scale + p * B2F_LO(va.x); a0.y = a0.y * scale + p * B2F_HI(va.x);
            a0.z = a0.z * scale + p * B2F_LO(va.y); a0.w = a0.w * scale + p * B2F_HI(va.y);
            a1.x = a1.x * scale + p * B2F_LO(va.z); a1.y = a1.y * scale + p * B2F_HI(va.z);
            a1.z = a1.z * scale + p * B2F_LO(va.w); a1.w = a1.w * scale + p * B2F_HI(va.w);
            a2.x = a2.x * scale + p * B2F_LO(vb.x); a2.y = a2.y * scale + p * B2F_HI(vb.x);
            a2.z = a2.z * scale + p * B2F_LO(vb.y); a2.w = a2.w * scale + p * B2F_HI(vb.y);
            a3.x = a3.x * scale + p * B2F_LO(vb.z); a3.y = a3.y * scale + p * B2F_HI(vb.z);
            a3.z = a3.z * scale + p * B2F_LO(vb.w); a3.w = a3.w * scale + p * B2F_HI(vb.w);
            m = nm;
            ka = na; kb = nb; va = nc; vb = nd;     // shift pipeline
            na = fa; nb = fb; nc = fc; nd = fd;
        }
    }
    // ---- merge the four quarter-streams (exact in fp32): xor 8, then 16 ----
    #pragma unroll
    for (int o = 8; o <= 16; o <<= 1) {
        const float mp = __shfl_xor(m, o);
        const float dp = __shfl_xor(d, o);
        const float mc = fmaxf(fmaxf(m, mp), -1e30f);  // -1e30 guard: empty-stream NaN
        const float s0 = __expf(m - mc);
        const float s1 = __expf(mp - mc);
        d = d * s0 + dp * s1;
        float pa;
        pa = __shfl_xor(a0.x, o); a0.x = a0.x * s0 + pa * s1;
        pa = __shfl_xor(a0.y, o); a0.y = a0.y * s0 + pa * s1;
        pa = __shfl_xor(a0.z, o); a0.z = a0.z * s0 + pa * s1;
        pa = __shfl_xor(a0.w, o); a0.w = a0.w * s0 + pa * s1;
        pa = __shfl_xor(a1.x, o); a1.x = a1.x * s0 + pa * s1;
        pa = __shfl_xor(a1.y, o); a1.y = a1.y * s0 + pa * s1;
        pa = __shfl_xor(a1.z, o); a1.z = a1.z * s0 + pa * s1;
        pa = __shfl_xor(a1.w, o); a1.w = a1.w * s0 + pa * s1;
        pa = __shfl_xor(a2.x, o); a2.x = a2.x * s0 + pa * s1;
        pa = __shfl_xor(a2.y, o); a2.y = a2.y * s0 + pa * s1;
        pa = __shfl_xor(a2.z, o); a2.z = a2.z * s0 + pa * s1;
        pa = __shfl_xor(a2.w, o); a2.w = a2.w * s0 + pa * s1;
        pa = __shfl_xor(a3.x, o); a3.x = a3.x * s0 + pa * s1;
        pa = __shfl_xor(a3.y, o); a3.y = a3.y * s0 + pa * s1;
        pa = __shfl_xor(a3.z, o); a3.z = a3.z * s0 + pa * s1;
        pa = __shfl_xor(a3.w, o); a3.w = a3.w * s0 + pa * s1;
        m = mc;
    }
    if (quarter == 0) {
        const float inv = 1.f / (d + 1e-16f);
        float4* op = (float4*)(xio + n * 128 + h * 16);
        float4 o0 = op[0], o1 = op[1], o2 = op[2], o3 = op[3];
        o0.x += a0.x * inv; o0.y += a0.y * inv; o0.z += a0.z * inv; o0.w += a0.w * inv;
        o1.x += a1.x * inv; o1.y += a1.y * inv; o1.z += a1.z * inv; o1.w += a1.w * inv;
        o2.x += a2.x * inv; o2.y += a2.y * inv; o2.z += a2.z * inv; o2.w += a2.w * inv;
        o3.x += a3.x * inv; o3.y += a3.y * inv; o3.z += a3.z * inv; o3.w += a3.w * inv;
        op[0] = o0; op[1] = o1; op[2] = o2; op[3] = o3;
    }
}

// ---------------------------------------------------------------- readout (2-phase, fused gate)
__global__ __launch_bounds__(128)
void pool_partial(const float* __restrict__ x, const float* __restrict__ wg,
                  const float* __restrict__ bg, const int* __restrict__ starts,
                  float* __restrict__ psum, float* __restrict__ pmax) {
    const int g  = blockIdx.x / PCH;
    const int ch = blockIdx.x % PCH;
    const int c  = threadIdx.x;
    const int s0 = starts[g], s1 = starts[g + 1];
    const int total = s1 - s0;
    const int len = (total + PCH - 1) / PCH;
    const int n0 = s0 + ch * len;
    const int n1 = min(n0 + len, s1);
    const float w = wg[c];
    const float b = bg[0];
    __shared__ float red[2];
    float sum = 0.f, mx = -__builtin_inff();
    for (int n = n0; n < n1; ++n) {
        const float xv = x[n * 128 + c];
        float p = xv * w;
        #pragma unroll
        for (int o = 32; o; o >>= 1) p += __shfl_xor(p, o);
        if ((c & 63) == 0) red[c >> 6] = p;
        __syncthreads();
        const float dot = red[0] + red[1];
        __syncthreads();
        const float score = 1.f / (1.f + __expf(-(dot + b)));
        sum += score * xv;
        mx = fmaxf(mx, xv);
    }
    psum[blockIdx.x * 128 + c] = sum;
    pmax[blockIdx.x * 128 + c] = mx;
}

__global__ __launch_bounds__(128)
void pool_final(const float* __restrict__ psum, const float* __restrict__ pmax,
                float* __restrict__ out) {
    const int g = blockIdx.x, c = threadIdx.x;
    float s = 0.f, m = -__builtin_inff();
    #pragma unroll
    for (int ch = 0; ch < PCH; ++ch) {
        s += psum[(g * PCH + ch) * 128 + c];
        m = fmaxf(m, pmax[(g * PCH + ch) * 128 + c]);
    }
    out[g * 256 + c] = s;
    out[g * 256 + 128 + c] = m;
}

// ---------------------------------------------------------------- launch
extern "C" void kernel_launch(void* const* d_in, const int* in_sizes, int n_in,
                              void* d_out, int out_size, void* d_ws, size_t ws_size,
                              hipStream_t stream) {
    const float* x     = (const float*)d_in[0];
    const int*   ei    = (const int*)d_in[1];
    const int*   batch = (const int*)d_in[2];
    const float* Wq = (const float*)d_in[3];
    const float* bq = (const float*)d_in[4];
    const float* Wk = (const float*)d_in[5];
    const float* bk = (const float*)d_in[6];
    const float* Wv = (const float*)d_in[7];
    const float* bv = (const float*)d_in[8];
    const float* Ws = (const float*)d_in[9];
    const float* bs = (const float*)d_in[10];
    const float* wg = (const float*)d_in[11];
    const float* bg = (const float*)d_in[12];
    float* out = (float*)d_out;

    char* w = (char*)d_ws;
    float* qb            = (float*)w;          w += (size_t)NN * 128 * 4;
    unsigned short* kvb  = (unsigned short*)w; w += (size_t)NN * 256 * 2;
    float* bufA          = (float*)w;          w += (size_t)NN * 128 * 4;
    float* bufB          = (float*)w;          w += (size_t)NN * 128 * 4;
    float* psum          = (float*)w;          w += (size_t)GG * PCH * 128 * 4;
    float* pmax          = (float*)w;          w += (size_t)GG * PCH * 128 * 4;
    unsigned short* wfh  = (unsigned short*)w; w += (size_t)12 * 16384 * 2;
    unsigned short* wfl  = (unsigned short*)w; w += (size_t)12 * 16384 * 2;
    int* counts          = (int*)w;            w += (size_t)NN * 4;
    int* offsets         = (int*)w;            w += (size_t)(NN + 1) * 4;
    int* bsums           = (int*)w;            w += (size_t)256 * 4;
    int* dhist           = (int*)w;            w += (size_t)256 * 4;
    int* dcur            = (int*)w;            w += (size_t)256 * 4;
    int* perm            = (int*)w;            w += (size_t)NN * 4;
    int* csrc            = (int*)w;            w += (size_t)EE * 4;
    int* starts          = (int*)w;            w += (size_t)(GG + 1) * 4;

    const int* srcI = ei;
    const int* dstI = ei + EE;

    // CSR over dst (reused by all 3 layers) + degree-sorted perm + weight prep
    hipMemsetAsync(counts, 0, (size_t)NN * 4, stream);
    hipMemsetAsync(dhist, 0, 256 * 4, stream);
    hipMemsetAsync(dcur, 0, 256 * 4, stream);
    hist_kernel<<<(EE + 255) / 256, 256, 0, stream>>>(dstI, counts);
    block_scan<<<SCB, 256, 0, stream>>>(counts, offsets, bsums);
    scan_sums<<<1, 256, 0, stream>>>(bsums);
    add_base<<<SCB, 256, 0, stream>>>(offsets, bsums);
    deg_hist<<<SCB, 256, 0, stream>>>(counts, dhist);
    deg_scan<<<1, 256, 0, stream>>>(dhist);
    deg_scatter<<<SCB, 256, 0, stream>>>(counts, dhist, dcur, perm);
    hipMemsetAsync(counts, 0, (size_t)NN * 4, stream);  // reuse as cursor
    scatter_kernel<<<(EE + 255) / 256, 256, 0, stream>>>(srcI, dstI, offsets, counts, csrc);
    starts_kernel<<<(NN + 256) / 256, 256, 0, stream>>>(batch, starts);
    prep_weights<<<dim3(12, 8), 256, 0, stream>>>(Wq, Wk, Wv, Ws, wfh, wfl);

    const float* xin = x;
    float* bufs[2] = {bufA, bufB};
    const int gemmBlocks = (NN + 63) / 64;   // 782
    const int attnBlocks = NN / 8;           // 6250, exact
    for (int l = 0; l < 3; ++l) {
        float* xs = bufs[l & 1];
        gemm_mfma<<<gemmBlocks, 256, 0, stream>>>(
            xin, wfh + (size_t)l * 4 * 16384, wfl + (size_t)l * 4 * 16384,
            bq + (size_t)l * 128, bk + (size_t)l * 128,
            bv + (size_t)l * 128, bs + (size_t)l * 128,
            qb, kvb, xs);
        attn_kernel<<<attnBlocks, 256, 0, stream>>>(qb, (const uint4*)kvb, xs, offsets, csrc, perm);
        xin = xs;
    }

    pool_partial<<<GG * PCH, 128, 0, stream>>>(xin, wg, bg, starts, psum, pmax);
    pool_final<<<GG, 128, 0, stream>>>(psum, pmax, out);
}

// Round 14
// 442.483 us; speedup vs baseline: 1.8545x; 1.0788x over previous
//
#include <hip/hip_runtime.h>
#include <hip/hip_bf16.h>

#define NN 50000
#define EE 800000
#define GG 64
#define PCH 16   // pooling chunks per graph
#define SCB ((NN + 255) / 256)   // 196 scan blocks
// D=128, H=8, C=16, L=3

typedef __attribute__((ext_vector_type(8)))  short          s16x8;
typedef __attribute__((ext_vector_type(8)))  unsigned short u16x8;
typedef __attribute__((ext_vector_type(16))) float          f32x16;

// bf16 helpers (bit-pattern based)
union BFU { __hip_bfloat16 h; unsigned short u; };
__device__ __forceinline__ unsigned short f2bf(float f) {
    BFU b; b.h = __float2bfloat16(f); return b.u;
}
#define B2F_LO(u) __uint_as_float((u) << 16)
#define B2F_HI(u) __uint_as_float((u) & 0xffff0000u)
#define BF2F(us)  __uint_as_float(((unsigned)(us)) << 16)

// ---------------------------------------------------------------- CSR build
__global__ __launch_bounds__(256) void hist_kernel(const int* __restrict__ dst,
                                                   int* __restrict__ counts) {
    int e = blockIdx.x * 256 + threadIdx.x;
    if (e < EE) atomicAdd(&counts[dst[e]], 1);
}

// block_scan fused with deg_hist (both consume counts[i] once)
__global__ __launch_bounds__(256)
void block_scan_deg(const int* __restrict__ counts, int* __restrict__ offsets,
                    int* __restrict__ bsums, int* __restrict__ dhist) {
    __shared__ int sm[256];
    __shared__ int lh[256];
    const int t = threadIdx.x;
    const int i = blockIdx.x * 256 + t;
    const int v = (i < NN) ? counts[i] : 0;
    lh[t] = 0;
    sm[t] = v;
    __syncthreads();
    if (i < NN) atomicAdd(&lh[min(v, 255)], 1);   // LDS histogram (visible after loop barriers)
    for (int off = 1; off < 256; off <<= 1) {
        int val = (t >= off) ? sm[t - off] : 0;
        __syncthreads();
        sm[t] += val;
        __syncthreads();
    }
    if (i < NN) offsets[i] = sm[t] - v;      // exclusive
    if (t == 255) bsums[blockIdx.x] = sm[255];
    if (lh[t]) atomicAdd(&dhist[t], lh[t]);
}

// one kernel, two blocks: block 0 scans bsums (SCB entries), block 1 scans dhist (256)
__global__ __launch_bounds__(256)
void scan2(int* __restrict__ bsums, int* __restrict__ dhist) {
    int* arr = (blockIdx.x == 0) ? bsums : dhist;
    const int lim = (blockIdx.x == 0) ? SCB : 256;
    __shared__ int sm[256];
    const int t = threadIdx.x;
    const int v = (t < lim) ? arr[t] : 0;
    sm[t] = v;
    __syncthreads();
    for (int off = 1; off < 256; off <<= 1) {
        int val = (t >= off) ? sm[t - off] : 0;
        __syncthreads();
        sm[t] += val;
        __syncthreads();
    }
    if (t < lim) arr[t] = sm[t] - v;         // exclusive
}

// add_base fused with starts_kernel (same index space)
__global__ __launch_bounds__(256)
void add_base_starts(int* __restrict__ offsets, const int* __restrict__ bsums,
                     const int* __restrict__ batch, int* __restrict__ starts) {
    const int i = blockIdx.x * 256 + threadIdx.x;
    if (i < NN) offsets[i] += bsums[blockIdx.x];
    if (i == 0) offsets[NN] = EE;            // total edges is a constant
    if (i <= NN) {
        int b  = (i < NN) ? batch[i] : GG;
        int bp = (i == 0) ? -1 : batch[i - 1];
        for (int g = bp + 1; g <= b && g <= GG; ++g) starts[g] = i;
    }
}

__global__ __launch_bounds__(256)
void deg_scatter(const int* __restrict__ counts, const int* __restrict__ dbase,
                 int* __restrict__ dcur, int* __restrict__ perm) {
    __shared__ int lh[256];   // per-bin count in this block
    __shared__ int lb[256];   // block's reserved chunk base within bin
    const int t = threadIdx.x;
    lh[t] = 0;
    __syncthreads();
    const int i = blockIdx.x * 256 + t;
    int d = 0, r = 0;
    if (i < NN) {
        d = min(counts[i], 255);
        r = atomicAdd(&lh[d], 1);            // rank within block (LDS speed)
    }
    __syncthreads();
    if (lh[t]) lb[t] = atomicAdd(&dcur[t], lh[t]);   // one global atomic per bin
    __syncthreads();
    if (i < NN) perm[dbase[d] + lb[d] + r] = i;
}

__global__ __launch_bounds__(256) void scatter_kernel(const int* __restrict__ src,
                                                      const int* __restrict__ dst,
                                                      const int* __restrict__ offs,
                                                      int* __restrict__ cursor,
                                                      int* __restrict__ csrc) {
    int e = blockIdx.x * 256 + threadIdx.x;
    if (e < EE) {
        int dn = dst[e];
        int p = atomicAdd(&cursor[dn], 1);
        csrc[offs[dn] + p] = src[e];
    }
}

// ---------------------------------------------------------------- weight prep
// W[l][k][c] fp32 -> B-FRAGMENT-ORDER split-bf16:
//   wf[mat][(kk*128 + col)*8 + j] = W[kk*8 + j][col],  kk = K-chunk 0..15.
__global__ __launch_bounds__(256)
void prep_weights(const float* __restrict__ Wq, const float* __restrict__ Wk,
                  const float* __restrict__ Wv, const float* __restrict__ Ws,
                  unsigned short* __restrict__ wfh, unsigned short* __restrict__ wfl) {
    const int mat = blockIdx.x;           // 0..11
    const int l = mat >> 2, m = mat & 3;
    const float* W;
    switch (m) {
        case 0:  W = Wq; break;
        case 1:  W = Wk; break;
        case 2:  W = Wv; break;
        default: W = Ws; break;
    }
    W += (size_t)l * 16384;
    const int t = threadIdx.x;
    const int col = blockIdx.y * 16 + (t >> 4);
    const int kk  = t & 15;               // chunk of 8 K values
    u16x8 hi, lo;
    #pragma unroll
    for (int j = 0; j < 8; ++j) {
        float w = W[(kk * 8 + j) * 128 + col];
        unsigned short uh = f2bf(w);
        hi[j] = uh;
        lo[j] = f2bf(w - BF2F(uh));
    }
    const size_t o = (size_t)mat * 16384 + ((size_t)kk * 128 + col) * 8;
    *(u16x8*)(wfh + o) = hi;
    *(u16x8*)(wfl + o) = lo;
}

// ---------------------------------------------------------------- MFMA GEMM
// Phases: Q (3-term), K+V interleaved (1-term each, 2x loads in flight),
// S (3-term). One barrier total; B-frags stream from L2 in fragment order.
__global__ __launch_bounds__(256)
void gemm_mfma(const float* __restrict__ xin,
               const unsigned short* __restrict__ wHg,   // + l*4*16384, frag order
               const unsigned short* __restrict__ wLg,
               const float* __restrict__ bq, const float* __restrict__ bk,
               const float* __restrict__ bv, const float* __restrict__ bs,
               float* __restrict__ q, unsigned short* __restrict__ kvb,
               float* __restrict__ xs) {
    __shared__ unsigned short xl[16384];   // [0..8191]=hi, [8192..]=lo
    const int t = threadIdx.x;
    const int n0 = blockIdx.x * 64;

    // ---- stage x (fp32 -> split bf16, swizzled) ----
    const float4* X4 = (const float4*)xin;
    for (int i = t; i < 1024; i += 256) {            // 64 rows x 16 chunks
        const int row = i >> 4, ch = i & 15;
        const int node = n0 + row;
        float4 fa = make_float4(0.f, 0.f, 0.f, 0.f);
        float4 fb = make_float4(0.f, 0.f, 0.f, 0.f);
        if (node < NN) { fa = X4[node * 32 + ch * 2]; fb = X4[node * 32 + ch * 2 + 1]; }
        const float fv[8] = {fa.x, fa.y, fa.z, fa.w, fb.x, fb.y, fb.z, fb.w};
        u16x8 hi, lo;
        #pragma unroll
        for (int j = 0; j < 8; ++j) {
            unsigned short uh = f2bf(fv[j]);
            hi[j] = uh;
            lo[j] = f2bf(fv[j] - BF2F(uh));
        }
        const int base = row * 128 + (ch ^ (row & 7)) * 8;
        *(u16x8*)&xl[base] = hi;
        *(u16x8*)&xl[8192 + base] = lo;
    }
    __syncthreads();

    // ---- per-wave tile & A-fragments ----
    const int lane = t & 63, wid = t >> 6;
    const int r = lane & 31, g = lane >> 5;
    const int nt = (wid & 1) * 32;        // node offset in tile
    const int cb = (wid >> 1) * 64;       // col base
    s16x8 ah[8], al[8];
    {
        const int row = nt + r;
        const int s = row & 7;
        const int rb = row * 128;
        #pragma unroll
        for (int kc = 0; kc < 8; ++kc) {
            const int idx = rb + (((kc << 1) | g) ^ s) * 8;
            ah[kc] = *(const s16x8*)&xl[idx];
            al[kc] = *(const s16x8*)&xl[8192 + idx];
        }
    }
    const int col0 = cb + r, col1 = cb + 32 + r;

    // ---- phase Q and phase S (3-term split-bf16) ----
    #pragma unroll
    for (int pm = 0; pm < 2; ++pm) {
        const int m = pm ? 3 : 0;
        const unsigned short* WH = wHg + m * 16384;
        const unsigned short* WL = wLg + m * 16384;
        f32x16 acc0, acc1;
        #pragma unroll
        for (int j = 0; j < 16; ++j) { acc0[j] = 0.f; acc1[j] = 0.f; }
        #pragma unroll
        for (int kc = 0; kc < 8; ++kc) {
            const int kk = (kc << 1) | g;
            const s16x8 b0 = *(const s16x8*)&WH[(kk * 128 + col0) * 8];
            const s16x8 b1 = *(const s16x8*)&WH[(kk * 128 + col1) * 8];
            const s16x8 c0 = *(const s16x8*)&WL[(kk * 128 + col0) * 8];
            const s16x8 c1 = *(const s16x8*)&WL[(kk * 128 + col1) * 8];
            acc0 = __builtin_amdgcn_mfma_f32_32x32x16_bf16(ah[kc], b0, acc0, 0, 0, 0);
            acc1 = __builtin_amdgcn_mfma_f32_32x32x16_bf16(ah[kc], b1, acc1, 0, 0, 0);
            acc0 = __builtin_amdgcn_mfma_f32_32x32x16_bf16(al[kc], b0, acc0, 0, 0, 0);
            acc1 = __builtin_amdgcn_mfma_f32_32x32x16_bf16(al[kc], b1, acc1, 0, 0, 0);
            acc0 = __builtin_amdgcn_mfma_f32_32x32x16_bf16(ah[kc], c0, acc0, 0, 0, 0);
            acc1 = __builtin_amdgcn_mfma_f32_32x32x16_bf16(ah[kc], c1, acc1, 0, 0, 0);
        }
        const float* bp = pm ? bs : bq;
        float* outp = pm ? xs : q;
        const float b0 = bp[col0], b1 = bp[col1];
        #pragma unroll
        for (int reg = 0; reg < 16; ++reg) {
            const int node = n0 + nt + (reg & 3) + 8 * (reg >> 2) + 4 * g;
            if (node < NN) {
                outp[node * 128 + col0] = acc0[reg] + b0;
                outp[node * 128 + col1] = acc1[reg] + b1;
            }
        }
    }

    // ---- phase K+V interleaved (single hi-term each; 4 loads in flight) ----
    {
        const unsigned short* WK = wHg + 1 * 16384;
        const unsigned short* WV = wHg + 2 * 16384;
        f32x16 ak0, ak1, av0, av1;
        #pragma unroll
        for (int j = 0; j < 16; ++j) { ak0[j] = 0.f; ak1[j] = 0.f; av0[j] = 0.f; av1[j] = 0.f; }
        #pragma unroll
        for (int kc = 0; kc < 8; ++kc) {
            const int kk = (kc << 1) | g;
            const s16x8 k0 = *(const s16x8*)&WK[(kk * 128 + col0) * 8];
            const s16x8 k1 = *(const s16x8*)&WK[(kk * 128 + col1) * 8];
            const s16x8 v0 = *(const s16x8*)&WV[(kk * 128 + col0) * 8];
            const s16x8 v1 = *(const s16x8*)&WV[(kk * 128 + col1) * 8];
            ak0 = __builtin_amdgcn_mfma_f32_32x32x16_bf16(ah[kc], k0, ak0, 0, 0, 0);
            ak1 = __builtin_amdgcn_mfma_f32_32x32x16_bf16(ah[kc], k1, ak1, 0, 0, 0);
            av0 = __builtin_amdgcn_mfma_f32_32x32x16_bf16(ah[kc], v0, av0, 0, 0, 0);
            av1 = __builtin_amdgcn_mfma_f32_32x32x16_bf16(ah[kc], v1, av1, 0, 0, 0);
        }
        const float bk0 = bk[col0], bk1 = bk[col1];
        const float bv0 = bv[col0], bv1 = bv[col1];
        // kv layout (ushorts): kvb[node*256 + h*32 + 0..15]=k, +16..31=v
        const int k0o = (col0 >> 4) * 32 + (col0 & 15);
        const int k1o = (col1 >> 4) * 32 + (col1 & 15);
        #pragma unroll
        for (int reg = 0; reg < 16; ++reg) {
            const int node = n0 + nt + (reg & 3) + 8 * (reg >> 2) + 4 * g;
            if (node < NN) {
                unsigned short* row = kvb + (size_t)node * 256;
                row[k0o]      = f2bf(ak0[reg] + bk0);
                row[k1o]      = f2bf(ak1[reg] + bk1);
                row[k0o + 16] = f2bf(av0[reg] + bv0);
                row[k1o + 16] = f2bf(av1[reg] + bv1);
            }
        }
    }
}

// ---------------------------------------------------------------- attention (CSR, online softmax)
// FROZEN (round 13): at memory-system roofline — 410MB/layer of irreducible
// random bf16 kv gathers served at ~6.4 TB/s. 32 threads/node, LPT order,
// prefetch depth 2, two-round shfl merge.
__global__ __launch_bounds__(256)
void attn_kernel(const float* __restrict__ q, const uint4* __restrict__ kv4,
                 float* __restrict__ xio,
                 const int* __restrict__ offs, const int* __restrict__ csrc,
                 const int* __restrict__ perm) {
    const int t = threadIdx.x;
    const int h = t & 7;
    const int quarter = (t >> 3) & 3;
    const int idx = blockIdx.x * 8 + (t >> 5);
    const int n = perm[NN - 1 - idx];              // LPT order
    const float4* qp = (const float4*)(q + n * 128 + h * 16);
    const float4 q0 = qp[0], q1 = qp[1], q2 = qp[2], q3 = qp[3];
    float m = -__builtin_inff();
    float d = 0.f;
    float4 a0 = {}, a1 = {}, a2 = {}, a3 = {};
    const int e0 = offs[n], e1 = offs[n + 1];
    const int estart = e0 + quarter;
    if (estart < e1) {
        uint4 ka, kb, va, vb;                       // current
        { const uint4* p = kv4 + (size_t)csrc[estart] * 32 + h * 4;
          ka = p[0]; kb = p[1]; va = p[2]; vb = p[3]; }
        uint4 na, nb, nc, nd;                       // next
        if (estart + 4 < e1) {
            const uint4* p = kv4 + (size_t)csrc[estart + 4] * 32 + h * 4;
            na = p[0]; nb = p[1]; nc = p[2]; nd = p[3];
        }
        for (int ec = estart; ec < e1; ec += 4) {
            uint4 fa, fb, fc, fd;                   // next-next
            if (ec + 8 < e1) {
                const uint4* p = kv4 + (size_t)csrc[ec + 8] * 32 + h * 4;
                fa = p[0]; fb = p[1]; fc = p[2]; fd = p[3];
            }
            float dot =
                q0.x * B2F_LO(ka.x) + q0.y * B2F_HI(ka.x) + q0.z * B2F_LO(ka.y) + q0.w * B2F_HI(ka.y)
              + q1.x * B2F_LO(ka.z) + q1.y * B2F_HI(ka.z) + q1.z * B2F_LO(ka.w) + q1.w * B2F_HI(ka.w)
              + q2.x * B2F_LO(kb.x) + q2.y * B2F_HI(kb.x) + q2.z * B2F_LO(kb.y) + q2.w * B2F_HI(kb.y)
              + q3.x * B2F_LO(kb.z) + q3.y * B2F_HI(kb.z) + q3.z * B2F_LO(kb.w) + q3.w * B2F_HI(kb.w);
            const float alpha = dot * 0.25f;        // / sqrt(C=16)
            const float nm = fmaxf(m, alpha);
            const float scale = __expf(m - nm);     // 0 on first edge
            const float p = __expf(alpha - nm);
            d = d * scale + p;
            a0.x = a0.x * scale + p * B2F_LO(va.x); a0.y = a0.y * scale + p * B2F_HI(va.x);
            a0.z = a0.z * scale + p * B2F_LO(va.y); a0.w = a0.w * scale + p * B2F_HI(va.y);
            a1.x = a1.x * scale + p * B2F_LO(va.z); a1.y = a1.y * scale + p * B2F_HI(va.z);
            a1.z = a1.z * scale + p * B2F_LO(va.w); a1.w = a1.w * scale + p * B2F_HI(va.w);
            a2.x = a2.x * scale + p * B2F_LO(vb.x); a2.y = a2.y * scale + p * B2F_HI(vb.x);
            a2.z = a2.z * scale + p * B2F_LO(vb.y); a2.w = a2.w * scale + p * B2F_HI(vb.y);
            a3.x = a3.x * scale + p * B2F_LO(vb.z); a3.y = a3.y * scale + p * B2F_HI(vb.z);
            a3.z = a3.z * scale + p * B2F_LO(vb.w); a3.w = a3.w * scale + p * B2F_HI(vb.w);
            m = nm;
            ka = na; kb = nb; va = nc; vb = nd;     // shift pipeline
            na = fa; nb = fb; nc = fc; nd = fd;
        }
    }
    // ---- merge the four quarter-streams (exact in fp32): xor 8, then 16 ----
    #pragma unroll
    for (int o = 8; o <= 16; o <<= 1) {
        const float mp = __shfl_xor(m, o);
        const float dp = __shfl_xor(d, o);
        const float mc = fmaxf(fmaxf(m, mp), -1e30f);  // -1e30 guard: empty-stream NaN
        const float s0 = __expf(m - mc);
        const float s1 = __expf(mp - mc);
        d = d * s0 + dp * s1;
        float pa;
        pa = __shfl_xor(a0.x, o); a0.x = a0.x * s0 + pa * s1;
        pa = __shfl_xor(a0.y, o); a0.y = a0.y * s0 + pa * s1;
        pa = __shfl_xor(a0.z, o); a0.z = a0.z * s0 + pa * s1;
        pa = __shfl_xor(a0.w, o); a0.w = a0.w * s0 + pa * s1;
        pa = __shfl_xor(a1.x, o); a1.x = a1.x * s0 + pa * s1;
        pa = __shfl_xor(a1.y, o); a1.y = a1.y * s0 + pa * s1;
        pa = __shfl_xor(a1.z, o); a1.z = a1.z * s0 + pa * s1;
        pa = __shfl_xor(a1.w, o); a1.w = a1.w * s0 + pa * s1;
        pa = __shfl_xor(a2.x, o); a2.x = a2.x * s0 + pa * s1;
        pa = __shfl_xor(a2.y, o); a2.y = a2.y * s0 + pa * s1;
        pa = __shfl_xor(a2.z, o); a2.z = a2.z * s0 + pa * s1;
        pa = __shfl_xor(a2.w, o); a2.w = a2.w * s0 + pa * s1;
        pa = __shfl_xor(a3.x, o); a3.x = a3.x * s0 + pa * s1;
        pa = __shfl_xor(a3.y, o); a3.y = a3.y * s0 + pa * s1;
        pa = __shfl_xor(a3.z, o); a3.z = a3.z * s0 + pa * s1;
        pa = __shfl_xor(a3.w, o); a3.w = a3.w * s0 + pa * s1;
        m = mc;
    }
    if (quarter == 0) {
        const float inv = 1.f / (d + 1e-16f);
        float4* op = (float4*)(xio + n * 128 + h * 16);
        float4 o0 = op[0], o1 = op[1], o2 = op[2], o3 = op[3];
        o0.x += a0.x * inv; o0.y += a0.y * inv; o0.z += a0.z * inv; o0.w += a0.w * inv;
        o1.x += a1.x * inv; o1.y += a1.y * inv; o1.z += a1.z * inv; o1.w += a1.w * inv;
        o2.x += a2.x * inv; o2.y += a2.y * inv; o2.z += a2.z * inv; o2.w += a2.w * inv;
        o3.x += a3.x * inv; o3.y += a3.y * inv; o3.z += a3.z * inv; o3.w += a3.w * inv;
        op[0] = o0; op[1] = o1; op[2] = o2; op[3] = o3;
    }
}

// ---------------------------------------------------------------- readout (2-phase, fused gate)
__global__ __launch_bounds__(128)
void pool_partial(const float* __restrict__ x, const float* __restrict__ wg,
                  const float* __restrict__ bg, const int* __restrict__ starts,
                  float* __restrict__ psum, float* __restrict__ pmax) {
    const int g  = blockIdx.x / PCH;
    const int ch = blockIdx.x % PCH;
    const int c  = threadIdx.x;
    const int s0 = starts[g], s1 = starts[g + 1];
    const int total = s1 - s0;
    const int len = (total + PCH - 1) / PCH;
    const int n0 = s0 + ch * len;
    const int n1 = min(n0 + len, s1);
    const float w = wg[c];
    const float b = bg[0];
    __shared__ float red[2];
    float sum = 0.f, mx = -__builtin_inff();
    for (int n = n0; n < n1; ++n) {
        const float xv = x[n * 128 + c];
        float p = xv * w;
        #pragma unroll
        for (int o = 32; o; o >>= 1) p += __shfl_xor(p, o);
        if ((c & 63) == 0) red[c >> 6] = p;
        __syncthreads();
        const float dot = red[0] + red[1];
        __syncthreads();
        const float score = 1.f / (1.f + __expf(-(dot + b)));
        sum += score * xv;
        mx = fmaxf(mx, xv);
    }
    psum[blockIdx.x * 128 + c] = sum;
    pmax[blockIdx.x * 128 + c] = mx;
}

__global__ __launch_bounds__(128)
void pool_final(const float* __restrict__ psum, const float* __restrict__ pmax,
                float* __restrict__ out) {
    const int g = blockIdx.x, c = threadIdx.x;
    float s = 0.f, m = -__builtin_inff();
    #pragma unroll
    for (int ch = 0; ch < PCH; ++ch) {
        s += psum[(g * PCH + ch) * 128 + c];
        m = fmaxf(m, pmax[(g * PCH + ch) * 128 + c]);
    }
    out[g * 256 + c] = s;
    out[g * 256 + 128 + c] = m;
}

// ---------------------------------------------------------------- launch
extern "C" void kernel_launch(void* const* d_in, const int* in_sizes, int n_in,
                              void* d_out, int out_size, void* d_ws, size_t ws_size,
                              hipStream_t stream) {
    const float* x     = (const float*)d_in[0];
    const int*   ei    = (const int*)d_in[1];
    const int*   batch = (const int*)d_in[2];
    const float* Wq = (const float*)d_in[3];
    const float* bq = (const float*)d_in[4];
    const float* Wk = (const float*)d_in[5];
    const float* bk = (const float*)d_in[6];
    const float* Wv = (const float*)d_in[7];
    const float* bv = (const float*)d_in[8];
    const float* Ws = (const float*)d_in[9];
    const float* bs = (const float*)d_in[10];
    const float* wg = (const float*)d_in[11];
    const float* bg = (const float*)d_in[12];
    float* out = (float*)d_out;

    char* w = (char*)d_ws;
    float* qb            = (float*)w;          w += (size_t)NN * 128 * 4;
    unsigned short* kvb  = (unsigned short*)w; w += (size_t)NN * 256 * 2;
    float* bufA          = (float*)w;          w += (size_t)NN * 128 * 4;
    float* bufB          = (float*)w;          w += (size_t)NN * 128 * 4;
    float* psum          = (float*)w;          w += (size_t)GG * PCH * 128 * 4;
    float* pmax          = (float*)w;          w += (size_t)GG * PCH * 128 * 4;
    unsigned short* wfh  = (unsigned short*)w; w += (size_t)12 * 16384 * 2;
    unsigned short* wfl  = (unsigned short*)w; w += (size_t)12 * 16384 * 2;
    // zero-region: counts | cursor | dhist | dcur  (one memset)
    int* counts          = (int*)w;            w += (size_t)NN * 4;
    int* cursor          = (int*)w;            w += (size_t)NN * 4;
    int* dhist           = (int*)w;            w += (size_t)256 * 4;
    int* dcur            = (int*)w;            w += (size_t)256 * 4;
    const size_t zero_bytes = (size_t)(NN + NN + 256 + 256) * 4;
    int* offsets         = (int*)w;            w += (size_t)(NN + 1) * 4;
    int* bsums           = (int*)w;            w += (size_t)256 * 4;
    int* perm            = (int*)w;            w += (size_t)NN * 4;
    int* csrc            = (int*)w;            w += (size_t)EE * 4;
    int* starts          = (int*)w;            w += (size_t)(GG + 1) * 4;

    const int* srcI = ei;
    const int* dstI = ei + EE;

    // CSR + degree-sorted perm + weight prep (16 graph nodes total, was 25)
    hipMemsetAsync(counts, 0, zero_bytes, stream);
    hist_kernel<<<(EE + 255) / 256, 256, 0, stream>>>(dstI, counts);
    block_scan_deg<<<SCB, 256, 0, stream>>>(counts, offsets, bsums, dhist);
    scan2<<<2, 256, 0, stream>>>(bsums, dhist);
    add_base_starts<<<SCB, 256, 0, stream>>>(offsets, bsums, batch, starts);
    deg_scatter<<<SCB, 256, 0, stream>>>(counts, dhist, dcur, perm);
    scatter_kernel<<<(EE + 255) / 256, 256, 0, stream>>>(srcI, dstI, offsets, cursor, csrc);
    prep_weights<<<dim3(12, 8), 256, 0, stream>>>(Wq, Wk, Wv, Ws, wfh, wfl);

    const float* xin = x;
    float* bufs[2] = {bufA, bufB};
    const int gemmBlocks = (NN + 63) / 64;   // 782
    const int attnBlocks = NN / 8;           // 6250, exact
    for (int l = 0; l < 3; ++l) {
        float* xs = bufs[l & 1];
        gemm_mfma<<<gemmBlocks, 256, 0, stream>>>(
            xin, wfh + (size_t)l * 4 * 16384, wfl + (size_t)l * 4 * 16384,
            bq + (size_t)l * 128, bk + (size_t)l * 128,
            bv + (size_t)l * 128, bs + (size_t)l * 128,
            qb, kvb, xs);
        attn_kernel<<<attnBlocks, 256, 0, stream>>>(qb, (const uint4*)kvb, xs, offsets, csrc, perm);
        xin = xs;
    }

    pool_partial<<<GG * PCH, 128, 0, stream>>>(xin, wg, bg, starts, psum, pmax);
    pool_final<<<GG, 128, 0, stream>>>(psum, pmax, out);
}

// Round 15
// 431.482 us; speedup vs baseline: 1.9018x; 1.0255x over previous
//
#include <hip/hip_runtime.h>
#include <hip/hip_bf16.h>

#define NN 50000
#define EE 800000
#define GG 64
#define PCH 16   // pooling chunks per graph
#define SCB ((NN + 255) / 256)   // 196 node blocks
// D=128, H=8, C=16, L=3

typedef __attribute__((ext_vector_type(8)))  short          s16x8;
typedef __attribute__((ext_vector_type(8)))  unsigned short u16x8;
typedef __attribute__((ext_vector_type(16))) float          f32x16;

// bf16 helpers (bit-pattern based)
union BFU { __hip_bfloat16 h; unsigned short u; };
__device__ __forceinline__ unsigned short f2bf(float f) {
    BFU b; b.h = __float2bfloat16(f); return b.u;
}
#define B2F_LO(u) __uint_as_float((u) << 16)
#define B2F_HI(u) __uint_as_float((u) & 0xffff0000u)
#define BF2F(us)  __uint_as_float(((unsigned)(us)) << 16)

// ---------------------------------------------------------------- CSR build
__global__ __launch_bounds__(256) void hist_kernel(const int* __restrict__ dst,
                                                   int* __restrict__ counts) {
    int e = blockIdx.x * 256 + threadIdx.x;
    if (e < EE) atomicAdd(&counts[dst[e]], 1);
}

// Single-kernel offsets build: per-block LDS scan + one atomicAdd block-base
// reservation (offsets need not be monotone in node id — any disjoint
// contiguous layout is a valid CSR; attn uses e1 = offs[n] + counts[n]).
// Also folds in the batch->starts computation (same index space).
__global__ __launch_bounds__(256)
void node_prep(const int* __restrict__ counts, int* __restrict__ offsets,
               int* __restrict__ gcur,
               const int* __restrict__ batch, int* __restrict__ starts) {
    __shared__ int sm[256];
    __shared__ int base;
    const int t = threadIdx.x;
    const int i = blockIdx.x * 256 + t;
    const int v = (i < NN) ? counts[i] : 0;
    sm[t] = v;
    __syncthreads();
    for (int off = 1; off < 256; off <<= 1) {
        int val = (t >= off) ? sm[t - off] : 0;
        __syncthreads();
        sm[t] += val;
        __syncthreads();
    }
    if (t == 255) base = atomicAdd(gcur, sm[255]);   // reserve contiguous chunk
    __syncthreads();
    if (i < NN) offsets[i] = base + sm[t] - v;       // exclusive within block
    if (i <= NN) {
        int b  = (i < NN) ? batch[i] : GG;
        int bp = (i == 0) ? -1 : batch[i - 1];
        for (int g = bp + 1; g <= b && g <= GG; ++g) starts[g] = i;
    }
}

__global__ __launch_bounds__(256) void scatter_kernel(const int* __restrict__ src,
                                                      const int* __restrict__ dst,
                                                      const int* __restrict__ offs,
                                                      int* __restrict__ cursor,
                                                      int* __restrict__ csrc) {
    int e = blockIdx.x * 256 + threadIdx.x;
    if (e < EE) {
        int dn = dst[e];
        int p = atomicAdd(&cursor[dn], 1);
        csrc[offs[dn] + p] = src[e];
    }
}

// ---------------------------------------------------------------- weight prep
// W[l][k][c] fp32 -> B-FRAGMENT-ORDER split-bf16:
//   wf[mat][(kk*128 + col)*8 + j] = W[kk*8 + j][col],  kk = K-chunk 0..15.
__global__ __launch_bounds__(256)
void prep_weights(const float* __restrict__ Wq, const float* __restrict__ Wk,
                  const float* __restrict__ Wv, const float* __restrict__ Ws,
                  unsigned short* __restrict__ wfh, unsigned short* __restrict__ wfl) {
    const int mat = blockIdx.x;           // 0..11
    const int l = mat >> 2, m = mat & 3;
    const float* W;
    switch (m) {
        case 0:  W = Wq; break;
        case 1:  W = Wk; break;
        case 2:  W = Wv; break;
        default: W = Ws; break;
    }
    W += (size_t)l * 16384;
    const int t = threadIdx.x;
    const int col = blockIdx.y * 16 + (t >> 4);
    const int kk  = t & 15;               // chunk of 8 K values
    u16x8 hi, lo;
    #pragma unroll
    for (int j = 0; j < 8; ++j) {
        float w = W[(kk * 8 + j) * 128 + col];
        unsigned short uh = f2bf(w);
        hi[j] = uh;
        lo[j] = f2bf(w - BF2F(uh));
    }
    const size_t o = (size_t)mat * 16384 + ((size_t)kk * 128 + col) * 8;
    *(u16x8*)(wfh + o) = hi;
    *(u16x8*)(wfl + o) = lo;
}

// ---------------------------------------------------------------- MFMA GEMM
// Phases: Q (3-term, bf16 out), K+V interleaved (1-term each), S (3-term,
// fp32 out). One barrier; B-frags stream from L2 in fragment order.
__global__ __launch_bounds__(256)
void gemm_mfma(const float* __restrict__ xin,
               const unsigned short* __restrict__ wHg,   // + l*4*16384, frag order
               const unsigned short* __restrict__ wLg,
               const float* __restrict__ bq, const float* __restrict__ bk,
               const float* __restrict__ bv, const float* __restrict__ bs,
               unsigned short* __restrict__ qbf, unsigned short* __restrict__ kvb,
               float* __restrict__ xs) {
    __shared__ unsigned short xl[16384];   // [0..8191]=hi, [8192..]=lo
    const int t = threadIdx.x;
    const int n0 = blockIdx.x * 64;

    // ---- stage x (fp32 -> split bf16, swizzled) ----
    const float4* X4 = (const float4*)xin;
    for (int i = t; i < 1024; i += 256) {            // 64 rows x 16 chunks
        const int row = i >> 4, ch = i & 15;
        const int node = n0 + row;
        float4 fa = make_float4(0.f, 0.f, 0.f, 0.f);
        float4 fb = make_float4(0.f, 0.f, 0.f, 0.f);
        if (node < NN) { fa = X4[node * 32 + ch * 2]; fb = X4[node * 32 + ch * 2 + 1]; }
        const float fv[8] = {fa.x, fa.y, fa.z, fa.w, fb.x, fb.y, fb.z, fb.w};
        u16x8 hi, lo;
        #pragma unroll
        for (int j = 0; j < 8; ++j) {
            unsigned short uh = f2bf(fv[j]);
            hi[j] = uh;
            lo[j] = f2bf(fv[j] - BF2F(uh));
        }
        const int base = row * 128 + (ch ^ (row & 7)) * 8;
        *(u16x8*)&xl[base] = hi;
        *(u16x8*)&xl[8192 + base] = lo;
    }
    __syncthreads();

    // ---- per-wave tile & A-fragments ----
    const int lane = t & 63, wid = t >> 6;
    const int r = lane & 31, g = lane >> 5;
    const int nt = (wid & 1) * 32;        // node offset in tile
    const int cb = (wid >> 1) * 64;       // col base
    s16x8 ah[8], al[8];
    {
        const int row = nt + r;
        const int s = row & 7;
        const int rb = row * 128;
        #pragma unroll
        for (int kc = 0; kc < 8; ++kc) {
            const int idx = rb + (((kc << 1) | g) ^ s) * 8;
            ah[kc] = *(const s16x8*)&xl[idx];
            al[kc] = *(const s16x8*)&xl[8192 + idx];
        }
    }
    const int col0 = cb + r, col1 = cb + 32 + r;

    // ---- phase Q (bf16 out) and phase S (fp32 out), 3-term split-bf16 ----
    #pragma unroll
    for (int pm = 0; pm < 2; ++pm) {
        const int m = pm ? 3 : 0;
        const unsigned short* WH = wHg + m * 16384;
        const unsigned short* WL = wLg + m * 16384;
        f32x16 acc0, acc1;
        #pragma unroll
        for (int j = 0; j < 16; ++j) { acc0[j] = 0.f; acc1[j] = 0.f; }
        #pragma unroll
        for (int kc = 0; kc < 8; ++kc) {
            const int kk = (kc << 1) | g;
            const s16x8 b0 = *(const s16x8*)&WH[(kk * 128 + col0) * 8];
            const s16x8 b1 = *(const s16x8*)&WH[(kk * 128 + col1) * 8];
            const s16x8 c0 = *(const s16x8*)&WL[(kk * 128 + col0) * 8];
            const s16x8 c1 = *(const s16x8*)&WL[(kk * 128 + col1) * 8];
            acc0 = __builtin_amdgcn_mfma_f32_32x32x16_bf16(ah[kc], b0, acc0, 0, 0, 0);
            acc1 = __builtin_amdgcn_mfma_f32_32x32x16_bf16(ah[kc], b1, acc1, 0, 0, 0);
            acc0 = __builtin_amdgcn_mfma_f32_32x32x16_bf16(al[kc], b0, acc0, 0, 0, 0);
            acc1 = __builtin_amdgcn_mfma_f32_32x32x16_bf16(al[kc], b1, acc1, 0, 0, 0);
            acc0 = __builtin_amdgcn_mfma_f32_32x32x16_bf16(ah[kc], c0, acc0, 0, 0, 0);
            acc1 = __builtin_amdgcn_mfma_f32_32x32x16_bf16(ah[kc], c1, acc1, 0, 0, 0);
        }
        const float* bp = pm ? bs : bq;
        const float b0 = bp[col0], b1 = bp[col1];
        if (pm == 0) {                                  // q -> bf16
            #pragma unroll
            for (int reg = 0; reg < 16; ++reg) {
                const int node = n0 + nt + (reg & 3) + 8 * (reg >> 2) + 4 * g;
                if (node < NN) {
                    unsigned short* qrow = qbf + (size_t)node * 128;
                    qrow[col0] = f2bf(acc0[reg] + b0);
                    qrow[col1] = f2bf(acc1[reg] + b1);
                }
            }
        } else {                                        // skip xs -> fp32
            #pragma unroll
            for (int reg = 0; reg < 16; ++reg) {
                const int node = n0 + nt + (reg & 3) + 8 * (reg >> 2) + 4 * g;
                if (node < NN) {
                    xs[node * 128 + col0] = acc0[reg] + b0;
                    xs[node * 128 + col1] = acc1[reg] + b1;
                }
            }
        }
    }

    // ---- phase K+V interleaved (single hi-term each; 4 loads in flight) ----
    {
        const unsigned short* WK = wHg + 1 * 16384;
        const unsigned short* WV = wHg + 2 * 16384;
        f32x16 ak0, ak1, av0, av1;
        #pragma unroll
        for (int j = 0; j < 16; ++j) { ak0[j] = 0.f; ak1[j] = 0.f; av0[j] = 0.f; av1[j] = 0.f; }
        #pragma unroll
        for (int kc = 0; kc < 8; ++kc) {
            const int kk = (kc << 1) | g;
            const s16x8 k0 = *(const s16x8*)&WK[(kk * 128 + col0) * 8];
            const s16x8 k1 = *(const s16x8*)&WK[(kk * 128 + col1) * 8];
            const s16x8 v0 = *(const s16x8*)&WV[(kk * 128 + col0) * 8];
            const s16x8 v1 = *(const s16x8*)&WV[(kk * 128 + col1) * 8];
            ak0 = __builtin_amdgcn_mfma_f32_32x32x16_bf16(ah[kc], k0, ak0, 0, 0, 0);
            ak1 = __builtin_amdgcn_mfma_f32_32x32x16_bf16(ah[kc], k1, ak1, 0, 0, 0);
            av0 = __builtin_amdgcn_mfma_f32_32x32x16_bf16(ah[kc], v0, av0, 0, 0, 0);
            av1 = __builtin_amdgcn_mfma_f32_32x32x16_bf16(ah[kc], v1, av1, 0, 0, 0);
        }
        const float bk0 = bk[col0], bk1 = bk[col1];
        const float bv0 = bv[col0], bv1 = bv[col1];
        // kv layout (ushorts): kvb[node*256 + h*32 + 0..15]=k, +16..31=v
        const int k0o = (col0 >> 4) * 32 + (col0 & 15);
        const int k1o = (col1 >> 4) * 32 + (col1 & 15);
        #pragma unroll
        for (int reg = 0; reg < 16; ++reg) {
            const int node = n0 + nt + (reg & 3) + 8 * (reg >> 2) + 4 * g;
            if (node < NN) {
                unsigned short* row = kvb + (size_t)node * 256;
                row[k0o]      = f2bf(ak0[reg] + bk0);
                row[k1o]      = f2bf(ak1[reg] + bk1);
                row[k0o + 16] = f2bf(av0[reg] + bv0);
                row[k1o + 16] = f2bf(av1[reg] + bv1);
            }
        }
    }
}

// ---------------------------------------------------------------- attention (CSR, online softmax)
// At memory-system roofline for kv gathers (r13). 32 threads/node, 4-way
// edge split, prefetch depth 2, two-round shfl merge. q is bf16 (r15).
// deg-sort perm removed (ledger r9/r13: sort itself never paid).
__global__ __launch_bounds__(256)
void attn_kernel(const unsigned short* __restrict__ qbf, const uint4* __restrict__ kv4,
                 float* __restrict__ xio,
                 const int* __restrict__ offs, const int* __restrict__ cnts,
                 const int* __restrict__ csrc) {
    const int t = threadIdx.x;
    const int h = t & 7;
    const int quarter = (t >> 3) & 3;
    const int n = blockIdx.x * 8 + (t >> 5);
    const uint4* qp = (const uint4*)(qbf + (size_t)n * 128) + h * 2;
    const uint4 qA = qp[0], qB = qp[1];
    const float4 q0 = make_float4(B2F_LO(qA.x), B2F_HI(qA.x), B2F_LO(qA.y), B2F_HI(qA.y));
    const float4 q1 = make_float4(B2F_LO(qA.z), B2F_HI(qA.z), B2F_LO(qA.w), B2F_HI(qA.w));
    const float4 q2 = make_float4(B2F_LO(qB.x), B2F_HI(qB.x), B2F_LO(qB.y), B2F_HI(qB.y));
    const float4 q3 = make_float4(B2F_LO(qB.z), B2F_HI(qB.z), B2F_LO(qB.w), B2F_HI(qB.w));
    float m = -__builtin_inff();
    float d = 0.f;
    float4 a0 = {}, a1 = {}, a2 = {}, a3 = {};
    const int e0 = offs[n], e1 = e0 + cnts[n];
    const int estart = e0 + quarter;
    if (estart < e1) {
        uint4 ka, kb, va, vb;                       // current
        { const uint4* p = kv4 + (size_t)csrc[estart] * 32 + h * 4;
          ka = p[0]; kb = p[1]; va = p[2]; vb = p[3]; }
        uint4 na, nb, nc, nd;                       // next
        if (estart + 4 < e1) {
            const uint4* p = kv4 + (size_t)csrc[estart + 4] * 32 + h * 4;
            na = p[0]; nb = p[1]; nc = p[2]; nd = p[3];
        }
        for (int ec = estart; ec < e1; ec += 4) {
            uint4 fa, fb, fc, fd;                   // next-next
            if (ec + 8 < e1) {
                const uint4* p = kv4 + (size_t)csrc[ec + 8] * 32 + h * 4;
                fa = p[0]; fb = p[1]; fc = p[2]; fd = p[3];
            }
            float dot =
                q0.x * B2F_LO(ka.x) + q0.y * B2F_HI(ka.x) + q0.z * B2F_LO(ka.y) + q0.w * B2F_HI(ka.y)
              + q1.x * B2F_LO(ka.z) + q1.y * B2F_HI(ka.z) + q1.z * B2F_LO(ka.w) + q1.w * B2F_HI(ka.w)
              + q2.x * B2F_LO(kb.x) + q2.y * B2F_HI(kb.x) + q2.z * B2F_LO(kb.y) + q2.w * B2F_HI(kb.y)
              + q3.x * B2F_LO(kb.z) + q3.y * B2F_HI(kb.z) + q3.z * B2F_LO(kb.w) + q3.w * B2F_HI(kb.w);
            const float alpha = dot * 0.25f;        // / sqrt(C=16)
            const float nm = fmaxf(m, alpha);
            const float scale = __expf(m - nm);     // 0 on first edge
            const float p = __expf(alpha - nm);
            d = d * scale + p;
            a0.x = a0.x * scale + p * B2F_LO(va.x); a0.y = a0.y * scale + p * B2F_HI(va.x);
            a0.z = a0.z * scale + p * B2F_LO(va.y); a0.w = a0.w * scale + p * B2F_HI(va.y);
            a1.x = a1.x * scale + p * B2F_LO(va.z); a1.y = a1.y * scale + p * B2F_HI(va.z);
            a1.z = a1.z * scale + p * B2F_LO(va.w); a1.w = a1.w * scale + p * B2F_HI(va.w);
            a2.x = a2.x * scale + p * B2F_LO(vb.x); a2.y = a2.y * scale + p * B2F_HI(vb.x);
            a2.z = a2.z * scale + p * B2F_LO(vb.y); a2.w = a2.w * scale + p * B2F_HI(vb.y);
            a3.x = a3.x * scale + p * B2F_LO(vb.z); a3.y = a3.y * scale + p * B2F_HI(vb.z);
            a3.z = a3.z * scale + p * B2F_LO(vb.w); a3.w = a3.w * scale + p * B2F_HI(vb.w);
            m = nm;
            ka = na; kb = nb; va = nc; vb = nd;     // shift pipeline
            na = fa; nb = fb; nc = fc; nd = fd;
        }
    }
    // ---- merge the four quarter-streams (exact in fp32): xor 8, then 16 ----
    #pragma unroll
    for (int o = 8; o <= 16; o <<= 1) {
        const float mp = __shfl_xor(m, o);
        const float dp = __shfl_xor(d, o);
        const float mc = fmaxf(fmaxf(m, mp), -1e30f);  // -1e30 guard: empty-stream NaN
        const float s0 = __expf(m - mc);
        const float s1 = __expf(mp - mc);
        d = d * s0 + dp * s1;
        float pa;
        pa = __shfl_xor(a0.x, o); a0.x = a0.x * s0 + pa * s1;
        pa = __shfl_xor(a0.y, o); a0.y = a0.y * s0 + pa * s1;
        pa = __shfl_xor(a0.z, o); a0.z = a0.z * s0 + pa * s1;
        pa = __shfl_xor(a0.w, o); a0.w = a0.w * s0 + pa * s1;
        pa = __shfl_xor(a1.x, o); a1.x = a1.x * s0 + pa * s1;
        pa = __shfl_xor(a1.y, o); a1.y = a1.y * s0 + pa * s1;
        pa = __shfl_xor(a1.z, o); a1.z = a1.z * s0 + pa * s1;
        pa = __shfl_xor(a1.w, o); a1.w = a1.w * s0 + pa * s1;
        pa = __shfl_xor(a2.x, o); a2.x = a2.x * s0 + pa * s1;
        pa = __shfl_xor(a2.y, o); a2.y = a2.y * s0 + pa * s1;
        pa = __shfl_xor(a2.z, o); a2.z = a2.z * s0 + pa * s1;
        pa = __shfl_xor(a2.w, o); a2.w = a2.w * s0 + pa * s1;
        pa = __shfl_xor(a3.x, o); a3.x = a3.x * s0 + pa * s1;
        pa = __shfl_xor(a3.y, o); a3.y = a3.y * s0 + pa * s1;
        pa = __shfl_xor(a3.z, o); a3.z = a3.z * s0 + pa * s1;
        pa = __shfl_xor(a3.w, o); a3.w = a3.w * s0 + pa * s1;
        m = mc;
    }
    if (quarter == 0) {
        const float inv = 1.f / (d + 1e-16f);
        float4* op = (float4*)(xio + (size_t)n * 128 + h * 16);
        float4 o0 = op[0], o1 = op[1], o2 = op[2], o3 = op[3];
        o0.x += a0.x * inv; o0.y += a0.y * inv; o0.z += a0.z * inv; o0.w += a0.w * inv;
        o1.x += a1.x * inv; o1.y += a1.y * inv; o1.z += a1.z * inv; o1.w += a1.w * inv;
        o2.x += a2.x * inv; o2.y += a2.y * inv; o2.z += a2.z * inv; o2.w += a2.w * inv;
        o3.x += a3.x * inv; o3.y += a3.y * inv; o3.z += a3.z * inv; o3.w += a3.w * inv;
        op[0] = o0; op[1] = o1; op[2] = o2; op[3] = o3;
    }
}

// ---------------------------------------------------------------- readout (2-phase, fused gate)
__global__ __launch_bounds__(128)
void pool_partial(const float* __restrict__ x, const float* __restrict__ wg,
                  const float* __restrict__ bg, const int* __restrict__ starts,
                  float* __restrict__ psum, float* __restrict__ pmax) {
    const int g  = blockIdx.x / PCH;
    const int ch = blockIdx.x % PCH;
    const int c  = threadIdx.x;
    const int s0 = starts[g], s1 = starts[g + 1];
    const int total = s1 - s0;
    const int len = (total + PCH - 1) / PCH;
    const int n0 = s0 + ch * len;
    const int n1 = min(n0 + len, s1);
    const float w = wg[c];
    const float b = bg[0];
    __shared__ float red[2];
    float sum = 0.f, mx = -__builtin_inff();
    for (int n = n0; n < n1; ++n) {
        const float xv = x[n * 128 + c];
        float p = xv * w;
        #pragma unroll
        for (int o = 32; o; o >>= 1) p += __shfl_xor(p, o);
        if ((c & 63) == 0) red[c >> 6] = p;
        __syncthreads();
        const float dot = red[0] + red[1];
        __syncthreads();
        const float score = 1.f / (1.f + __expf(-(dot + b)));
        sum += score * xv;
        mx = fmaxf(mx, xv);
    }
    psum[blockIdx.x * 128 + c] = sum;
    pmax[blockIdx.x * 128 + c] = mx;
}

__global__ __launch_bounds__(128)
void pool_final(const float* __restrict__ psum, const float* __restrict__ pmax,
                float* __restrict__ out) {
    const int g = blockIdx.x, c = threadIdx.x;
    float s = 0.f, m = -__builtin_inff();
    #pragma unroll
    for (int ch = 0; ch < PCH; ++ch) {
        s += psum[(g * PCH + ch) * 128 + c];
        m = fmaxf(m, pmax[(g * PCH + ch) * 128 + c]);
    }
    out[g * 256 + c] = s;
    out[g * 256 + 128 + c] = m;
}

// ---------------------------------------------------------------- launch
extern "C" void kernel_launch(void* const* d_in, const int* in_sizes, int n_in,
                              void* d_out, int out_size, void* d_ws, size_t ws_size,
                              hipStream_t stream) {
    const float* x     = (const float*)d_in[0];
    const int*   ei    = (const int*)d_in[1];
    const int*   batch = (const int*)d_in[2];
    const float* Wq = (const float*)d_in[3];
    const float* bq = (const float*)d_in[4];
    const float* Wk = (const float*)d_in[5];
    const float* bk = (const float*)d_in[6];
    const float* Wv = (const float*)d_in[7];
    const float* bv = (const float*)d_in[8];
    const float* Ws = (const float*)d_in[9];
    const float* bs = (const float*)d_in[10];
    const float* wg = (const float*)d_in[11];
    const float* bg = (const float*)d_in[12];
    float* out = (float*)d_out;

    char* w = (char*)d_ws;
    unsigned short* qbf  = (unsigned short*)w; w += (size_t)NN * 128 * 2;
    unsigned short* kvb  = (unsigned short*)w; w += (size_t)NN * 256 * 2;
    float* bufA          = (float*)w;          w += (size_t)NN * 128 * 4;
    float* bufB          = (float*)w;          w += (size_t)NN * 128 * 4;
    float* psum          = (float*)w;          w += (size_t)GG * PCH * 128 * 4;
    float* pmax          = (float*)w;          w += (size_t)GG * PCH * 128 * 4;
    unsigned short* wfh  = (unsigned short*)w; w += (size_t)12 * 16384 * 2;
    unsigned short* wfl  = (unsigned short*)w; w += (size_t)12 * 16384 * 2;
    // zero-region: counts | cursor | gcur  (one memset)
    int* counts          = (int*)w;            w += (size_t)NN * 4;
    int* cursor          = (int*)w;            w += (size_t)NN * 4;
    int* gcur            = (int*)w;            w += (size_t)64 * 4;
    const size_t zero_bytes = (size_t)(NN + NN + 64) * 4;
    int* offsets         = (int*)w;            w += (size_t)NN * 4;
    int* csrc            = (int*)w;            w += (size_t)EE * 4;
    int* starts          = (int*)w;            w += (size_t)(GG + 1) * 4;

    const int* srcI = ei;
    const int* dstI = ei + EE;

    // CSR + weight prep (6 graph nodes, was 9)
    hipMemsetAsync(counts, 0, zero_bytes, stream);
    hist_kernel<<<(EE + 255) / 256, 256, 0, stream>>>(dstI, counts);
    node_prep<<<SCB, 256, 0, stream>>>(counts, offsets, gcur, batch, starts);
    scatter_kernel<<<(EE + 255) / 256, 256, 0, stream>>>(srcI, dstI, offsets, cursor, csrc);
    prep_weights<<<dim3(12, 8), 256, 0, stream>>>(Wq, Wk, Wv, Ws, wfh, wfl);

    const float* xin = x;
    float* bufs[2] = {bufA, bufB};
    const int gemmBlocks = (NN + 63) / 64;   // 782
    const int attnBlocks = NN / 8;           // 6250, exact
    for (int l = 0; l < 3; ++l) {
        float* xs = bufs[l & 1];
        gemm_mfma<<<gemmBlocks, 256, 0, stream>>>(
            xin, wfh + (size_t)l * 4 * 16384, wfl + (size_t)l * 4 * 16384,
            bq + (size_t)l * 128, bk + (size_t)l * 128,
            bv + (size_t)l * 128, bs + (size_t)l * 128,
            qbf, kvb, xs);
        attn_kernel<<<attnBlocks, 256, 0, stream>>>(qbf, (const uint4*)kvb, xs, offsets, counts, csrc);
        xin = xs;
    }

    pool_partial<<<GG * PCH, 128, 0, stream>>>(xin, wg, bg, starts, psum, pmax);
    pool_final<<<GG, 128, 0, stream>>>(psum, pmax, out);
}